// Round 1
// baseline (203.846 us; speedup 1.0000x reference)
//
#include <hip/hip_runtime.h>
#include <stdint.h>
#include <math.h>

#define CTX 2048
#define DM  2048
#define NH  16
#define HD  128

typedef __attribute__((ext_vector_type(8))) short short8;   // 8 x bf16 (4 VGPRs)
typedef __attribute__((ext_vector_type(4))) float f32x4;    // MFMA acc
typedef unsigned short u16;

__device__ __forceinline__ u16 f2bf(float f) {
    unsigned u = __float_as_uint(f);
    unsigned r = u + 0x7fffu + ((u >> 16) & 1u);   // RTNE
    return (u16)(r >> 16);
}
__device__ __forceinline__ float bf2f(u16 h) {
    return __uint_as_float(((unsigned)h) << 16);
}

// ------- merged weight transpose + f32->bf16 (W[K][N] -> WT[N][K]), 4 slabs ---
__global__ __launch_bounds__(256)
void transpose_all_kernel(const float* __restrict__ Wq, const float* __restrict__ Wo,
                          const float* __restrict__ Wkv,
                          u16* __restrict__ WqT, u16* __restrict__ WoT, u16* __restrict__ WkvT)
{
    __shared__ float tile[32][33];
    int z = blockIdx.z;
    const float* S; u16* D; int nsrc, c0, r0;
    if (z == 0)      { S = Wq;  D = WqT;  nsrc = DM;     c0 = 0;  r0 = 0;    }
    else if (z == 1) { S = Wo;  D = WoT;  nsrc = DM;     c0 = 0;  r0 = 0;    }
    else if (z == 2) { S = Wkv; D = WkvT; nsrc = 2 * DM; c0 = 0;  r0 = 0;    }
    else             { S = Wkv; D = WkvT; nsrc = 2 * DM; c0 = DM; r0 = DM;   }
    int k0 = blockIdx.x * 32, n0 = blockIdx.y * 32;
    int tx = threadIdx.x, ty = threadIdx.y;          // 32 x 8
#pragma unroll
    for (int j = 0; j < 4; ++j) {
        int kk = ty + 8 * j;
        tile[kk][tx] = S[(size_t)(k0 + kk) * nsrc + c0 + n0 + tx];
    }
    __syncthreads();
#pragma unroll
    for (int j = 0; j < 4; ++j) {
        int nn = ty + 8 * j;
        D[(size_t)(r0 + n0 + nn) * DM + k0 + tx] = f2bf(tile[tx][nn]);
    }
}

// -------- LN stats + normalized A matrices (bf16) + rotary factor table -------
__global__ __launch_bounds__(256)
void ln_stats_kernel(const float* __restrict__ x,
                     const float* __restrict__ qg, const float* __restrict__ qb,
                     const float* __restrict__ kg, const float* __restrict__ kb,
                     u16* __restrict__ Aq, u16* __restrict__ Akv, float* __restrict__ ftab)
{
    int c = blockIdx.x, t = threadIdx.x;
    const float* row = x + (size_t)c * DM;
    float4 v0 = *(const float4*)(row + t * 8);
    float4 v1 = *(const float4*)(row + t * 8 + 4);
    float vals[8] = {v0.x, v0.y, v0.z, v0.w, v1.x, v1.y, v1.z, v1.w};
    float s = 0.f, ss = 0.f;
#pragma unroll
    for (int j = 0; j < 8; ++j) { s += vals[j]; ss += vals[j] * vals[j]; }
#pragma unroll
    for (int off = 32; off; off >>= 1) { s += __shfl_xor(s, off); ss += __shfl_xor(ss, off); }
    __shared__ float red[8];
    int w = t >> 6;
    if ((t & 63) == 0) { red[w] = s; red[4 + w] = ss; }
    __syncthreads();
    float st  = red[0] + red[1] + red[2] + red[3];
    float sst = red[4] + red[5] + red[6] + red[7];
    float mu   = st * (1.f / DM);
    float var  = sst * (1.f / DM) - mu * mu;
    float rstd = rsqrtf(var + 1e-5f);
    if (t < 64) {                         // rotary table, m folded in
        const float LT64 = 10.30895266f / 64.f;   // ln(30000)/64
        float m = sqrtf(sst);
        float sn, cs;
        sincosf((float)c * ((float)t * LT64), &sn, &cs);
        float2 wv = {m * cs, m * sn};
        *(float2*)(ftab + ((size_t)c * 64 + t) * 2) = wv;
    }
    short8 aq, akv;
#pragma unroll
    for (int j = 0; j < 8; ++j) {
        int d = t * 8 + j;
        float xh = (vals[j] - mu) * rstd;
        aq[j]  = (short)f2bf(xh * qg[d] + qb[d]);
        akv[j] = (short)f2bf(xh * kg[d] + kb[d]);
    }
    *(short8*)(Aq  + (size_t)c * DM + t * 8) = aq;
    *(short8*)(Akv + (size_t)c * DM + t * 8) = akv;
}

// ---------------- fused QKV projection GEMM -----------------------------------
// 256x256 tile, BK=64, 8 waves (2Mx4N), 4-phase K-tile schedule with counted
// vmcnt(6) (T3+T4), XOR-swizzled LDS (T2: 16B unit u ^= row&7, swizzle applied
// on the GLOBAL source side so global_load_lds's linear lane-ordered LDS write
// lands swizzled; ds_read applies the same XOR), setprio around MFMA (T5).
// Three segments of 8x8 tiles: seg0 Q = Aq * WqT^T, seg1 K = Akv * WkvT[0:2048]^T,
// seg2 V with swapped operands (A = WkvT[2048:4096], B = Akv) so the epilogue
// writes vT[h*128+d][c] directly (row bias).
//
// Race audit (who may overwrite LDS when):
//   P1 stages B(kt+1,1) -> other buffer, always safe.
//   P3 stages B(kt+2,0) -> overwrites B(kt,0): all B-reads of buf issued in
//       P1/P2, retired at P2's lgkmcnt(0), all waves past P2's end barrier.
//   P4 stages A(kt+2,0/1) -> overwrites A(kt,*): A-reads issued P1/P3, retired
//       at P3's lgkmcnt(0), all waves past P3's end barrier.
// vmcnt at each tile boundary: loads newer than tile kt+1 = B(kt+2,0) + 2x
// A(kt+2,*) = 3 half-tiles = 6 load instructions -> s_waitcnt vmcnt(6).
__global__ __launch_bounds__(512, 2)
void qkv_gemm256_kernel(const u16* __restrict__ Aq, const u16* __restrict__ Akv,
                        const u16* __restrict__ WqT, const u16* __restrict__ WkvT,
                        const float* __restrict__ bq, const float* __restrict__ bkv,
                        u16* __restrict__ Qf, u16* __restrict__ Kf, u16* __restrict__ vT)
{
    __shared__ __align__(16) u16 As[2][2][128][64];   // [buf][half][row][col]
    __shared__ __align__(16) u16 Bs[2][2][128][64];

    constexpr int NT = DM / 64;                       // 32 K-tiles

    // XCD-aware swizzle: 192 blocks, 24 contiguous tiles per XCD (192 % 8 == 0)
    int lin = blockIdx.x;
    int swz = (lin & 7) * 24 + (lin >> 3);
    int mt  = swz & 7;          // M tile 0..7
    int ng  = swz >> 3;         // 0..23
    int seg = ng >> 3;          // 0:Q 1:K 2:V
    int nt  = ng & 7;           // N tile 0..7

    const u16* Amat; const u16* Bmat; const float* bias; u16* outp; bool rowbias;
    if (seg == 0) {
        Amat = Aq  + (size_t)mt * 256 * DM;
        Bmat = WqT + (size_t)nt * 256 * DM;
        bias = bq + nt * 256;
        outp = Qf + (size_t)mt * 256 * DM + nt * 256;
        rowbias = false;
    } else if (seg == 1) {
        Amat = Akv  + (size_t)mt * 256 * DM;
        Bmat = WkvT + (size_t)nt * 256 * DM;
        bias = bkv + nt * 256;
        outp = Kf + (size_t)mt * 256 * DM + nt * 256;
        rowbias = false;
    } else {
        Amat = WkvT + (size_t)(DM + mt * 256) * DM;   // V dims as GEMM rows
        Bmat = Akv  + (size_t)nt * 256 * DM;          // context as GEMM cols
        bias = bkv + DM + mt * 256;                   // per-row bias
        outp = vT + (size_t)mt * 256 * CTX + nt * 256;
        rowbias = true;
    }

    int tid = threadIdx.x;
    int wid = tid >> 6, l = tid & 63;
    int wr = wid >> 2, wc = wid & 3;                  // 2x4 wave grid
    int lhi = l >> 4, llo = l & 15;
    int srow  = l >> 3;                               // staging: row within 8-row group
    int sunit = (l & 7) ^ srow;                       // inverse-swizzled global 16B unit

    auto stageA = [&](int kt, int h) {
#pragma unroll
        for (int rd = 0; rd < 2; ++rd) {
            const u16* src = Amat + (size_t)(h * 128 + rd * 64 + wid * 8 + srow) * DM
                             + kt * 64 + sunit * 8;
            __builtin_amdgcn_global_load_lds((const __attribute__((address_space(1))) void*)src,
                (__attribute__((address_space(3))) void*)&As[kt & 1][h][rd * 64 + wid * 8][0],
                16, 0, 0);
        }
    };
    auto stageB = [&](int kt, int h) {
#pragma unroll
        for (int rd = 0; rd < 2; ++rd) {
            const u16* src = Bmat + (size_t)(h * 128 + rd * 64 + wid * 8 + srow) * DM
                             + kt * 64 + sunit * 8;
            __builtin_amdgcn_global_load_lds((const __attribute__((address_space(1))) void*)src,
                (__attribute__((address_space(3))) void*)&Bs[kt & 1][h][rd * 64 + wid * 8][0],
                16, 0, 0);
        }
    };

    f32x4 acc[8][4] = {};                 // 128 VGPRs of accumulator
    short8 a[4][2];                       // 4 m-frags x 2 k-slices (reused mi0-3 / mi4-7)
    short8 b0[2][2], b1[2][2];            // ni0-1 / ni2-3
    int bhalf = wc >> 1, brow = (wc & 1) * 64;

    // prologue: tile0 fully + A(1,0),A(1,1),B(1,0) = 7 half-tiles (14 loads)
    stageA(0, 0); stageA(0, 1); stageB(0, 0); stageB(0, 1);
    stageA(1, 0); stageA(1, 1); stageB(1, 0);
    asm volatile("s_waitcnt vmcnt(6)" ::: "memory");
    __builtin_amdgcn_s_barrier();

    for (int kt = 0; kt < NT; ++kt) {
        int buf = kt & 1;

        // ---------- P1: ds_read b0(ni0-1)+a(mi0-3) [12xb128]; stage B(kt+1,1)
#pragma unroll
        for (int ni = 0; ni < 2; ++ni)
#pragma unroll
            for (int ks = 0; ks < 2; ++ks) {
                int r = brow + 16 * ni + llo;
                b0[ni][ks] = *(const short8*)&Bs[buf][bhalf][r][((ks * 4 + lhi) ^ (llo & 7)) << 3];
            }
#pragma unroll
        for (int mi = 0; mi < 4; ++mi)
#pragma unroll
            for (int ks = 0; ks < 2; ++ks) {
                int r = 16 * mi + llo;
                a[mi][ks] = *(const short8*)&As[buf][wr][r][((ks * 4 + lhi) ^ (llo & 7)) << 3];
            }
        if (kt + 1 < NT) stageB(kt + 1, 1);
        __builtin_amdgcn_s_barrier();
        asm volatile("s_waitcnt lgkmcnt(0)" ::: "memory");
        __builtin_amdgcn_s_setprio(1);
#pragma unroll
        for (int ks = 0; ks < 2; ++ks)
#pragma unroll
            for (int mi = 0; mi < 4; ++mi)
#pragma unroll
                for (int ni = 0; ni < 2; ++ni)
                    acc[mi][ni] = __builtin_amdgcn_mfma_f32_16x16x32_bf16(
                        a[mi][ks], b0[ni][ks], acc[mi][ni], 0, 0, 0);
        __builtin_amdgcn_s_setprio(0);
        __builtin_amdgcn_s_barrier();

        // ---------- P2: ds_read b1(ni2-3) [4xb128]; MFMA mi0-3 x ni2-3
#pragma unroll
        for (int ni = 0; ni < 2; ++ni)
#pragma unroll
            for (int ks = 0; ks < 2; ++ks) {
                int r = brow + 16 * (2 + ni) + llo;
                b1[ni][ks] = *(const short8*)&Bs[buf][bhalf][r][((ks * 4 + lhi) ^ (llo & 7)) << 3];
            }
        __builtin_amdgcn_s_barrier();
        asm volatile("s_waitcnt lgkmcnt(0)" ::: "memory");
        __builtin_amdgcn_s_setprio(1);
#pragma unroll
        for (int ks = 0; ks < 2; ++ks)
#pragma unroll
            for (int mi = 0; mi < 4; ++mi)
#pragma unroll
                for (int ni = 0; ni < 2; ++ni)
                    acc[mi][2 + ni] = __builtin_amdgcn_mfma_f32_16x16x32_bf16(
                        a[mi][ks], b1[ni][ks], acc[mi][2 + ni], 0, 0, 0);
        __builtin_amdgcn_s_setprio(0);
        __builtin_amdgcn_s_barrier();

        // ---------- P3: ds_read a(mi4-7) [8xb128]; stage B(kt+2,0); MFMA mi4-7 x ni2-3
#pragma unroll
        for (int mi = 0; mi < 4; ++mi)
#pragma unroll
            for (int ks = 0; ks < 2; ++ks) {
                int r = 16 * (4 + mi) + llo;
                a[mi][ks] = *(const short8*)&As[buf][wr][r][((ks * 4 + lhi) ^ (llo & 7)) << 3];
            }
        if (kt + 2 < NT) stageB(kt + 2, 0);
        __builtin_amdgcn_s_barrier();
        asm volatile("s_waitcnt lgkmcnt(0)" ::: "memory");
        __builtin_amdgcn_s_setprio(1);
#pragma unroll
        for (int ks = 0; ks < 2; ++ks)
#pragma unroll
            for (int mi = 0; mi < 4; ++mi)
#pragma unroll
                for (int ni = 0; ni < 2; ++ni)
                    acc[4 + mi][2 + ni] = __builtin_amdgcn_mfma_f32_16x16x32_bf16(
                        a[mi][ks], b1[ni][ks], acc[4 + mi][2 + ni], 0, 0, 0);
        __builtin_amdgcn_s_setprio(0);
        __builtin_amdgcn_s_barrier();

        // ---------- P4: stage A(kt+2,0/1); MFMA mi4-7 x ni0-1; counted vmcnt
        if (kt + 2 < NT) { stageA(kt + 2, 0); stageA(kt + 2, 1); }
        __builtin_amdgcn_s_barrier();
        __builtin_amdgcn_s_setprio(1);
#pragma unroll
        for (int ks = 0; ks < 2; ++ks)
#pragma unroll
            for (int mi = 0; mi < 4; ++mi)
#pragma unroll
                for (int ni = 0; ni < 2; ++ni)
                    acc[4 + mi][ni] = __builtin_amdgcn_mfma_f32_16x16x32_bf16(
                        a[mi][ks], b0[ni][ks], acc[4 + mi][ni], 0, 0, 0);
        __builtin_amdgcn_s_setprio(0);
        if (kt + 2 < NT)      { asm volatile("s_waitcnt vmcnt(6)" ::: "memory"); }
        else if (kt + 1 < NT) { asm volatile("s_waitcnt vmcnt(0)" ::: "memory"); }
        __builtin_amdgcn_s_barrier();
    }

    // ---------------- epilogue: bias + bf16 store ----------------------------
    int rbase = 128 * wr;
    int cbase = 64 * wc;
    if (!rowbias) {
#pragma unroll
        for (int ni = 0; ni < 4; ++ni) {
            float bv = bias[cbase + 16 * ni + llo];
#pragma unroll
            for (int mi = 0; mi < 8; ++mi)
#pragma unroll
                for (int rr = 0; rr < 4; ++rr) {
                    int gr = rbase + 16 * mi + 4 * lhi + rr;
                    outp[(size_t)gr * DM + cbase + 16 * ni + llo] = f2bf(acc[mi][ni][rr] + bv);
                }
        }
    } else {
#pragma unroll
        for (int mi = 0; mi < 8; ++mi)
#pragma unroll
            for (int rr = 0; rr < 4; ++rr) {
                int gr = rbase + 16 * mi + 4 * lhi + rr;
                float bv = bias[gr];
#pragma unroll
                for (int ni = 0; ni < 4; ++ni)
                    outp[(size_t)gr * CTX + cbase + 16 * ni + llo] = f2bf(acc[mi][ni][rr] + bv);
            }
    }
}

// -------- table-driven rotary + per-head LN (one block per token row) ---------
__global__ __launch_bounds__(256)
void rot_ln_kernel(const u16* __restrict__ Qf, const u16* __restrict__ Kf,
                   const float* __restrict__ ftab,
                   const float* __restrict__ g, const float* __restrict__ b,
                   u16* __restrict__ qnB, u16* __restrict__ knB,
                   float qk_scale, float fold_q)
{
    int c = blockIdx.x, t = threadIdx.x;
    int h  = t >> 4;
    int dl = (t & 15) * 8;
    const float* tab = ftab + ((size_t)c * 64 + (dl >> 1)) * 2;
    float fre[4], fim[4];
#pragma unroll
    for (int p = 0; p < 4; ++p) { fre[p] = tab[2 * p]; fim[p] = tab[2 * p + 1]; }
    float gv[8], bv2[8];
#pragma unroll
    for (int j = 0; j < 8; ++j) { gv[j] = g[dl + j]; bv2[j] = b[dl + j]; }

#pragma unroll
    for (int z = 0; z < 2; ++z) {
        const u16* src = z ? Kf : Qf;
        u16* dst = z ? knB : qnB;
        float fold = z ? 1.f : fold_q;
        short8 vv = *(const short8*)(src + (size_t)c * DM + t * 8);
        float o[8];
        float s = 0.f, ss = 0.f;
#pragma unroll
        for (int p = 0; p < 4; ++p) {
            float a  = bf2f((u16)vv[2 * p])     * qk_scale;
            float b2 = bf2f((u16)vv[2 * p + 1]) * qk_scale;
            float o0 = a * fre[p] - b2 * fim[p];
            float o1 = a * fim[p] + b2 * fre[p];
            o[2 * p] = o0; o[2 * p + 1] = o1;
            s += o0 + o1;
            ss += o0 * o0 + o1 * o1;
        }
#pragma unroll
        for (int off = 1; off < 16; off <<= 1) {
            s += __shfl_xor(s, off);
            ss += __shfl_xor(ss, off);
        }
        float mu   = s * (1.f / HD);
        float var  = ss * (1.f / HD) - mu * mu;
        float rstd = rsqrtf(var + 1e-5f);
        short8 r;
#pragma unroll
        for (int j = 0; j < 8; ++j)
            r[j] = (short)f2bf(((o[j] - mu) * rstd * gv[j] + bv2[j]) * fold);
        *(short8*)(dst + ((size_t)h * CTX + c) * HD + dl) = r;
    }
}

// ---------------- causal flash attention v4b ----------------------------------
__global__ __launch_bounds__(256, 2)
void attn_kernel(const u16* __restrict__ qn, const u16* __restrict__ kn,
                 const u16* __restrict__ vT, u16* __restrict__ aout)
{
    __shared__ __align__(16) u16 Kb[2][64][128];
    __shared__ __align__(16) u16 Vb[2][128][64];
    __shared__ __align__(16) u16 p_lds[4][16][72];

    int h  = blockIdx.y;
    int xs = blockIdx.x;
    int qb = (h >= 8) ? (31 - xs) : xs;   // CU load-balance pairing
    int q0 = qb * 64;
    int tid = threadIdx.x, w = tid >> 6, l = tid & 63;
    int lhi = l >> 4, llo = l & 15;

    const u16* qrow = qn + ((size_t)h * CTX + q0 + 16 * w + llo) * HD + 8 * lhi;
    short8 qf[4];
#pragma unroll
    for (int ks = 0; ks < 4; ++ks) qf[ks] = *(const short8*)(qrow + 32 * ks);

    auto stage = [&](int buf, int kv0) {
        int rb = 16 * w;
#pragma unroll
        for (int j = 0; j < 4; ++j) {
            int r = rb + 4 * j + (l >> 4);
            int csw = (l & 15) ^ (r & 15);
            const u16* src = kn + ((size_t)h * CTX + kv0 + r) * HD + (csw << 3);
            __builtin_amdgcn_global_load_lds((const __attribute__((address_space(1))) void*)src,
                (__attribute__((address_space(3))) void*)&Kb[buf][rb + 4 * j][0], 16, 0, 0);
        }
        int db = 32 * w;
#pragma unroll
        for (int j = 0; j < 4; ++j) {
            int d = db + 8 * j + (l >> 3);
            int csw = (l & 7) ^ (d & 7);
            const u16* src = vT + ((size_t)h * HD + d) * CTX + kv0 + (csw << 3);
            __builtin_amdgcn_global_load_lds((const __attribute__((address_space(1))) void*)src,
                (__attribute__((address_space(3))) void*)&Vb[buf][db + 8 * j][0], 16, 0, 0);
        }
    };

    float m_s = -1e30f, l_p = 0.f;
    f32x4 o_acc[8];
#pragma unroll
    for (int ni = 0; ni < 8; ++ni) o_acc[ni] = (f32x4){0.f, 0.f, 0.f, 0.f};

    stage(0, 0);
    __syncthreads();

    int cur = 0;
    for (int jt = 0; jt <= qb; ++jt) {
        if (jt < qb) stage(cur ^ 1, (jt + 1) * 64);   // prefetch overlaps compute

        f32x4 sacc[4] = {};
        __builtin_amdgcn_s_setprio(1);
#pragma unroll
        for (int ks = 0; ks < 4; ++ks) {
#pragma unroll
            for (int ni = 0; ni < 4; ++ni) {
                short8 kf = *(const short8*)&Kb[cur][16 * ni + llo][((4 * ks + lhi) ^ llo) << 3];
                sacc[ni] = __builtin_amdgcn_mfma_f32_16x16x32_bf16(kf, qf[ks], sacc[ni], 0, 0, 0);
            }
        }
        __builtin_amdgcn_s_setprio(0);

        if (jt == qb) {                  // causal mask inside diagonal tile
            int qloc = 16 * w + llo;
#pragma unroll
            for (int ni = 0; ni < 4; ++ni)
#pragma unroll
                for (int r = 0; r < 4; ++r)
                    if (16 * ni + 4 * lhi + r > qloc) sacc[ni][r] = -INFINITY;
        }

        // speculative P with OLD running max (no cross-lane wait)
        float pv[16];
#pragma unroll
        for (int ni = 0; ni < 4; ++ni)
#pragma unroll
            for (int r = 0; r < 4; ++r) pv[4 * ni + r] = exp2f(sacc[ni][r] - m_s);

        // per-lane local max only; __any supplies the cross-lane OR
        float mx = sacc[0][0];
#pragma unroll
        for (int ni = 0; ni < 4; ++ni)
#pragma unroll
            for (int r = 0; r < 4; ++r) mx = fmaxf(mx, sacc[ni][r]);

        if (__any(mx > m_s + 8.f)) {     // rare path: full reduce + rescale
            mx = fmaxf(mx, __shfl_xor(mx, 16));
            mx = fmaxf(mx, __shfl_xor(mx, 32));
            float mnew = fmaxf(m_s, mx);
            float fac = exp2f(m_s - mnew);
#pragma unroll
            for (int r = 0; r < 4; ++r) {
                float fr = __shfl(fac, 4 * lhi + r);
#pragma unroll
                for (int ni = 0; ni < 8; ++ni) o_acc[ni][r] *= fr;
            }
#pragma unroll
            for (int ni = 0; ni < 4; ++ni)
#pragma unroll
                for (int r = 0; r < 4; ++r) pv[4 * ni + r] = exp2f(sacc[ni][r] - mnew);
            l_p *= fac;
            m_s = mnew;
        }

        // pack P -> p_lds
#pragma unroll
        for (int ni = 0; ni < 4; ++ni)
#pragma unroll
            for (int hf = 0; hf < 2; ++hf) {
                unsigned pk;
                asm("v_cvt_pk_bf16_f32 %0, %1, %2" : "=v"(pk)
                    : "v"(pv[4 * ni + 2 * hf]), "v"(pv[4 * ni + 2 * hf + 1]));
                *(unsigned*)&p_lds[w][llo][16 * ni + 4 * lhi + 2 * hf] = pk;
            }

        // deferred l: per-lane partial only (cross-lane reduce in epilogue)
        float ps = 0.f;
#pragma unroll
        for (int j = 0; j < 16; ++j) ps += pv[j];
        l_p += ps;

        // O += P . V
        __builtin_amdgcn_s_setprio(1);
#pragma unroll
        for (int ks = 0; ks < 2; ++ks) {
            short8 pa = *(const short8*)&p_lds[w][llo][32 * ks + 8 * lhi];
#pragma unroll
            for (int ni = 0; ni < 8; ++ni) {
                short8 vf = *(const short8*)&Vb[cur][16 * ni + llo][((4 * ks + lhi) ^ (llo & 7)) << 3];
                o_acc[ni] = __builtin_amdgcn_mfma_f32_16x16x32_bf16(pa, vf, o_acc[ni], 0, 0, 0);
            }
        }
        __builtin_amdgcn_s_setprio(0);

        __syncthreads();   // drains prefetch vmcnt + frees buf[cur]
        cur ^= 1;
    }

    float lsum = l_p;
    lsum += __shfl_xor(lsum, 16);
    lsum += __shfl_xor(lsum, 32);
#pragma unroll
    for (int r = 0; r < 4; ++r) {
        float lr  = __shfl(lsum, 4 * lhi + r);
        float inv = 1.f / lr;
        int qrow2 = q0 + 16 * w + 4 * lhi + r;
#pragma unroll
        for (int ni = 0; ni < 8; ++ni)
            aout[(size_t)qrow2 * DM + h * HD + 16 * ni + llo] = f2bf(o_acc[ni][r] * inv);
    }
}

// ---------------- O-projection GEMM, split-K, bf16 partials -------------------
__global__ __launch_bounds__(256, 2)
void gemm_split_kernel(const u16* __restrict__ A, const u16* __restrict__ BT,
                       u16* __restrict__ outp, int klen)
{
    __shared__ __align__(16) u16 At[128][32];
    __shared__ __align__(16) u16 Bt[128][32];
    int tid = threadIdx.x;
    int w = tid >> 6, l = tid & 63;
    int wr = w >> 1, wc = w & 1;
    int m0 = blockIdx.x * 128, n0 = blockIdx.y * 128;
    int koff = blockIdx.z * klen;
    int lhi = l >> 4, llo = l & 15;
    f32x4 acc[4][4] = {};
    outp += (size_t)blockIdx.z * CTX * DM;

    int srow = l >> 2, scol = (l & 3) * 8;
    for (int k0 = koff; k0 < koff + klen; k0 += 32) {
#pragma unroll
        for (int j = 0; j < 2; ++j) {
            int r = 32 * w + 16 * j;
            const void* ga = A  + (size_t)(m0 + r + srow) * DM + k0 + scol;
            const void* gb = BT + (size_t)(n0 + r + srow) * DM + k0 + scol;
            __builtin_amdgcn_global_load_lds((const __attribute__((address_space(1))) void*)ga,
                                             (__attribute__((address_space(3))) void*)&At[r][0], 16, 0, 0);
            __builtin_amdgcn_global_load_lds((const __attribute__((address_space(1))) void*)gb,
                                             (__attribute__((address_space(3))) void*)&Bt[r][0], 16, 0, 0);
        }
        __syncthreads();
        short8 a[4];
#pragma unroll
        for (int mi = 0; mi < 4; ++mi)
            a[mi] = *(const short8*)&At[64 * wr + 16 * mi + llo][lhi * 8];
#pragma unroll
        for (int ni = 0; ni < 4; ++ni) {
            short8 b = *(const short8*)&Bt[64 * wc + 16 * ni + llo][lhi * 8];
#pragma unroll
            for (int mi = 0; mi < 4; ++mi)
                acc[mi][ni] = __builtin_amdgcn_mfma_f32_16x16x32_bf16(a[mi], b, acc[mi][ni], 0, 0, 0);
        }
        __syncthreads();
    }
#pragma unroll
    for (int ni = 0; ni < 4; ++ni) {
        int gc = n0 + 64 * wc + 16 * ni + llo;
#pragma unroll
        for (int mi = 0; mi < 4; ++mi)
#pragma unroll
            for (int rr = 0; rr < 4; ++rr) {
                int gr = m0 + 64 * wr + 16 * mi + lhi * 4 + rr;
                outp[(size_t)gr * DM + gc] = f2bf(acc[mi][ni][rr]);
            }
    }
}

// ---------------- combine bf16 split-K partials + bias ------------------------
__global__ __launch_bounds__(256)
void combine_kernel(const u16* __restrict__ p, const float* __restrict__ bias,
                    float* __restrict__ out)
{
    size_t i = ((size_t)blockIdx.x * 256 + threadIdx.x) * 8;
    short8 a = *(const short8*)(p + i);
    short8 b = *(const short8*)(p + (size_t)CTX * DM + i);
    int dbase = (int)(i & (DM - 1));
    float4 bv0 = *(const float4*)(bias + dbase);
    float4 bv1 = *(const float4*)(bias + dbase + 4);
    float r[8];
    float bvv[8] = {bv0.x, bv0.y, bv0.z, bv0.w, bv1.x, bv1.y, bv1.z, bv1.w};
#pragma unroll
    for (int j = 0; j < 8; ++j)
        r[j] = bf2f((u16)a[j]) + bf2f((u16)b[j]) + bvv[j];
    *(float4*)(out + i)     = (float4){r[0], r[1], r[2], r[3]};
    *(float4*)(out + i + 4) = (float4){r[4], r[5], r[6], r[7]};
}

// ------------------------------- launcher ------------------------------------
extern "C" void kernel_launch(void* const* d_in, const int* in_sizes, int n_in,
                              void* d_out, int out_size, void* d_ws, size_t ws_size,
                              hipStream_t stream)
{
    const float* x   = (const float*)d_in[0];
    const float* qng = (const float*)d_in[1];
    const float* qnb = (const float*)d_in[2];
    const float* kng = (const float*)d_in[3];
    const float* knb = (const float*)d_in[4];
    const float* Wq  = (const float*)d_in[5];
    const float* bq  = (const float*)d_in[6];
    const float* Wkv = (const float*)d_in[7];
    const float* bkv = (const float*)d_in[8];
    const float* Wo  = (const float*)d_in[9];
    const float* bo  = (const float*)d_in[10];
    const float* lng = (const float*)d_in[11];
    const float* lnb = (const float*)d_in[12];
    float* out = (float*)d_out;

    uint8_t* ws = (uint8_t*)d_ws;
    size_t off = 0;
    auto alloc = [&](size_t bytes) -> void* {
        void* p = ws + off;
        off += (bytes + 255) & ~(size_t)255;
        return p;
    };
    u16*   WqT  = (u16*)alloc((size_t)DM * DM * 2);
    u16*   WkvT = (u16*)alloc((size_t)2 * DM * DM * 2);
    u16*   WoT  = (u16*)alloc((size_t)DM * DM * 2);
    u16*   Aq   = (u16*)alloc((size_t)CTX * DM * 2);
    u16*   Akv  = (u16*)alloc((size_t)CTX * DM * 2);
    float* ftab = (float*)alloc((size_t)CTX * 64 * 2 * 4);
    u16*   Qf   = (u16*)alloc((size_t)CTX * DM * 2);
    u16*   Kf   = (u16*)alloc((size_t)CTX * DM * 2);
    u16*   vTB  = (u16*)alloc((size_t)CTX * DM * 2);
    u16*   qnB  = (u16*)alloc((size_t)CTX * DM * 2);
    u16*   knB  = (u16*)alloc((size_t)CTX * DM * 2);
    u16*   aB   = (u16*)alloc((size_t)CTX * DM * 2);
    u16*   oprt = (u16*)alloc((size_t)2 * CTX * DM * 2);
    (void)ws_size; (void)in_sizes; (void)n_in; (void)out_size;

    transpose_all_kernel<<<dim3(DM / 32, DM / 32, 4), dim3(32, 8), 0, stream>>>(
        Wq, Wo, Wkv, WqT, WoT, WkvT);

    ln_stats_kernel<<<CTX, 256, 0, stream>>>(x, qng, qnb, kng, knb, Aq, Akv, ftab);

    qkv_gemm256_kernel<<<dim3(192), 512, 0, stream>>>(
        Aq, Akv, WqT, WkvT, bq, bkv, Qf, Kf, vTB);

    const float qk_scale = 0.29730177875068026f;                       // 128^-0.25
    const float fold_q   = 0.08838834764831845f * 1.4426950408889634f; // 1/sqrt(128)*log2(e)
    rot_ln_kernel<<<CTX, 256, 0, stream>>>(
        Qf, Kf, ftab, lng, lnb, qnB, knB, qk_scale, fold_q);

    attn_kernel<<<dim3(CTX / 64, NH), 256, 0, stream>>>(qnB, knB, vTB, aB);

    gemm_split_kernel<<<dim3(CTX / 128, DM / 128, 2), 256, 0, stream>>>(aB, WoT, oprt, DM / 2);
    combine_kernel<<<(CTX * DM) / 2048, 256, 0, stream>>>(oprt, bo, out);
}

// Round 2
// 194.640 us; speedup vs baseline: 1.0473x; 1.0473x over previous
//
#include <hip/hip_runtime.h>
#include <stdint.h>
#include <math.h>

#define CTX 2048
#define DM  2048
#define NH  16
#define HD  128

typedef __attribute__((ext_vector_type(8))) short short8;   // 8 x bf16 (4 VGPRs)
typedef __attribute__((ext_vector_type(4))) float f32x4;    // MFMA acc
typedef unsigned short u16;

__device__ __forceinline__ u16 f2bf(float f) {
    unsigned u = __float_as_uint(f);
    unsigned r = u + 0x7fffu + ((u >> 16) & 1u);   // RTNE
    return (u16)(r >> 16);
}
__device__ __forceinline__ float bf2f(u16 h) {
    return __uint_as_float(((unsigned)h) << 16);
}

// Opaque LDS read: invisible to SIInsertWaitcnts' LDS-DMA alias tracking, so
// the compiler does NOT insert s_waitcnt vmcnt(0) before it (the per-phase
// drain that killed the previous version). Ordering vs global_load_lds is
// enforced manually via counted vmcnt + barriers. Rule #18: every consumer
// cluster is guarded by lgkmcnt(0) + sched_barrier(0).
__device__ __forceinline__ short8 ds_read_b128_o(const void* p) {
    short8 r;
    asm volatile("ds_read_b128 %0, %1"
                 : "=v"(r)
                 : "v"((const __attribute__((address_space(3))) void*)p));
    return r;
}

// ------- merged weight transpose + f32->bf16 (W[K][N] -> WT[N][K]), 4 slabs ---
__global__ __launch_bounds__(256)
void transpose_all_kernel(const float* __restrict__ Wq, const float* __restrict__ Wo,
                          const float* __restrict__ Wkv,
                          u16* __restrict__ WqT, u16* __restrict__ WoT, u16* __restrict__ WkvT)
{
    __shared__ float tile[32][33];
    int z = blockIdx.z;
    const float* S; u16* D; int nsrc, c0, r0;
    if (z == 0)      { S = Wq;  D = WqT;  nsrc = DM;     c0 = 0;  r0 = 0;    }
    else if (z == 1) { S = Wo;  D = WoT;  nsrc = DM;     c0 = 0;  r0 = 0;    }
    else if (z == 2) { S = Wkv; D = WkvT; nsrc = 2 * DM; c0 = 0;  r0 = 0;    }
    else             { S = Wkv; D = WkvT; nsrc = 2 * DM; c0 = DM; r0 = DM;   }
    int k0 = blockIdx.x * 32, n0 = blockIdx.y * 32;
    int tx = threadIdx.x, ty = threadIdx.y;          // 32 x 8
#pragma unroll
    for (int j = 0; j < 4; ++j) {
        int kk = ty + 8 * j;
        tile[kk][tx] = S[(size_t)(k0 + kk) * nsrc + c0 + n0 + tx];
    }
    __syncthreads();
#pragma unroll
    for (int j = 0; j < 4; ++j) {
        int nn = ty + 8 * j;
        D[(size_t)(r0 + n0 + nn) * DM + k0 + tx] = f2bf(tile[tx][nn]);
    }
}

// -------- LN stats + normalized A matrices (bf16) + rotary factor table -------
__global__ __launch_bounds__(256)
void ln_stats_kernel(const float* __restrict__ x,
                     const float* __restrict__ qg, const float* __restrict__ qb,
                     const float* __restrict__ kg, const float* __restrict__ kb,
                     u16* __restrict__ Aq, u16* __restrict__ Akv, float* __restrict__ ftab)
{
    int c = blockIdx.x, t = threadIdx.x;
    const float* row = x + (size_t)c * DM;
    float4 v0 = *(const float4*)(row + t * 8);
    float4 v1 = *(const float4*)(row + t * 8 + 4);
    float vals[8] = {v0.x, v0.y, v0.z, v0.w, v1.x, v1.y, v1.z, v1.w};
    float s = 0.f, ss = 0.f;
#pragma unroll
    for (int j = 0; j < 8; ++j) { s += vals[j]; ss += vals[j] * vals[j]; }
#pragma unroll
    for (int off = 32; off; off >>= 1) { s += __shfl_xor(s, off); ss += __shfl_xor(ss, off); }
    __shared__ float red[8];
    int w = t >> 6;
    if ((t & 63) == 0) { red[w] = s; red[4 + w] = ss; }
    __syncthreads();
    float st  = red[0] + red[1] + red[2] + red[3];
    float sst = red[4] + red[5] + red[6] + red[7];
    float mu   = st * (1.f / DM);
    float var  = sst * (1.f / DM) - mu * mu;
    float rstd = rsqrtf(var + 1e-5f);
    if (t < 64) {                         // rotary table, m folded in
        const float LT64 = 10.30895266f / 64.f;   // ln(30000)/64
        float m = sqrtf(sst);
        float sn, cs;
        sincosf((float)c * ((float)t * LT64), &sn, &cs);
        float2 wv = {m * cs, m * sn};
        *(float2*)(ftab + ((size_t)c * 64 + t) * 2) = wv;
    }
    short8 aq, akv;
#pragma unroll
    for (int j = 0; j < 8; ++j) {
        int d = t * 8 + j;
        float xh = (vals[j] - mu) * rstd;
        aq[j]  = (short)f2bf(xh * qg[d] + qb[d]);
        akv[j] = (short)f2bf(xh * kg[d] + kb[d]);
    }
    *(short8*)(Aq  + (size_t)c * DM + t * 8) = aq;
    *(short8*)(Akv + (size_t)c * DM + t * 8) = akv;
}

// ---------------- fused QKV projection GEMM -----------------------------------
// 256x256 tile, BK=64, 8 waves (2Mx4N), 4-phase K-tile schedule.
// v2 fixes: (a) fragment loads are opaque asm ds_read_b128 so the compiler's
// LDS-DMA alias tracking cannot insert per-phase vmcnt(0) drains; (b) uniform
// 2-tile lookahead: iteration kt stages ALL of tile kt+2 (B halves in P3 after
// B-reads retire, A halves in P4 after A-reads retire), end-of-iteration
// s_waitcnt vmcnt(8) leaves exactly tile kt+2's 8 loads in flight and forces
// tile kt+1 landed (issued a full iteration earlier -> HBM latency covered).
//
// Race audit:
//   P3 stage B(kt+2,*) overwrites B(kt): all B-reads issued P1/P2, each wave's
//     lgkmcnt(0) retires its own before P2's ending barrier -> safe.
//   P4 stage A(kt+2,*) overwrites A(kt): A-reads issued P1/P3, retired at P3's
//     lgkmcnt(0) + ending barrier -> safe.
//   Reads of tile kt+2 happen in iter kt+2 P1, after iter kt+1's vmcnt(8)
//     proved tile kt+2 landed -> safe.
__global__ __launch_bounds__(512, 2)
void qkv_gemm256_kernel(const u16* __restrict__ Aq, const u16* __restrict__ Akv,
                        const u16* __restrict__ WqT, const u16* __restrict__ WkvT,
                        const float* __restrict__ bq, const float* __restrict__ bkv,
                        u16* __restrict__ Qf, u16* __restrict__ Kf, u16* __restrict__ vT)
{
    __shared__ __align__(16) u16 As[2][2][128][64];   // [buf][half][row][col]
    __shared__ __align__(16) u16 Bs[2][2][128][64];

    constexpr int NT = DM / 64;                       // 32 K-tiles

    // XCD-aware swizzle: 192 blocks, 24 contiguous tiles per XCD (192 % 8 == 0)
    int lin = blockIdx.x;
    int swz = (lin & 7) * 24 + (lin >> 3);
    int mt  = swz & 7;          // M tile 0..7
    int ng  = swz >> 3;         // 0..23
    int seg = ng >> 3;          // 0:Q 1:K 2:V
    int nt  = ng & 7;           // N tile 0..7

    const u16* Amat; const u16* Bmat; const float* bias; u16* outp; bool rowbias;
    if (seg == 0) {
        Amat = Aq  + (size_t)mt * 256 * DM;
        Bmat = WqT + (size_t)nt * 256 * DM;
        bias = bq + nt * 256;
        outp = Qf + (size_t)mt * 256 * DM + nt * 256;
        rowbias = false;
    } else if (seg == 1) {
        Amat = Akv  + (size_t)mt * 256 * DM;
        Bmat = WkvT + (size_t)nt * 256 * DM;
        bias = bkv + nt * 256;
        outp = Kf + (size_t)mt * 256 * DM + nt * 256;
        rowbias = false;
    } else {
        Amat = WkvT + (size_t)(DM + mt * 256) * DM;   // V dims as GEMM rows
        Bmat = Akv  + (size_t)nt * 256 * DM;          // context as GEMM cols
        bias = bkv + DM + mt * 256;                   // per-row bias
        outp = vT + (size_t)mt * 256 * CTX + nt * 256;
        rowbias = true;
    }

    int tid = threadIdx.x;
    int wid = tid >> 6, l = tid & 63;
    int wr = wid >> 2, wc = wid & 3;                  // 2x4 wave grid
    int lhi = l >> 4, llo = l & 15;
    int srow  = l >> 3;                               // staging: row within 8-row group
    int sunit = (l & 7) ^ srow;                       // inverse-swizzled global 16B unit

    auto stageA = [&](int kt, int h) {
#pragma unroll
        for (int rd = 0; rd < 2; ++rd) {
            const u16* src = Amat + (size_t)(h * 128 + rd * 64 + wid * 8 + srow) * DM
                             + kt * 64 + sunit * 8;
            __builtin_amdgcn_global_load_lds((const __attribute__((address_space(1))) void*)src,
                (__attribute__((address_space(3))) void*)&As[kt & 1][h][rd * 64 + wid * 8][0],
                16, 0, 0);
        }
    };
    auto stageB = [&](int kt, int h) {
#pragma unroll
        for (int rd = 0; rd < 2; ++rd) {
            const u16* src = Bmat + (size_t)(h * 128 + rd * 64 + wid * 8 + srow) * DM
                             + kt * 64 + sunit * 8;
            __builtin_amdgcn_global_load_lds((const __attribute__((address_space(1))) void*)src,
                (__attribute__((address_space(3))) void*)&Bs[kt & 1][h][rd * 64 + wid * 8][0],
                16, 0, 0);
        }
    };

    f32x4 acc[8][4] = {};                 // 128 regs of accumulator
    short8 a[4][2];                       // 4 m-frags x 2 k-slices (reused mi0-3 / mi4-7)
    short8 b0[2][2], b1[2][2];            // ni0-1 / ni2-3
    int bhalf = wc >> 1, brow = (wc & 1) * 64;

    // prologue: tiles 0 and 1 fully staged (16 loads); enter loop with tile0
    // landed and tile1's 8 loads allowed in flight.
    stageA(0, 0); stageA(0, 1); stageB(0, 0); stageB(0, 1);
    stageA(1, 0); stageA(1, 1); stageB(1, 0); stageB(1, 1);
    asm volatile("s_waitcnt vmcnt(8)" ::: "memory");
    __builtin_amdgcn_s_barrier();

    for (int kt = 0; kt < NT; ++kt) {
        int buf = kt & 1;

        // ---------- P1: ds_read b0(ni0-1) + a(mi0-3) [12xb128]; MFMA q00
#pragma unroll
        for (int ni = 0; ni < 2; ++ni)
#pragma unroll
            for (int ks = 0; ks < 2; ++ks) {
                int r = brow + 16 * ni + llo;
                b0[ni][ks] = ds_read_b128_o(&Bs[buf][bhalf][r][((ks * 4 + lhi) ^ (llo & 7)) << 3]);
            }
#pragma unroll
        for (int mi = 0; mi < 4; ++mi)
#pragma unroll
            for (int ks = 0; ks < 2; ++ks) {
                int r = 16 * mi + llo;
                a[mi][ks] = ds_read_b128_o(&As[buf][wr][r][((ks * 4 + lhi) ^ (llo & 7)) << 3]);
            }
        __builtin_amdgcn_s_barrier();
        asm volatile("s_waitcnt lgkmcnt(0)" ::: "memory");
        __builtin_amdgcn_sched_barrier(0);
        __builtin_amdgcn_s_setprio(1);
#pragma unroll
        for (int ks = 0; ks < 2; ++ks)
#pragma unroll
            for (int mi = 0; mi < 4; ++mi)
#pragma unroll
                for (int ni = 0; ni < 2; ++ni)
                    acc[mi][ni] = __builtin_amdgcn_mfma_f32_16x16x32_bf16(
                        a[mi][ks], b0[ni][ks], acc[mi][ni], 0, 0, 0);
        __builtin_amdgcn_s_setprio(0);
        __builtin_amdgcn_s_barrier();

        // ---------- P2: ds_read b1(ni2-3) [4xb128]; MFMA q01
#pragma unroll
        for (int ni = 0; ni < 2; ++ni)
#pragma unroll
            for (int ks = 0; ks < 2; ++ks) {
                int r = brow + 16 * (2 + ni) + llo;
                b1[ni][ks] = ds_read_b128_o(&Bs[buf][bhalf][r][((ks * 4 + lhi) ^ (llo & 7)) << 3]);
            }
        __builtin_amdgcn_s_barrier();
        asm volatile("s_waitcnt lgkmcnt(0)" ::: "memory");
        __builtin_amdgcn_sched_barrier(0);
        __builtin_amdgcn_s_setprio(1);
#pragma unroll
        for (int ks = 0; ks < 2; ++ks)
#pragma unroll
            for (int mi = 0; mi < 4; ++mi)
#pragma unroll
                for (int ni = 0; ni < 2; ++ni)
                    acc[mi][2 + ni] = __builtin_amdgcn_mfma_f32_16x16x32_bf16(
                        a[mi][ks], b1[ni][ks], acc[mi][2 + ni], 0, 0, 0);
        __builtin_amdgcn_s_setprio(0);
        __builtin_amdgcn_s_barrier();

        // ---------- P3: ds_read a(mi4-7) [8xb128]; stage B(kt+2,0/1); MFMA q11
#pragma unroll
        for (int mi = 0; mi < 4; ++mi)
#pragma unroll
            for (int ks = 0; ks < 2; ++ks) {
                int r = 16 * (4 + mi) + llo;
                a[mi][ks] = ds_read_b128_o(&As[buf][wr][r][((ks * 4 + lhi) ^ (llo & 7)) << 3]);
            }
        if (kt + 2 < NT) { stageB(kt + 2, 0); stageB(kt + 2, 1); }
        __builtin_amdgcn_s_barrier();
        asm volatile("s_waitcnt lgkmcnt(0)" ::: "memory");
        __builtin_amdgcn_sched_barrier(0);
        __builtin_amdgcn_s_setprio(1);
#pragma unroll
        for (int ks = 0; ks < 2; ++ks)
#pragma unroll
            for (int mi = 0; mi < 4; ++mi)
#pragma unroll
                for (int ni = 0; ni < 2; ++ni)
                    acc[4 + mi][2 + ni] = __builtin_amdgcn_mfma_f32_16x16x32_bf16(
                        a[mi][ks], b1[ni][ks], acc[4 + mi][2 + ni], 0, 0, 0);
        __builtin_amdgcn_s_setprio(0);
        __builtin_amdgcn_s_barrier();

        // ---------- P4: stage A(kt+2,0/1); MFMA q10; counted vmcnt(8)
        if (kt + 2 < NT) { stageA(kt + 2, 0); stageA(kt + 2, 1); }
        __builtin_amdgcn_s_setprio(1);
#pragma unroll
        for (int ks = 0; ks < 2; ++ks)
#pragma unroll
            for (int mi = 0; mi < 4; ++mi)
#pragma unroll
                for (int ni = 0; ni < 2; ++ni)
                    acc[4 + mi][ni] = __builtin_amdgcn_mfma_f32_16x16x32_bf16(
                        a[mi][ks], b0[ni][ks], acc[4 + mi][ni], 0, 0, 0);
        __builtin_amdgcn_s_setprio(0);
        if (kt + 2 < NT)      { asm volatile("s_waitcnt vmcnt(8)" ::: "memory"); }
        else if (kt + 1 < NT) { asm volatile("s_waitcnt vmcnt(0)" ::: "memory"); }
        __builtin_amdgcn_s_barrier();
    }

    // ---------------- epilogue: bias + bf16 store ----------------------------
    int rbase = 128 * wr;
    int cbase = 64 * wc;
    if (!rowbias) {
#pragma unroll
        for (int ni = 0; ni < 4; ++ni) {
            float bv = bias[cbase + 16 * ni + llo];
#pragma unroll
            for (int mi = 0; mi < 8; ++mi)
#pragma unroll
                for (int rr = 0; rr < 4; ++rr) {
                    int gr = rbase + 16 * mi + 4 * lhi + rr;
                    outp[(size_t)gr * DM + cbase + 16 * ni + llo] = f2bf(acc[mi][ni][rr] + bv);
                }
        }
    } else {
#pragma unroll
        for (int mi = 0; mi < 8; ++mi)
#pragma unroll
            for (int rr = 0; rr < 4; ++rr) {
                int gr = rbase + 16 * mi + 4 * lhi + rr;
                float bv = bias[gr];
#pragma unroll
                for (int ni = 0; ni < 4; ++ni)
                    outp[(size_t)gr * CTX + cbase + 16 * ni + llo] = f2bf(acc[mi][ni][rr] + bv);
            }
    }
}

// -------- table-driven rotary + per-head LN (one block per token row) ---------
__global__ __launch_bounds__(256)
void rot_ln_kernel(const u16* __restrict__ Qf, const u16* __restrict__ Kf,
                   const float* __restrict__ ftab,
                   const float* __restrict__ g, const float* __restrict__ b,
                   u16* __restrict__ qnB, u16* __restrict__ knB,
                   float qk_scale, float fold_q)
{
    int c = blockIdx.x, t = threadIdx.x;
    int h  = t >> 4;
    int dl = (t & 15) * 8;
    const float* tab = ftab + ((size_t)c * 64 + (dl >> 1)) * 2;
    float fre[4], fim[4];
#pragma unroll
    for (int p = 0; p < 4; ++p) { fre[p] = tab[2 * p]; fim[p] = tab[2 * p + 1]; }
    float gv[8], bv2[8];
#pragma unroll
    for (int j = 0; j < 8; ++j) { gv[j] = g[dl + j]; bv2[j] = b[dl + j]; }

#pragma unroll
    for (int z = 0; z < 2; ++z) {
        const u16* src = z ? Kf : Qf;
        u16* dst = z ? knB : qnB;
        float fold = z ? 1.f : fold_q;
        short8 vv = *(const short8*)(src + (size_t)c * DM + t * 8);
        float o[8];
        float s = 0.f, ss = 0.f;
#pragma unroll
        for (int p = 0; p < 4; ++p) {
            float a  = bf2f((u16)vv[2 * p])     * qk_scale;
            float b2 = bf2f((u16)vv[2 * p + 1]) * qk_scale;
            float o0 = a * fre[p] - b2 * fim[p];
            float o1 = a * fim[p] + b2 * fre[p];
            o[2 * p] = o0; o[2 * p + 1] = o1;
            s += o0 + o1;
            ss += o0 * o0 + o1 * o1;
        }
#pragma unroll
        for (int off = 1; off < 16; off <<= 1) {
            s += __shfl_xor(s, off);
            ss += __shfl_xor(ss, off);
        }
        float mu   = s * (1.f / HD);
        float var  = ss * (1.f / HD) - mu * mu;
        float rstd = rsqrtf(var + 1e-5f);
        short8 r;
#pragma unroll
        for (int j = 0; j < 8; ++j)
            r[j] = (short)f2bf(((o[j] - mu) * rstd * gv[j] + bv2[j]) * fold);
        *(short8*)(dst + ((size_t)h * CTX + c) * HD + dl) = r;
    }
}

// ---------------- causal flash attention v4b ----------------------------------
__global__ __launch_bounds__(256, 2)
void attn_kernel(const u16* __restrict__ qn, const u16* __restrict__ kn,
                 const u16* __restrict__ vT, u16* __restrict__ aout)
{
    __shared__ __align__(16) u16 Kb[2][64][128];
    __shared__ __align__(16) u16 Vb[2][128][64];
    __shared__ __align__(16) u16 p_lds[4][16][72];

    int h  = blockIdx.y;
    int xs = blockIdx.x;
    int qb = (h >= 8) ? (31 - xs) : xs;   // CU load-balance pairing
    int q0 = qb * 64;
    int tid = threadIdx.x, w = tid >> 6, l = tid & 63;
    int lhi = l >> 4, llo = l & 15;

    const u16* qrow = qn + ((size_t)h * CTX + q0 + 16 * w + llo) * HD + 8 * lhi;
    short8 qf[4];
#pragma unroll
    for (int ks = 0; ks < 4; ++ks) qf[ks] = *(const short8*)(qrow + 32 * ks);

    auto stage = [&](int buf, int kv0) {
        int rb = 16 * w;
#pragma unroll
        for (int j = 0; j < 4; ++j) {
            int r = rb + 4 * j + (l >> 4);
            int csw = (l & 15) ^ (r & 15);
            const u16* src = kn + ((size_t)h * CTX + kv0 + r) * HD + (csw << 3);
            __builtin_amdgcn_global_load_lds((const __attribute__((address_space(1))) void*)src,
                (__attribute__((address_space(3))) void*)&Kb[buf][rb + 4 * j][0], 16, 0, 0);
        }
        int db = 32 * w;
#pragma unroll
        for (int j = 0; j < 4; ++j) {
            int d = db + 8 * j + (l >> 3);
            int csw = (l & 7) ^ (d & 7);
            const u16* src = vT + ((size_t)h * HD + d) * CTX + kv0 + (csw << 3);
            __builtin_amdgcn_global_load_lds((const __attribute__((address_space(1))) void*)src,
                (__attribute__((address_space(3))) void*)&Vb[buf][db + 8 * j][0], 16, 0, 0);
        }
    };

    float m_s = -1e30f, l_p = 0.f;
    f32x4 o_acc[8];
#pragma unroll
    for (int ni = 0; ni < 8; ++ni) o_acc[ni] = (f32x4){0.f, 0.f, 0.f, 0.f};

    stage(0, 0);
    __syncthreads();

    int cur = 0;
    for (int jt = 0; jt <= qb; ++jt) {
        if (jt < qb) stage(cur ^ 1, (jt + 1) * 64);   // prefetch overlaps compute

        f32x4 sacc[4] = {};
        __builtin_amdgcn_s_setprio(1);
#pragma unroll
        for (int ks = 0; ks < 4; ++ks) {
#pragma unroll
            for (int ni = 0; ni < 4; ++ni) {
                short8 kf = *(const short8*)&Kb[cur][16 * ni + llo][((4 * ks + lhi) ^ llo) << 3];
                sacc[ni] = __builtin_amdgcn_mfma_f32_16x16x32_bf16(kf, qf[ks], sacc[ni], 0, 0, 0);
            }
        }
        __builtin_amdgcn_s_setprio(0);

        if (jt == qb) {                  // causal mask inside diagonal tile
            int qloc = 16 * w + llo;
#pragma unroll
            for (int ni = 0; ni < 4; ++ni)
#pragma unroll
                for (int r = 0; r < 4; ++r)
                    if (16 * ni + 4 * lhi + r > qloc) sacc[ni][r] = -INFINITY;
        }

        // speculative P with OLD running max (no cross-lane wait)
        float pv[16];
#pragma unroll
        for (int ni = 0; ni < 4; ++ni)
#pragma unroll
            for (int r = 0; r < 4; ++r) pv[4 * ni + r] = exp2f(sacc[ni][r] - m_s);

        // per-lane local max only; __any supplies the cross-lane OR
        float mx = sacc[0][0];
#pragma unroll
        for (int ni = 0; ni < 4; ++ni)
#pragma unroll
            for (int r = 0; r < 4; ++r) mx = fmaxf(mx, sacc[ni][r]);

        if (__any(mx > m_s + 8.f)) {     // rare path: full reduce + rescale
            mx = fmaxf(mx, __shfl_xor(mx, 16));
            mx = fmaxf(mx, __shfl_xor(mx, 32));
            float mnew = fmaxf(m_s, mx);
            float fac = exp2f(m_s - mnew);
#pragma unroll
            for (int r = 0; r < 4; ++r) {
                float fr = __shfl(fac, 4 * lhi + r);
#pragma unroll
                for (int ni = 0; ni < 8; ++ni) o_acc[ni][r] *= fr;
            }
#pragma unroll
            for (int ni = 0; ni < 4; ++ni)
#pragma unroll
                for (int r = 0; r < 4; ++r) pv[4 * ni + r] = exp2f(sacc[ni][r] - mnew);
            l_p *= fac;
            m_s = mnew;
        }

        // pack P -> p_lds
#pragma unroll
        for (int ni = 0; ni < 4; ++ni)
#pragma unroll
            for (int hf = 0; hf < 2; ++hf) {
                unsigned pk;
                asm("v_cvt_pk_bf16_f32 %0, %1, %2" : "=v"(pk)
                    : "v"(pv[4 * ni + 2 * hf]), "v"(pv[4 * ni + 2 * hf + 1]));
                *(unsigned*)&p_lds[w][llo][16 * ni + 4 * lhi + 2 * hf] = pk;
            }

        // deferred l: per-lane partial only (cross-lane reduce in epilogue)
        float ps = 0.f;
#pragma unroll
        for (int j = 0; j < 16; ++j) ps += pv[j];
        l_p += ps;

        // O += P . V
        __builtin_amdgcn_s_setprio(1);
#pragma unroll
        for (int ks = 0; ks < 2; ++ks) {
            short8 pa = *(const short8*)&p_lds[w][llo][32 * ks + 8 * lhi];
#pragma unroll
            for (int ni = 0; ni < 8; ++ni) {
                short8 vf = *(const short8*)&Vb[cur][16 * ni + llo][((4 * ks + lhi) ^ (llo & 7)) << 3];
                o_acc[ni] = __builtin_amdgcn_mfma_f32_16x16x32_bf16(pa, vf, o_acc[ni], 0, 0, 0);
            }
        }
        __builtin_amdgcn_s_setprio(0);

        __syncthreads();   // drains prefetch vmcnt + frees buf[cur]
        cur ^= 1;
    }

    float lsum = l_p;
    lsum += __shfl_xor(lsum, 16);
    lsum += __shfl_xor(lsum, 32);
#pragma unroll
    for (int r = 0; r < 4; ++r) {
        float lr  = __shfl(lsum, 4 * lhi + r);
        float inv = 1.f / lr;
        int qrow2 = q0 + 16 * w + 4 * lhi + r;
#pragma unroll
        for (int ni = 0; ni < 8; ++ni)
            aout[(size_t)qrow2 * DM + h * HD + 16 * ni + llo] = f2bf(o_acc[ni][r] * inv);
    }
}

// ---------------- O-projection GEMM, split-K, bf16 partials -------------------
__global__ __launch_bounds__(256, 2)
void gemm_split_kernel(const u16* __restrict__ A, const u16* __restrict__ BT,
                       u16* __restrict__ outp, int klen)
{
    __shared__ __align__(16) u16 At[128][32];
    __shared__ __align__(16) u16 Bt[128][32];
    int tid = threadIdx.x;
    int w = tid >> 6, l = tid & 63;
    int wr = w >> 1, wc = w & 1;
    int m0 = blockIdx.x * 128, n0 = blockIdx.y * 128;
    int koff = blockIdx.z * klen;
    int lhi = l >> 4, llo = l & 15;
    f32x4 acc[4][4] = {};
    outp += (size_t)blockIdx.z * CTX * DM;

    int srow = l >> 2, scol = (l & 3) * 8;
    for (int k0 = koff; k0 < koff + klen; k0 += 32) {
#pragma unroll
        for (int j = 0; j < 2; ++j) {
            int r = 32 * w + 16 * j;
            const void* ga = A  + (size_t)(m0 + r + srow) * DM + k0 + scol;
            const void* gb = BT + (size_t)(n0 + r + srow) * DM + k0 + scol;
            __builtin_amdgcn_global_load_lds((const __attribute__((address_space(1))) void*)ga,
                                             (__attribute__((address_space(3))) void*)&At[r][0], 16, 0, 0);
            __builtin_amdgcn_global_load_lds((const __attribute__((address_space(1))) void*)gb,
                                             (__attribute__((address_space(3))) void*)&Bt[r][0], 16, 0, 0);
        }
        __syncthreads();
        short8 a[4];
#pragma unroll
        for (int mi = 0; mi < 4; ++mi)
            a[mi] = *(const short8*)&At[64 * wr + 16 * mi + llo][lhi * 8];
#pragma unroll
        for (int ni = 0; ni < 4; ++ni) {
            short8 b = *(const short8*)&Bt[64 * wc + 16 * ni + llo][lhi * 8];
#pragma unroll
            for (int mi = 0; mi < 4; ++mi)
                acc[mi][ni] = __builtin_amdgcn_mfma_f32_16x16x32_bf16(a[mi], b, acc[mi][ni], 0, 0, 0);
        }
        __syncthreads();
    }
#pragma unroll
    for (int ni = 0; ni < 4; ++ni) {
        int gc = n0 + 64 * wc + 16 * ni + llo;
#pragma unroll
        for (int mi = 0; mi < 4; ++mi)
#pragma unroll
            for (int rr = 0; rr < 4; ++rr) {
                int gr = m0 + 64 * wr + 16 * mi + lhi * 4 + rr;
                outp[(size_t)gr * DM + gc] = f2bf(acc[mi][ni][rr]);
            }
    }
}

// ---------------- combine bf16 split-K partials + bias ------------------------
__global__ __launch_bounds__(256)
void combine_kernel(const u16* __restrict__ p, const float* __restrict__ bias,
                    float* __restrict__ out)
{
    size_t i = ((size_t)blockIdx.x * 256 + threadIdx.x) * 8;
    short8 a = *(const short8*)(p + i);
    short8 b = *(const short8*)(p + (size_t)CTX * DM + i);
    int dbase = (int)(i & (DM - 1));
    float4 bv0 = *(const float4*)(bias + dbase);
    float4 bv1 = *(const float4*)(bias + dbase + 4);
    float r[8];
    float bvv[8] = {bv0.x, bv0.y, bv0.z, bv0.w, bv1.x, bv1.y, bv1.z, bv1.w};
#pragma unroll
    for (int j = 0; j < 8; ++j)
        r[j] = bf2f((u16)a[j]) + bf2f((u16)b[j]) + bvv[j];
    *(float4*)(out + i)     = (float4){r[0], r[1], r[2], r[3]};
    *(float4*)(out + i + 4) = (float4){r[4], r[5], r[6], r[7]};
}

// ------------------------------- launcher ------------------------------------
extern "C" void kernel_launch(void* const* d_in, const int* in_sizes, int n_in,
                              void* d_out, int out_size, void* d_ws, size_t ws_size,
                              hipStream_t stream)
{
    const float* x   = (const float*)d_in[0];
    const float* qng = (const float*)d_in[1];
    const float* qnb = (const float*)d_in[2];
    const float* kng = (const float*)d_in[3];
    const float* knb = (const float*)d_in[4];
    const float* Wq  = (const float*)d_in[5];
    const float* bq  = (const float*)d_in[6];
    const float* Wkv = (const float*)d_in[7];
    const float* bkv = (const float*)d_in[8];
    const float* Wo  = (const float*)d_in[9];
    const float* bo  = (const float*)d_in[10];
    const float* lng = (const float*)d_in[11];
    const float* lnb = (const float*)d_in[12];
    float* out = (float*)d_out;

    uint8_t* ws = (uint8_t*)d_ws;
    size_t off = 0;
    auto alloc = [&](size_t bytes) -> void* {
        void* p = ws + off;
        off += (bytes + 255) & ~(size_t)255;
        return p;
    };
    u16*   WqT  = (u16*)alloc((size_t)DM * DM * 2);
    u16*   WkvT = (u16*)alloc((size_t)2 * DM * DM * 2);
    u16*   WoT  = (u16*)alloc((size_t)DM * DM * 2);
    u16*   Aq   = (u16*)alloc((size_t)CTX * DM * 2);
    u16*   Akv  = (u16*)alloc((size_t)CTX * DM * 2);
    float* ftab = (float*)alloc((size_t)CTX * 64 * 2 * 4);
    u16*   Qf   = (u16*)alloc((size_t)CTX * DM * 2);
    u16*   Kf   = (u16*)alloc((size_t)CTX * DM * 2);
    u16*   vTB  = (u16*)alloc((size_t)CTX * DM * 2);
    u16*   qnB  = (u16*)alloc((size_t)CTX * DM * 2);
    u16*   knB  = (u16*)alloc((size_t)CTX * DM * 2);
    u16*   aB   = (u16*)alloc((size_t)CTX * DM * 2);
    u16*   oprt = (u16*)alloc((size_t)2 * CTX * DM * 2);
    (void)ws_size; (void)in_sizes; (void)n_in; (void)out_size;

    transpose_all_kernel<<<dim3(DM / 32, DM / 32, 4), dim3(32, 8), 0, stream>>>(
        Wq, Wo, Wkv, WqT, WoT, WkvT);

    ln_stats_kernel<<<CTX, 256, 0, stream>>>(x, qng, qnb, kng, knb, Aq, Akv, ftab);

    qkv_gemm256_kernel<<<dim3(192), 512, 0, stream>>>(
        Aq, Akv, WqT, WkvT, bq, bkv, Qf, Kf, vTB);

    const float qk_scale = 0.29730177875068026f;                       // 128^-0.25
    const float fold_q   = 0.08838834764831845f * 1.4426950408889634f; // 1/sqrt(128)*log2(e)
    rot_ln_kernel<<<CTX, 256, 0, stream>>>(
        Qf, Kf, ftab, lng, lnb, qnB, knB, qk_scale, fold_q);

    attn_kernel<<<dim3(CTX / 64, NH), 256, 0, stream>>>(qnB, knB, vTB, aB);

    gemm_split_kernel<<<dim3(CTX / 128, DM / 128, 2), 256, 0, stream>>>(aB, WoT, oprt, DM / 2);
    combine_kernel<<<(CTX * DM) / 2048, 256, 0, stream>>>(oprt, bo, out);
}

// Round 3
// 191.707 us; speedup vs baseline: 1.0633x; 1.0153x over previous
//
#include <hip/hip_runtime.h>
#include <stdint.h>
#include <math.h>

#define CTX 2048
#define DM  2048
#define NH  16
#define HD  128

typedef __attribute__((ext_vector_type(8))) short short8;   // 8 x bf16 (4 VGPRs)
typedef __attribute__((ext_vector_type(4))) float f32x4;    // MFMA acc
typedef unsigned short u16;

__device__ __forceinline__ u16 f2bf(float f) {
    unsigned u = __float_as_uint(f);
    unsigned r = u + 0x7fffu + ((u >> 16) & 1u);   // RTNE
    return (u16)(r >> 16);
}
__device__ __forceinline__ float bf2f(u16 h) {
    return __uint_as_float(((unsigned)h) << 16);
}

// Opaque LDS read: invisible to SIInsertWaitcnts' LDS-DMA alias tracking, so
// the compiler cannot insert vmcnt(0) drains before it. Ordering enforced
// manually: counted lgkmcnt + sched_barrier(0) before every consumer (rule #18).
__device__ __forceinline__ short8 ds_read_b128_o(const void* p) {
    short8 r;
    asm volatile("ds_read_b128 %0, %1"
                 : "=v"(r)
                 : "v"((const __attribute__((address_space(3))) void*)p));
    return r;
}

// ------- merged weight transpose + f32->bf16 (W[K][N] -> WT[N][K]), 4 slabs ---
__global__ __launch_bounds__(256)
void transpose_all_kernel(const float* __restrict__ Wq, const float* __restrict__ Wo,
                          const float* __restrict__ Wkv,
                          u16* __restrict__ WqT, u16* __restrict__ WoT, u16* __restrict__ WkvT)
{
    __shared__ float tile[32][33];
    int z = blockIdx.z;
    const float* S; u16* D; int nsrc, c0, r0;
    if (z == 0)      { S = Wq;  D = WqT;  nsrc = DM;     c0 = 0;  r0 = 0;    }
    else if (z == 1) { S = Wo;  D = WoT;  nsrc = DM;     c0 = 0;  r0 = 0;    }
    else if (z == 2) { S = Wkv; D = WkvT; nsrc = 2 * DM; c0 = 0;  r0 = 0;    }
    else             { S = Wkv; D = WkvT; nsrc = 2 * DM; c0 = DM; r0 = DM;   }
    int k0 = blockIdx.x * 32, n0 = blockIdx.y * 32;
    int tx = threadIdx.x, ty = threadIdx.y;          // 32 x 8
#pragma unroll
    for (int j = 0; j < 4; ++j) {
        int kk = ty + 8 * j;
        tile[kk][tx] = S[(size_t)(k0 + kk) * nsrc + c0 + n0 + tx];
    }
    __syncthreads();
#pragma unroll
    for (int j = 0; j < 4; ++j) {
        int nn = ty + 8 * j;
        D[(size_t)(r0 + n0 + nn) * DM + k0 + tx] = f2bf(tile[tx][nn]);
    }
}

// -------- LN stats + normalized A matrices (bf16) + rotary factor table -------
__global__ __launch_bounds__(256)
void ln_stats_kernel(const float* __restrict__ x,
                     const float* __restrict__ qg, const float* __restrict__ qb,
                     const float* __restrict__ kg, const float* __restrict__ kb,
                     u16* __restrict__ Aq, u16* __restrict__ Akv, float* __restrict__ ftab)
{
    int c = blockIdx.x, t = threadIdx.x;
    const float* row = x + (size_t)c * DM;
    float4 v0 = *(const float4*)(row + t * 8);
    float4 v1 = *(const float4*)(row + t * 8 + 4);
    float vals[8] = {v0.x, v0.y, v0.z, v0.w, v1.x, v1.y, v1.z, v1.w};
    float s = 0.f, ss = 0.f;
#pragma unroll
    for (int j = 0; j < 8; ++j) { s += vals[j]; ss += vals[j] * vals[j]; }
#pragma unroll
    for (int off = 32; off; off >>= 1) { s += __shfl_xor(s, off); ss += __shfl_xor(ss, off); }
    __shared__ float red[8];
    int w = t >> 6;
    if ((t & 63) == 0) { red[w] = s; red[4 + w] = ss; }
    __syncthreads();
    float st  = red[0] + red[1] + red[2] + red[3];
    float sst = red[4] + red[5] + red[6] + red[7];
    float mu   = st * (1.f / DM);
    float var  = sst * (1.f / DM) - mu * mu;
    float rstd = rsqrtf(var + 1e-5f);
    if (t < 64) {                         // rotary table, m folded in
        const float LT64 = 10.30895266f / 64.f;   // ln(30000)/64
        float m = sqrtf(sst);
        float sn, cs;
        sincosf((float)c * ((float)t * LT64), &sn, &cs);
        float2 wv = {m * cs, m * sn};
        *(float2*)(ftab + ((size_t)c * 64 + t) * 2) = wv;
    }
    short8 aq, akv;
#pragma unroll
    for (int j = 0; j < 8; ++j) {
        int d = t * 8 + j;
        float xh = (vals[j] - mu) * rstd;
        aq[j]  = (short)f2bf(xh * qg[d] + qb[d]);
        akv[j] = (short)f2bf(xh * kg[d] + kb[d]);
    }
    *(short8*)(Aq  + (size_t)c * DM + t * 8) = aq;
    *(short8*)(Akv + (size_t)c * DM + t * 8) = akv;
}

// ---------------- fused QKV projection GEMM -----------------------------------
// 256x256 tile, BK=64, 8 waves (2Mx4N). v3: minimal-barrier schedule.
// Only 3 barriers/iteration (down from 7); counted lgkmcnt(4) overlaps the q00
// MFMA with the tail b1 reads. Correctness audit:
//   barrier #1: every wave executed lgkmcnt(0) before its q01 MFMA, so at the
//     barrier ALL waves' B-reads (b0,b1) and a03-reads of buf are retired ->
//     stageB(kt+2) into Bs[buf] after it is race-free.
//   barrier #2: every wave's a47 reads retired (lgkmcnt(0) pre-q11) ->
//     stageA(kt+2) into As[buf] after it is race-free.
//   vmcnt(8)+barrier #3: 8 newest VMEM ops = this iter's 8 stage loads
//     (tile kt+2); everything older (tile kt+1, issued last iter) has landed
//     in ALL waves before anyone reads buf^1 next iteration.
//   lgkm counting is exact: global_load_lds is vmcnt-only, so the only lgkm
//     ops are our 16 ds_reads per iteration, none crossing iterations.
__global__ __launch_bounds__(512, 2)
void qkv_gemm256_kernel(const u16* __restrict__ Aq, const u16* __restrict__ Akv,
                        const u16* __restrict__ WqT, const u16* __restrict__ WkvT,
                        const float* __restrict__ bq, const float* __restrict__ bkv,
                        u16* __restrict__ Qf, u16* __restrict__ Kf, u16* __restrict__ vT)
{
    __shared__ __align__(16) u16 As[2][2][128][64];   // [buf][half][row][col]
    __shared__ __align__(16) u16 Bs[2][2][128][64];

    constexpr int NT = DM / 64;                       // 32 K-tiles

    // XCD-aware swizzle: 192 blocks, 24 contiguous tiles per XCD (192 % 8 == 0)
    int lin = blockIdx.x;
    int swz = (lin & 7) * 24 + (lin >> 3);
    int mt  = swz & 7;          // M tile 0..7
    int ng  = swz >> 3;         // 0..23
    int seg = ng >> 3;          // 0:Q 1:K 2:V
    int nt  = ng & 7;           // N tile 0..7

    const u16* Amat; const u16* Bmat; const float* bias; u16* outp; bool rowbias;
    if (seg == 0) {
        Amat = Aq  + (size_t)mt * 256 * DM;
        Bmat = WqT + (size_t)nt * 256 * DM;
        bias = bq + nt * 256;
        outp = Qf + (size_t)mt * 256 * DM + nt * 256;
        rowbias = false;
    } else if (seg == 1) {
        Amat = Akv  + (size_t)mt * 256 * DM;
        Bmat = WkvT + (size_t)nt * 256 * DM;
        bias = bkv + nt * 256;
        outp = Kf + (size_t)mt * 256 * DM + nt * 256;
        rowbias = false;
    } else {
        Amat = WkvT + (size_t)(DM + mt * 256) * DM;   // V dims as GEMM rows
        Bmat = Akv  + (size_t)nt * 256 * DM;          // context as GEMM cols
        bias = bkv + DM + mt * 256;                   // per-row bias
        outp = vT + (size_t)mt * 256 * CTX + nt * 256;
        rowbias = true;
    }

    int tid = threadIdx.x;
    int wid = tid >> 6, l = tid & 63;
    int wr = wid >> 2, wc = wid & 3;                  // 2x4 wave grid
    int lhi = l >> 4, llo = l & 15;
    int srow  = l >> 3;                               // staging: row within 8-row group
    int sunit = (l & 7) ^ srow;                       // inverse-swizzled global 16B unit

    auto stageA = [&](int kt, int h) {
#pragma unroll
        for (int rd = 0; rd < 2; ++rd) {
            const u16* src = Amat + (size_t)(h * 128 + rd * 64 + wid * 8 + srow) * DM
                             + kt * 64 + sunit * 8;
            __builtin_amdgcn_global_load_lds((const __attribute__((address_space(1))) void*)src,
                (__attribute__((address_space(3))) void*)&As[kt & 1][h][rd * 64 + wid * 8][0],
                16, 0, 0);
        }
    };
    auto stageB = [&](int kt, int h) {
#pragma unroll
        for (int rd = 0; rd < 2; ++rd) {
            const u16* src = Bmat + (size_t)(h * 128 + rd * 64 + wid * 8 + srow) * DM
                             + kt * 64 + sunit * 8;
            __builtin_amdgcn_global_load_lds((const __attribute__((address_space(1))) void*)src,
                (__attribute__((address_space(3))) void*)&Bs[kt & 1][h][rd * 64 + wid * 8][0],
                16, 0, 0);
        }
    };

    f32x4 acc[8][4] = {};                 // 128 regs of accumulator
    short8 a[4][2];                       // 4 m-frags x 2 k-slices (reused mi0-3 / mi4-7)
    short8 b0[2][2], b1[2][2];            // ni0-1 / ni2-3
    int bhalf = wc >> 1, brow = (wc & 1) * 64;

    // prologue: tiles 0 and 1 fully staged (16 loads); enter loop with tile0
    // landed and tile1's 8 loads allowed in flight.
    stageA(0, 0); stageA(0, 1); stageB(0, 0); stageB(0, 1);
    stageA(1, 0); stageA(1, 1); stageB(1, 0); stageB(1, 1);
    asm volatile("s_waitcnt vmcnt(8)" ::: "memory");
    __builtin_amdgcn_s_barrier();

    for (int kt = 0; kt < NT; ++kt) {
        int buf = kt & 1;

        // ---- reads: b0 (4) + a03 (8) + b1 (4), issued back-to-back ----------
#pragma unroll
        for (int ni = 0; ni < 2; ++ni)
#pragma unroll
            for (int ks = 0; ks < 2; ++ks) {
                int r = brow + 16 * ni + llo;
                b0[ni][ks] = ds_read_b128_o(&Bs[buf][bhalf][r][((ks * 4 + lhi) ^ (llo & 7)) << 3]);
            }
#pragma unroll
        for (int mi = 0; mi < 4; ++mi)
#pragma unroll
            for (int ks = 0; ks < 2; ++ks) {
                int r = 16 * mi + llo;
                a[mi][ks] = ds_read_b128_o(&As[buf][wr][r][((ks * 4 + lhi) ^ (llo & 7)) << 3]);
            }
#pragma unroll
        for (int ni = 0; ni < 2; ++ni)
#pragma unroll
            for (int ks = 0; ks < 2; ++ks) {
                int r = brow + 16 * (2 + ni) + llo;
                b1[ni][ks] = ds_read_b128_o(&Bs[buf][bhalf][r][((ks * 4 + lhi) ^ (llo & 7)) << 3]);
            }

        // ---- q00 as soon as b0+a03 land (b1's 4 reads may still be in flight)
        asm volatile("s_waitcnt lgkmcnt(4)" ::: "memory");
        __builtin_amdgcn_sched_barrier(0);
        __builtin_amdgcn_s_setprio(1);
#pragma unroll
        for (int ks = 0; ks < 2; ++ks)
#pragma unroll
            for (int mi = 0; mi < 4; ++mi)
#pragma unroll
                for (int ni = 0; ni < 2; ++ni)
                    acc[mi][ni] = __builtin_amdgcn_mfma_f32_16x16x32_bf16(
                        a[mi][ks], b0[ni][ks], acc[mi][ni], 0, 0, 0);
        __builtin_amdgcn_s_setprio(0);

        // ---- q01 ------------------------------------------------------------
        asm volatile("s_waitcnt lgkmcnt(0)" ::: "memory");
        __builtin_amdgcn_sched_barrier(0);
        __builtin_amdgcn_s_setprio(1);
#pragma unroll
        for (int ks = 0; ks < 2; ++ks)
#pragma unroll
            for (int mi = 0; mi < 4; ++mi)
#pragma unroll
                for (int ni = 0; ni < 2; ++ni)
                    acc[mi][2 + ni] = __builtin_amdgcn_mfma_f32_16x16x32_bf16(
                        a[mi][ks], b1[ni][ks], acc[mi][2 + ni], 0, 0, 0);
        __builtin_amdgcn_s_setprio(0);

        __builtin_amdgcn_s_barrier();   // #1: all waves' B- and a03-reads retired

        // ---- stage B(kt+2) into Bs[buf] (now free); read a47 ----------------
        if (kt + 2 < NT) { stageB(kt + 2, 0); stageB(kt + 2, 1); }
#pragma unroll
        for (int mi = 0; mi < 4; ++mi)
#pragma unroll
            for (int ks = 0; ks < 2; ++ks) {
                int r = 16 * (4 + mi) + llo;
                a[mi][ks] = ds_read_b128_o(&As[buf][wr][r][((ks * 4 + lhi) ^ (llo & 7)) << 3]);
            }

        // ---- q11 ------------------------------------------------------------
        asm volatile("s_waitcnt lgkmcnt(0)" ::: "memory");
        __builtin_amdgcn_sched_barrier(0);
        __builtin_amdgcn_s_setprio(1);
#pragma unroll
        for (int ks = 0; ks < 2; ++ks)
#pragma unroll
            for (int mi = 0; mi < 4; ++mi)
#pragma unroll
                for (int ni = 0; ni < 2; ++ni)
                    acc[4 + mi][2 + ni] = __builtin_amdgcn_mfma_f32_16x16x32_bf16(
                        a[mi][ks], b1[ni][ks], acc[4 + mi][2 + ni], 0, 0, 0);
        __builtin_amdgcn_s_setprio(0);

        __builtin_amdgcn_s_barrier();   // #2: all waves' A-reads retired

        // ---- stage A(kt+2) into As[buf]; q10 from registers -----------------
        if (kt + 2 < NT) { stageA(kt + 2, 0); stageA(kt + 2, 1); }
        __builtin_amdgcn_s_setprio(1);
#pragma unroll
        for (int ks = 0; ks < 2; ++ks)
#pragma unroll
            for (int mi = 0; mi < 4; ++mi)
#pragma unroll
                for (int ni = 0; ni < 2; ++ni)
                    acc[4 + mi][ni] = __builtin_amdgcn_mfma_f32_16x16x32_bf16(
                        a[mi][ks], b0[ni][ks], acc[4 + mi][ni], 0, 0, 0);
        __builtin_amdgcn_s_setprio(0);

        // ---- counted vmcnt: keep tile kt+2's 8 loads in flight --------------
        if (kt + 2 < NT)      { asm volatile("s_waitcnt vmcnt(8)" ::: "memory"); }
        else if (kt + 1 < NT) { asm volatile("s_waitcnt vmcnt(0)" ::: "memory"); }
        __builtin_amdgcn_s_barrier();   // #3: tile kt+1 landed for everyone
    }

    // ---------------- epilogue: bias + bf16 store ----------------------------
    int rbase = 128 * wr;
    int cbase = 64 * wc;
    if (!rowbias) {
#pragma unroll
        for (int ni = 0; ni < 4; ++ni) {
            float bv = bias[cbase + 16 * ni + llo];
#pragma unroll
            for (int mi = 0; mi < 8; ++mi)
#pragma unroll
                for (int rr = 0; rr < 4; ++rr) {
                    int gr = rbase + 16 * mi + 4 * lhi + rr;
                    outp[(size_t)gr * DM + cbase + 16 * ni + llo] = f2bf(acc[mi][ni][rr] + bv);
                }
        }
    } else {
#pragma unroll
        for (int mi = 0; mi < 8; ++mi)
#pragma unroll
            for (int rr = 0; rr < 4; ++rr) {
                int gr = rbase + 16 * mi + 4 * lhi + rr;
                float bv = bias[gr];
#pragma unroll
                for (int ni = 0; ni < 4; ++ni)
                    outp[(size_t)gr * CTX + cbase + 16 * ni + llo] = f2bf(acc[mi][ni][rr] + bv);
            }
    }
}

// -------- table-driven rotary + per-head LN (one block per token row) ---------
__global__ __launch_bounds__(256)
void rot_ln_kernel(const u16* __restrict__ Qf, const u16* __restrict__ Kf,
                   const float* __restrict__ ftab,
                   const float* __restrict__ g, const float* __restrict__ b,
                   u16* __restrict__ qnB, u16* __restrict__ knB,
                   float qk_scale, float fold_q)
{
    int c = blockIdx.x, t = threadIdx.x;
    int h  = t >> 4;
    int dl = (t & 15) * 8;
    const float* tab = ftab + ((size_t)c * 64 + (dl >> 1)) * 2;
    float fre[4], fim[4];
#pragma unroll
    for (int p = 0; p < 4; ++p) { fre[p] = tab[2 * p]; fim[p] = tab[2 * p + 1]; }
    float gv[8], bv2[8];
#pragma unroll
    for (int j = 0; j < 8; ++j) { gv[j] = g[dl + j]; bv2[j] = b[dl + j]; }

#pragma unroll
    for (int z = 0; z < 2; ++z) {
        const u16* src = z ? Kf : Qf;
        u16* dst = z ? knB : qnB;
        float fold = z ? 1.f : fold_q;
        short8 vv = *(const short8*)(src + (size_t)c * DM + t * 8);
        float o[8];
        float s = 0.f, ss = 0.f;
#pragma unroll
        for (int p = 0; p < 4; ++p) {
            float a  = bf2f((u16)vv[2 * p])     * qk_scale;
            float b2 = bf2f((u16)vv[2 * p + 1]) * qk_scale;
            float o0 = a * fre[p] - b2 * fim[p];
            float o1 = a * fim[p] + b2 * fre[p];
            o[2 * p] = o0; o[2 * p + 1] = o1;
            s += o0 + o1;
            ss += o0 * o0 + o1 * o1;
        }
#pragma unroll
        for (int off = 1; off < 16; off <<= 1) {
            s += __shfl_xor(s, off);
            ss += __shfl_xor(ss, off);
        }
        float mu   = s * (1.f / HD);
        float var  = ss * (1.f / HD) - mu * mu;
        float rstd = rsqrtf(var + 1e-5f);
        short8 r;
#pragma unroll
        for (int j = 0; j < 8; ++j)
            r[j] = (short)f2bf(((o[j] - mu) * rstd * gv[j] + bv2[j]) * fold);
        *(short8*)(dst + ((size_t)h * CTX + c) * HD + dl) = r;
    }
}

// ---------------- causal flash attention v4b ----------------------------------
__global__ __launch_bounds__(256, 2)
void attn_kernel(const u16* __restrict__ qn, const u16* __restrict__ kn,
                 const u16* __restrict__ vT, u16* __restrict__ aout)
{
    __shared__ __align__(16) u16 Kb[2][64][128];
    __shared__ __align__(16) u16 Vb[2][128][64];
    __shared__ __align__(16) u16 p_lds[4][16][72];

    int h  = blockIdx.y;
    int xs = blockIdx.x;
    int qb = (h >= 8) ? (31 - xs) : xs;   // CU load-balance pairing
    int q0 = qb * 64;
    int tid = threadIdx.x, w = tid >> 6, l = tid & 63;
    int lhi = l >> 4, llo = l & 15;

    const u16* qrow = qn + ((size_t)h * CTX + q0 + 16 * w + llo) * HD + 8 * lhi;
    short8 qf[4];
#pragma unroll
    for (int ks = 0; ks < 4; ++ks) qf[ks] = *(const short8*)(qrow + 32 * ks);

    auto stage = [&](int buf, int kv0) {
        int rb = 16 * w;
#pragma unroll
        for (int j = 0; j < 4; ++j) {
            int r = rb + 4 * j + (l >> 4);
            int csw = (l & 15) ^ (r & 15);
            const u16* src = kn + ((size_t)h * CTX + kv0 + r) * HD + (csw << 3);
            __builtin_amdgcn_global_load_lds((const __attribute__((address_space(1))) void*)src,
                (__attribute__((address_space(3))) void*)&Kb[buf][rb + 4 * j][0], 16, 0, 0);
        }
        int db = 32 * w;
#pragma unroll
        for (int j = 0; j < 4; ++j) {
            int d = db + 8 * j + (l >> 3);
            int csw = (l & 7) ^ (d & 7);
            const u16* src = vT + ((size_t)h * HD + d) * CTX + kv0 + (csw << 3);
            __builtin_amdgcn_global_load_lds((const __attribute__((address_space(1))) void*)src,
                (__attribute__((address_space(3))) void*)&Vb[buf][db + 8 * j][0], 16, 0, 0);
        }
    };

    float m_s = -1e30f, l_p = 0.f;
    f32x4 o_acc[8];
#pragma unroll
    for (int ni = 0; ni < 8; ++ni) o_acc[ni] = (f32x4){0.f, 0.f, 0.f, 0.f};

    stage(0, 0);
    __syncthreads();

    int cur = 0;
    for (int jt = 0; jt <= qb; ++jt) {
        if (jt < qb) stage(cur ^ 1, (jt + 1) * 64);   // prefetch overlaps compute

        f32x4 sacc[4] = {};
        __builtin_amdgcn_s_setprio(1);
#pragma unroll
        for (int ks = 0; ks < 4; ++ks) {
#pragma unroll
            for (int ni = 0; ni < 4; ++ni) {
                short8 kf = *(const short8*)&Kb[cur][16 * ni + llo][((4 * ks + lhi) ^ llo) << 3];
                sacc[ni] = __builtin_amdgcn_mfma_f32_16x16x32_bf16(kf, qf[ks], sacc[ni], 0, 0, 0);
            }
        }
        __builtin_amdgcn_s_setprio(0);

        if (jt == qb) {                  // causal mask inside diagonal tile
            int qloc = 16 * w + llo;
#pragma unroll
            for (int ni = 0; ni < 4; ++ni)
#pragma unroll
                for (int r = 0; r < 4; ++r)
                    if (16 * ni + 4 * lhi + r > qloc) sacc[ni][r] = -INFINITY;
        }

        // speculative P with OLD running max (no cross-lane wait)
        float pv[16];
#pragma unroll
        for (int ni = 0; ni < 4; ++ni)
#pragma unroll
            for (int r = 0; r < 4; ++r) pv[4 * ni + r] = exp2f(sacc[ni][r] - m_s);

        // per-lane local max only; __any supplies the cross-lane OR
        float mx = sacc[0][0];
#pragma unroll
        for (int ni = 0; ni < 4; ++ni)
#pragma unroll
            for (int r = 0; r < 4; ++r) mx = fmaxf(mx, sacc[ni][r]);

        if (__any(mx > m_s + 8.f)) {     // rare path: full reduce + rescale
            mx = fmaxf(mx, __shfl_xor(mx, 16));
            mx = fmaxf(mx, __shfl_xor(mx, 32));
            float mnew = fmaxf(m_s, mx);
            float fac = exp2f(m_s - mnew);
#pragma unroll
            for (int r = 0; r < 4; ++r) {
                float fr = __shfl(fac, 4 * lhi + r);
#pragma unroll
                for (int ni = 0; ni < 8; ++ni) o_acc[ni][r] *= fr;
            }
#pragma unroll
            for (int ni = 0; ni < 4; ++ni)
#pragma unroll
                for (int r = 0; r < 4; ++r) pv[4 * ni + r] = exp2f(sacc[ni][r] - mnew);
            l_p *= fac;
            m_s = mnew;
        }

        // pack P -> p_lds
#pragma unroll
        for (int ni = 0; ni < 4; ++ni)
#pragma unroll
            for (int hf = 0; hf < 2; ++hf) {
                unsigned pk;
                asm("v_cvt_pk_bf16_f32 %0, %1, %2" : "=v"(pk)
                    : "v"(pv[4 * ni + 2 * hf]), "v"(pv[4 * ni + 2 * hf + 1]));
                *(unsigned*)&p_lds[w][llo][16 * ni + 4 * lhi + 2 * hf] = pk;
            }

        // deferred l: per-lane partial only (cross-lane reduce in epilogue)
        float ps = 0.f;
#pragma unroll
        for (int j = 0; j < 16; ++j) ps += pv[j];
        l_p += ps;

        // O += P . V
        __builtin_amdgcn_s_setprio(1);
#pragma unroll
        for (int ks = 0; ks < 2; ++ks) {
            short8 pa = *(const short8*)&p_lds[w][llo][32 * ks + 8 * lhi];
#pragma unroll
            for (int ni = 0; ni < 8; ++ni) {
                short8 vf = *(const short8*)&Vb[cur][16 * ni + llo][((4 * ks + lhi) ^ (llo & 7)) << 3];
                o_acc[ni] = __builtin_amdgcn_mfma_f32_16x16x32_bf16(pa, vf, o_acc[ni], 0, 0, 0);
            }
        }
        __builtin_amdgcn_s_setprio(0);

        __syncthreads();   // drains prefetch vmcnt + frees buf[cur]
        cur ^= 1;
    }

    float lsum = l_p;
    lsum += __shfl_xor(lsum, 16);
    lsum += __shfl_xor(lsum, 32);
#pragma unroll
    for (int r = 0; r < 4; ++r) {
        float lr  = __shfl(lsum, 4 * lhi + r);
        float inv = 1.f / lr;
        int qrow2 = q0 + 16 * w + 4 * lhi + r;
#pragma unroll
        for (int ni = 0; ni < 8; ++ni)
            aout[(size_t)qrow2 * DM + h * HD + 16 * ni + llo] = f2bf(o_acc[ni][r] * inv);
    }
}

// ---------------- O-projection GEMM, split-K, bf16 partials -------------------
__global__ __launch_bounds__(256, 2)
void gemm_split_kernel(const u16* __restrict__ A, const u16* __restrict__ BT,
                       u16* __restrict__ outp, int klen)
{
    __shared__ __align__(16) u16 At[128][32];
    __shared__ __align__(16) u16 Bt[128][32];
    int tid = threadIdx.x;
    int w = tid >> 6, l = tid & 63;
    int wr = w >> 1, wc = w & 1;
    int m0 = blockIdx.x * 128, n0 = blockIdx.y * 128;
    int koff = blockIdx.z * klen;
    int lhi = l >> 4, llo = l & 15;
    f32x4 acc[4][4] = {};
    outp += (size_t)blockIdx.z * CTX * DM;

    int srow = l >> 2, scol = (l & 3) * 8;
    for (int k0 = koff; k0 < koff + klen; k0 += 32) {
#pragma unroll
        for (int j = 0; j < 2; ++j) {
            int r = 32 * w + 16 * j;
            const void* ga = A  + (size_t)(m0 + r + srow) * DM + k0 + scol;
            const void* gb = BT + (size_t)(n0 + r + srow) * DM + k0 + scol;
            __builtin_amdgcn_global_load_lds((const __attribute__((address_space(1))) void*)ga,
                                             (__attribute__((address_space(3))) void*)&At[r][0], 16, 0, 0);
            __builtin_amdgcn_global_load_lds((const __attribute__((address_space(1))) void*)gb,
                                             (__attribute__((address_space(3))) void*)&Bt[r][0], 16, 0, 0);
        }
        __syncthreads();
        short8 a[4];
#pragma unroll
        for (int mi = 0; mi < 4; ++mi)
            a[mi] = *(const short8*)&At[64 * wr + 16 * mi + llo][lhi * 8];
#pragma unroll
        for (int ni = 0; ni < 4; ++ni) {
            short8 b = *(const short8*)&Bt[64 * wc + 16 * ni + llo][lhi * 8];
#pragma unroll
            for (int mi = 0; mi < 4; ++mi)
                acc[mi][ni] = __builtin_amdgcn_mfma_f32_16x16x32_bf16(a[mi], b, acc[mi][ni], 0, 0, 0);
        }
        __syncthreads();
    }
#pragma unroll
    for (int ni = 0; ni < 4; ++ni) {
        int gc = n0 + 64 * wc + 16 * ni + llo;
#pragma unroll
        for (int mi = 0; mi < 4; ++mi)
#pragma unroll
            for (int rr = 0; rr < 4; ++rr) {
                int gr = m0 + 64 * wr + 16 * mi + lhi * 4 + rr;
                outp[(size_t)gr * DM + gc] = f2bf(acc[mi][ni][rr]);
            }
    }
}

// ---------------- combine bf16 split-K partials + bias ------------------------
__global__ __launch_bounds__(256)
void combine_kernel(const u16* __restrict__ p, const float* __restrict__ bias,
                    float* __restrict__ out)
{
    size_t i = ((size_t)blockIdx.x * 256 + threadIdx.x) * 8;
    short8 a = *(const short8*)(p + i);
    short8 b = *(const short8*)(p + (size_t)CTX * DM + i);
    int dbase = (int)(i & (DM - 1));
    float4 bv0 = *(const float4*)(bias + dbase);
    float4 bv1 = *(const float4*)(bias + dbase + 4);
    float r[8];
    float bvv[8] = {bv0.x, bv0.y, bv0.z, bv0.w, bv1.x, bv1.y, bv1.z, bv1.w};
#pragma unroll
    for (int j = 0; j < 8; ++j)
        r[j] = bf2f((u16)a[j]) + bf2f((u16)b[j]) + bvv[j];
    *(float4*)(out + i)     = (float4){r[0], r[1], r[2], r[3]};
    *(float4*)(out + i + 4) = (float4){r[4], r[5], r[6], r[7]};
}

// ------------------------------- launcher ------------------------------------
extern "C" void kernel_launch(void* const* d_in, const int* in_sizes, int n_in,
                              void* d_out, int out_size, void* d_ws, size_t ws_size,
                              hipStream_t stream)
{
    const float* x   = (const float*)d_in[0];
    const float* qng = (const float*)d_in[1];
    const float* qnb = (const float*)d_in[2];
    const float* kng = (const float*)d_in[3];
    const float* knb = (const float*)d_in[4];
    const float* Wq  = (const float*)d_in[5];
    const float* bq  = (const float*)d_in[6];
    const float* Wkv = (const float*)d_in[7];
    const float* bkv = (const float*)d_in[8];
    const float* Wo  = (const float*)d_in[9];
    const float* bo  = (const float*)d_in[10];
    const float* lng = (const float*)d_in[11];
    const float* lnb = (const float*)d_in[12];
    float* out = (float*)d_out;

    uint8_t* ws = (uint8_t*)d_ws;
    size_t off = 0;
    auto alloc = [&](size_t bytes) -> void* {
        void* p = ws + off;
        off += (bytes + 255) & ~(size_t)255;
        return p;
    };
    u16*   WqT  = (u16*)alloc((size_t)DM * DM * 2);
    u16*   WkvT = (u16*)alloc((size_t)2 * DM * DM * 2);
    u16*   WoT  = (u16*)alloc((size_t)DM * DM * 2);
    u16*   Aq   = (u16*)alloc((size_t)CTX * DM * 2);
    u16*   Akv  = (u16*)alloc((size_t)CTX * DM * 2);
    float* ftab = (float*)alloc((size_t)CTX * 64 * 2 * 4);
    u16*   Qf   = (u16*)alloc((size_t)CTX * DM * 2);
    u16*   Kf   = (u16*)alloc((size_t)CTX * DM * 2);
    u16*   vTB  = (u16*)alloc((size_t)CTX * DM * 2);
    u16*   qnB  = (u16*)alloc((size_t)CTX * DM * 2);
    u16*   knB  = (u16*)alloc((size_t)CTX * DM * 2);
    u16*   aB   = (u16*)alloc((size_t)CTX * DM * 2);
    u16*   oprt = (u16*)alloc((size_t)2 * CTX * DM * 2);
    (void)ws_size; (void)in_sizes; (void)n_in; (void)out_size;

    transpose_all_kernel<<<dim3(DM / 32, DM / 32, 4), dim3(32, 8), 0, stream>>>(
        Wq, Wo, Wkv, WqT, WoT, WkvT);

    ln_stats_kernel<<<CTX, 256, 0, stream>>>(x, qng, qnb, kng, knb, Aq, Akv, ftab);

    qkv_gemm256_kernel<<<dim3(192), 512, 0, stream>>>(
        Aq, Akv, WqT, WkvT, bq, bkv, Qf, Kf, vTB);

    const float qk_scale = 0.29730177875068026f;                       // 128^-0.25
    const float fold_q   = 0.08838834764831845f * 1.4426950408889634f; // 1/sqrt(128)*log2(e)
    rot_ln_kernel<<<CTX, 256, 0, stream>>>(
        Qf, Kf, ftab, lng, lnb, qnB, knB, qk_scale, fold_q);

    attn_kernel<<<dim3(CTX / 64, NH), 256, 0, stream>>>(qnB, knB, vTB, aB);

    gemm_split_kernel<<<dim3(CTX / 128, DM / 128, 2), 256, 0, stream>>>(aB, WoT, oprt, DM / 2);
    combine_kernel<<<(CTX * DM) / 2048, 256, 0, stream>>>(oprt, bo, out);
}

// Round 4
// 191.353 us; speedup vs baseline: 1.0653x; 1.0018x over previous
//
#include <hip/hip_runtime.h>
#include <stdint.h>
#include <math.h>

#define CTX 2048
#define DM  2048
#define NH  16
#define HD  128

typedef __attribute__((ext_vector_type(8))) short short8;   // 8 x bf16 (4 VGPRs)
typedef __attribute__((ext_vector_type(4))) float f32x4;    // MFMA acc
typedef unsigned short u16;

__device__ __forceinline__ u16 f2bf(float f) {
    unsigned u = __float_as_uint(f);
    unsigned r = u + 0x7fffu + ((u >> 16) & 1u);   // RTNE
    return (u16)(r >> 16);
}
__device__ __forceinline__ float bf2f(u16 h) {
    return __uint_as_float(((unsigned)h) << 16);
}

// Opaque LDS read: invisible to SIInsertWaitcnts' LDS-DMA alias tracking, so
// the compiler cannot insert vmcnt(0) drains before it. Ordering enforced
// manually: counted lgkmcnt + sched_barrier(0) before every consumer (rule #18).
__device__ __forceinline__ short8 ds_read_b128_o(const void* p) {
    short8 r;
    asm volatile("ds_read_b128 %0, %1"
                 : "=v"(r)
                 : "v"((const __attribute__((address_space(3))) void*)p));
    return r;
}

// ------- merged weight transpose + f32->bf16 (W[K][N] -> WT[N][K]), 4 slabs ---
__global__ __launch_bounds__(256)
void transpose_all_kernel(const float* __restrict__ Wq, const float* __restrict__ Wo,
                          const float* __restrict__ Wkv,
                          u16* __restrict__ WqT, u16* __restrict__ WoT, u16* __restrict__ WkvT)
{
    __shared__ float tile[32][33];
    int z = blockIdx.z;
    const float* S; u16* D; int nsrc, c0, r0;
    if (z == 0)      { S = Wq;  D = WqT;  nsrc = DM;     c0 = 0;  r0 = 0;    }
    else if (z == 1) { S = Wo;  D = WoT;  nsrc = DM;     c0 = 0;  r0 = 0;    }
    else if (z == 2) { S = Wkv; D = WkvT; nsrc = 2 * DM; c0 = 0;  r0 = 0;    }
    else             { S = Wkv; D = WkvT; nsrc = 2 * DM; c0 = DM; r0 = DM;   }
    int k0 = blockIdx.x * 32, n0 = blockIdx.y * 32;
    int tx = threadIdx.x, ty = threadIdx.y;          // 32 x 8
#pragma unroll
    for (int j = 0; j < 4; ++j) {
        int kk = ty + 8 * j;
        tile[kk][tx] = S[(size_t)(k0 + kk) * nsrc + c0 + n0 + tx];
    }
    __syncthreads();
#pragma unroll
    for (int j = 0; j < 4; ++j) {
        int nn = ty + 8 * j;
        D[(size_t)(r0 + n0 + nn) * DM + k0 + tx] = f2bf(tile[tx][nn]);
    }
}

// -------- LN stats + normalized A matrices (bf16) + rotary factor table -------
__global__ __launch_bounds__(256)
void ln_stats_kernel(const float* __restrict__ x,
                     const float* __restrict__ qg, const float* __restrict__ qb,
                     const float* __restrict__ kg, const float* __restrict__ kb,
                     u16* __restrict__ Aq, u16* __restrict__ Akv, float* __restrict__ ftab)
{
    int c = blockIdx.x, t = threadIdx.x;
    const float* row = x + (size_t)c * DM;
    float4 v0 = *(const float4*)(row + t * 8);
    float4 v1 = *(const float4*)(row + t * 8 + 4);
    float vals[8] = {v0.x, v0.y, v0.z, v0.w, v1.x, v1.y, v1.z, v1.w};
    float s = 0.f, ss = 0.f;
#pragma unroll
    for (int j = 0; j < 8; ++j) { s += vals[j]; ss += vals[j] * vals[j]; }
#pragma unroll
    for (int off = 32; off; off >>= 1) { s += __shfl_xor(s, off); ss += __shfl_xor(ss, off); }
    __shared__ float red[8];
    int w = t >> 6;
    if ((t & 63) == 0) { red[w] = s; red[4 + w] = ss; }
    __syncthreads();
    float st  = red[0] + red[1] + red[2] + red[3];
    float sst = red[4] + red[5] + red[6] + red[7];
    float mu   = st * (1.f / DM);
    float var  = sst * (1.f / DM) - mu * mu;
    float rstd = rsqrtf(var + 1e-5f);
    if (t < 64) {                         // rotary table, m folded in
        const float LT64 = 10.30895266f / 64.f;   // ln(30000)/64
        float m = sqrtf(sst);
        float sn, cs;
        sincosf((float)c * ((float)t * LT64), &sn, &cs);
        float2 wv = {m * cs, m * sn};
        *(float2*)(ftab + ((size_t)c * 64 + t) * 2) = wv;
    }
    short8 aq, akv;
#pragma unroll
    for (int j = 0; j < 8; ++j) {
        int d = t * 8 + j;
        float xh = (vals[j] - mu) * rstd;
        aq[j]  = (short)f2bf(xh * qg[d] + qb[d]);
        akv[j] = (short)f2bf(xh * kg[d] + kb[d]);
    }
    *(short8*)(Aq  + (size_t)c * DM + t * 8) = aq;
    *(short8*)(Akv + (size_t)c * DM + t * 8) = akv;
}

// ---------------- fused QKV projection GEMM -----------------------------------
// 256x256 tile, BK=64, 8 waves (2Mx4N). v3 minimal-barrier schedule (proven
// 64us / passing). See round-2 race audit in comments below.
__global__ __launch_bounds__(512, 2)
void qkv_gemm256_kernel(const u16* __restrict__ Aq, const u16* __restrict__ Akv,
                        const u16* __restrict__ WqT, const u16* __restrict__ WkvT,
                        const float* __restrict__ bq, const float* __restrict__ bkv,
                        u16* __restrict__ Qf, u16* __restrict__ Kf, u16* __restrict__ vT)
{
    __shared__ __align__(16) u16 As[2][2][128][64];   // [buf][half][row][col]
    __shared__ __align__(16) u16 Bs[2][2][128][64];

    constexpr int NT = DM / 64;                       // 32 K-tiles

    // XCD-aware swizzle: 192 blocks, 24 contiguous tiles per XCD (192 % 8 == 0)
    int lin = blockIdx.x;
    int swz = (lin & 7) * 24 + (lin >> 3);
    int mt  = swz & 7;          // M tile 0..7
    int ng  = swz >> 3;         // 0..23
    int seg = ng >> 3;          // 0:Q 1:K 2:V
    int nt  = ng & 7;           // N tile 0..7

    const u16* Amat; const u16* Bmat; const float* bias; u16* outp; bool rowbias;
    if (seg == 0) {
        Amat = Aq  + (size_t)mt * 256 * DM;
        Bmat = WqT + (size_t)nt * 256 * DM;
        bias = bq + nt * 256;
        outp = Qf + (size_t)mt * 256 * DM + nt * 256;
        rowbias = false;
    } else if (seg == 1) {
        Amat = Akv  + (size_t)mt * 256 * DM;
        Bmat = WkvT + (size_t)nt * 256 * DM;
        bias = bkv + nt * 256;
        outp = Kf + (size_t)mt * 256 * DM + nt * 256;
        rowbias = false;
    } else {
        Amat = WkvT + (size_t)(DM + mt * 256) * DM;   // V dims as GEMM rows
        Bmat = Akv  + (size_t)nt * 256 * DM;          // context as GEMM cols
        bias = bkv + DM + mt * 256;                   // per-row bias
        outp = vT + (size_t)mt * 256 * CTX + nt * 256;
        rowbias = true;
    }

    int tid = threadIdx.x;
    int wid = tid >> 6, l = tid & 63;
    int wr = wid >> 2, wc = wid & 3;                  // 2x4 wave grid
    int lhi = l >> 4, llo = l & 15;
    int srow  = l >> 3;                               // staging: row within 8-row group
    int sunit = (l & 7) ^ srow;                       // inverse-swizzled global 16B unit

    auto stageA = [&](int kt, int h) {
#pragma unroll
        for (int rd = 0; rd < 2; ++rd) {
            const u16* src = Amat + (size_t)(h * 128 + rd * 64 + wid * 8 + srow) * DM
                             + kt * 64 + sunit * 8;
            __builtin_amdgcn_global_load_lds((const __attribute__((address_space(1))) void*)src,
                (__attribute__((address_space(3))) void*)&As[kt & 1][h][rd * 64 + wid * 8][0],
                16, 0, 0);
        }
    };
    auto stageB = [&](int kt, int h) {
#pragma unroll
        for (int rd = 0; rd < 2; ++rd) {
            const u16* src = Bmat + (size_t)(h * 128 + rd * 64 + wid * 8 + srow) * DM
                             + kt * 64 + sunit * 8;
            __builtin_amdgcn_global_load_lds((const __attribute__((address_space(1))) void*)src,
                (__attribute__((address_space(3))) void*)&Bs[kt & 1][h][rd * 64 + wid * 8][0],
                16, 0, 0);
        }
    };

    f32x4 acc[8][4] = {};                 // 128 regs of accumulator
    short8 a[4][2];                       // 4 m-frags x 2 k-slices (reused mi0-3 / mi4-7)
    short8 b0[2][2], b1[2][2];            // ni0-1 / ni2-3
    int bhalf = wc >> 1, brow = (wc & 1) * 64;

    // prologue: tiles 0 and 1 fully staged (16 loads)
    stageA(0, 0); stageA(0, 1); stageB(0, 0); stageB(0, 1);
    stageA(1, 0); stageA(1, 1); stageB(1, 0); stageB(1, 1);
    asm volatile("s_waitcnt vmcnt(8)" ::: "memory");
    __builtin_amdgcn_s_barrier();

    for (int kt = 0; kt < NT; ++kt) {
        int buf = kt & 1;

        // ---- reads: b0 (4) + a03 (8) + b1 (4), issued back-to-back ----------
#pragma unroll
        for (int ni = 0; ni < 2; ++ni)
#pragma unroll
            for (int ks = 0; ks < 2; ++ks) {
                int r = brow + 16 * ni + llo;
                b0[ni][ks] = ds_read_b128_o(&Bs[buf][bhalf][r][((ks * 4 + lhi) ^ (llo & 7)) << 3]);
            }
#pragma unroll
        for (int mi = 0; mi < 4; ++mi)
#pragma unroll
            for (int ks = 0; ks < 2; ++ks) {
                int r = 16 * mi + llo;
                a[mi][ks] = ds_read_b128_o(&As[buf][wr][r][((ks * 4 + lhi) ^ (llo & 7)) << 3]);
            }
#pragma unroll
        for (int ni = 0; ni < 2; ++ni)
#pragma unroll
            for (int ks = 0; ks < 2; ++ks) {
                int r = brow + 16 * (2 + ni) + llo;
                b1[ni][ks] = ds_read_b128_o(&Bs[buf][bhalf][r][((ks * 4 + lhi) ^ (llo & 7)) << 3]);
            }

        // ---- q00 as soon as b0+a03 land (b1's 4 reads may still be in flight)
        asm volatile("s_waitcnt lgkmcnt(4)" ::: "memory");
        __builtin_amdgcn_sched_barrier(0);
        __builtin_amdgcn_s_setprio(1);
#pragma unroll
        for (int ks = 0; ks < 2; ++ks)
#pragma unroll
            for (int mi = 0; mi < 4; ++mi)
#pragma unroll
                for (int ni = 0; ni < 2; ++ni)
                    acc[mi][ni] = __builtin_amdgcn_mfma_f32_16x16x32_bf16(
                        a[mi][ks], b0[ni][ks], acc[mi][ni], 0, 0, 0);
        __builtin_amdgcn_s_setprio(0);

        // ---- q01 ------------------------------------------------------------
        asm volatile("s_waitcnt lgkmcnt(0)" ::: "memory");
        __builtin_amdgcn_sched_barrier(0);
        __builtin_amdgcn_s_setprio(1);
#pragma unroll
        for (int ks = 0; ks < 2; ++ks)
#pragma unroll
            for (int mi = 0; mi < 4; ++mi)
#pragma unroll
                for (int ni = 0; ni < 2; ++ni)
                    acc[mi][2 + ni] = __builtin_amdgcn_mfma_f32_16x16x32_bf16(
                        a[mi][ks], b1[ni][ks], acc[mi][2 + ni], 0, 0, 0);
        __builtin_amdgcn_s_setprio(0);

        __builtin_amdgcn_s_barrier();   // #1: all waves' B- and a03-reads retired

        // ---- stage B(kt+2) into Bs[buf] (now free); read a47 ----------------
        if (kt + 2 < NT) { stageB(kt + 2, 0); stageB(kt + 2, 1); }
#pragma unroll
        for (int mi = 0; mi < 4; ++mi)
#pragma unroll
            for (int ks = 0; ks < 2; ++ks) {
                int r = 16 * (4 + mi) + llo;
                a[mi][ks] = ds_read_b128_o(&As[buf][wr][r][((ks * 4 + lhi) ^ (llo & 7)) << 3]);
            }

        // ---- q11 ------------------------------------------------------------
        asm volatile("s_waitcnt lgkmcnt(0)" ::: "memory");
        __builtin_amdgcn_sched_barrier(0);
        __builtin_amdgcn_s_setprio(1);
#pragma unroll
        for (int ks = 0; ks < 2; ++ks)
#pragma unroll
            for (int mi = 0; mi < 4; ++mi)
#pragma unroll
                for (int ni = 0; ni < 2; ++ni)
                    acc[4 + mi][2 + ni] = __builtin_amdgcn_mfma_f32_16x16x32_bf16(
                        a[mi][ks], b1[ni][ks], acc[4 + mi][2 + ni], 0, 0, 0);
        __builtin_amdgcn_s_setprio(0);

        __builtin_amdgcn_s_barrier();   // #2: all waves' A-reads retired

        // ---- stage A(kt+2) into As[buf]; q10 from registers -----------------
        if (kt + 2 < NT) { stageA(kt + 2, 0); stageA(kt + 2, 1); }
        __builtin_amdgcn_s_setprio(1);
#pragma unroll
        for (int ks = 0; ks < 2; ++ks)
#pragma unroll
            for (int mi = 0; mi < 4; ++mi)
#pragma unroll
                for (int ni = 0; ni < 2; ++ni)
                    acc[4 + mi][ni] = __builtin_amdgcn_mfma_f32_16x16x32_bf16(
                        a[mi][ks], b0[ni][ks], acc[4 + mi][ni], 0, 0, 0);
        __builtin_amdgcn_s_setprio(0);

        // ---- counted vmcnt: keep tile kt+2's 8 loads in flight --------------
        if (kt + 2 < NT)      { asm volatile("s_waitcnt vmcnt(8)" ::: "memory"); }
        else if (kt + 1 < NT) { asm volatile("s_waitcnt vmcnt(0)" ::: "memory"); }
        __builtin_amdgcn_s_barrier();   // #3: tile kt+1 landed for everyone
    }

    // ---------------- epilogue: bias + bf16 store ----------------------------
    int rbase = 128 * wr;
    int cbase = 64 * wc;
    if (!rowbias) {
#pragma unroll
        for (int ni = 0; ni < 4; ++ni) {
            float bv = bias[cbase + 16 * ni + llo];
#pragma unroll
            for (int mi = 0; mi < 8; ++mi)
#pragma unroll
                for (int rr = 0; rr < 4; ++rr) {
                    int gr = rbase + 16 * mi + 4 * lhi + rr;
                    outp[(size_t)gr * DM + cbase + 16 * ni + llo] = f2bf(acc[mi][ni][rr] + bv);
                }
        }
    } else {
#pragma unroll
        for (int mi = 0; mi < 8; ++mi)
#pragma unroll
            for (int rr = 0; rr < 4; ++rr) {
                int gr = rbase + 16 * mi + 4 * lhi + rr;
                float bv = bias[gr];
#pragma unroll
                for (int ni = 0; ni < 4; ++ni)
                    outp[(size_t)gr * CTX + cbase + 16 * ni + llo] = f2bf(acc[mi][ni][rr] + bv);
            }
    }
}

// ---------------- O-projection GEMM: 256^2 tile, 4-way split-K ----------------
// Same proven v3 schedule as qkv_gemm256; NT=8 (K=512 per split), 256 blocks
// (8 M x 8 N x 4 Kz) = exact CU fill. 256^2 tiles quarter the A/B re-read
// traffic vs the old 128^2 gemm_split (256MB -> 128MB through L2/L3), which
// was the binding constraint. Writes bf16 partials; combine4 adds bias.
__global__ __launch_bounds__(512, 2)
void oproj_gemm256_kernel(const u16* __restrict__ A, const u16* __restrict__ BT,
                          u16* __restrict__ outp)
{
    __shared__ __align__(16) u16 As[2][2][128][64];
    __shared__ __align__(16) u16 Bs[2][2][128][64];

    constexpr int NT = 8;                             // 8 K-tiles = 512 deep

    // XCD swizzle: 256 blocks, 32 contiguous per XCD (256 % 8 == 0, bijective)
    int lin = blockIdx.x;
    int swz = (lin & 7) * 32 + (lin >> 3);
    int kz  = swz >> 6;          // K split 0..3
    int rem = swz & 63;
    int mt  = rem & 7;
    int nt  = rem >> 3;

    const u16* Amat = A  + (size_t)mt * 256 * DM + kz * 512;
    const u16* Bmat = BT + (size_t)nt * 256 * DM + kz * 512;
    u16* out = outp + (size_t)kz * CTX * DM + (size_t)mt * 256 * DM + nt * 256;

    int tid = threadIdx.x;
    int wid = tid >> 6, l = tid & 63;
    int wr = wid >> 2, wc = wid & 3;
    int lhi = l >> 4, llo = l & 15;
    int srow  = l >> 3;
    int sunit = (l & 7) ^ srow;

    auto stageA = [&](int kt, int h) {
#pragma unroll
        for (int rd = 0; rd < 2; ++rd) {
            const u16* src = Amat + (size_t)(h * 128 + rd * 64 + wid * 8 + srow) * DM
                             + kt * 64 + sunit * 8;
            __builtin_amdgcn_global_load_lds((const __attribute__((address_space(1))) void*)src,
                (__attribute__((address_space(3))) void*)&As[kt & 1][h][rd * 64 + wid * 8][0],
                16, 0, 0);
        }
    };
    auto stageB = [&](int kt, int h) {
#pragma unroll
        for (int rd = 0; rd < 2; ++rd) {
            const u16* src = Bmat + (size_t)(h * 128 + rd * 64 + wid * 8 + srow) * DM
                             + kt * 64 + sunit * 8;
            __builtin_amdgcn_global_load_lds((const __attribute__((address_space(1))) void*)src,
                (__attribute__((address_space(3))) void*)&Bs[kt & 1][h][rd * 64 + wid * 8][0],
                16, 0, 0);
        }
    };

    f32x4 acc[8][4] = {};
    short8 a[4][2];
    short8 b0[2][2], b1[2][2];
    int bhalf = wc >> 1, brow = (wc & 1) * 64;

    stageA(0, 0); stageA(0, 1); stageB(0, 0); stageB(0, 1);
    stageA(1, 0); stageA(1, 1); stageB(1, 0); stageB(1, 1);
    asm volatile("s_waitcnt vmcnt(8)" ::: "memory");
    __builtin_amdgcn_s_barrier();

    for (int kt = 0; kt < NT; ++kt) {
        int buf = kt & 1;

#pragma unroll
        for (int ni = 0; ni < 2; ++ni)
#pragma unroll
            for (int ks = 0; ks < 2; ++ks) {
                int r = brow + 16 * ni + llo;
                b0[ni][ks] = ds_read_b128_o(&Bs[buf][bhalf][r][((ks * 4 + lhi) ^ (llo & 7)) << 3]);
            }
#pragma unroll
        for (int mi = 0; mi < 4; ++mi)
#pragma unroll
            for (int ks = 0; ks < 2; ++ks) {
                int r = 16 * mi + llo;
                a[mi][ks] = ds_read_b128_o(&As[buf][wr][r][((ks * 4 + lhi) ^ (llo & 7)) << 3]);
            }
#pragma unroll
        for (int ni = 0; ni < 2; ++ni)
#pragma unroll
            for (int ks = 0; ks < 2; ++ks) {
                int r = brow + 16 * (2 + ni) + llo;
                b1[ni][ks] = ds_read_b128_o(&Bs[buf][bhalf][r][((ks * 4 + lhi) ^ (llo & 7)) << 3]);
            }

        asm volatile("s_waitcnt lgkmcnt(4)" ::: "memory");
        __builtin_amdgcn_sched_barrier(0);
        __builtin_amdgcn_s_setprio(1);
#pragma unroll
        for (int ks = 0; ks < 2; ++ks)
#pragma unroll
            for (int mi = 0; mi < 4; ++mi)
#pragma unroll
                for (int ni = 0; ni < 2; ++ni)
                    acc[mi][ni] = __builtin_amdgcn_mfma_f32_16x16x32_bf16(
                        a[mi][ks], b0[ni][ks], acc[mi][ni], 0, 0, 0);
        __builtin_amdgcn_s_setprio(0);

        asm volatile("s_waitcnt lgkmcnt(0)" ::: "memory");
        __builtin_amdgcn_sched_barrier(0);
        __builtin_amdgcn_s_setprio(1);
#pragma unroll
        for (int ks = 0; ks < 2; ++ks)
#pragma unroll
            for (int mi = 0; mi < 4; ++mi)
#pragma unroll
                for (int ni = 0; ni < 2; ++ni)
                    acc[mi][2 + ni] = __builtin_amdgcn_mfma_f32_16x16x32_bf16(
                        a[mi][ks], b1[ni][ks], acc[mi][2 + ni], 0, 0, 0);
        __builtin_amdgcn_s_setprio(0);

        __builtin_amdgcn_s_barrier();   // #1

        if (kt + 2 < NT) { stageB(kt + 2, 0); stageB(kt + 2, 1); }
#pragma unroll
        for (int mi = 0; mi < 4; ++mi)
#pragma unroll
            for (int ks = 0; ks < 2; ++ks) {
                int r = 16 * (4 + mi) + llo;
                a[mi][ks] = ds_read_b128_o(&As[buf][wr][r][((ks * 4 + lhi) ^ (llo & 7)) << 3]);
            }

        asm volatile("s_waitcnt lgkmcnt(0)" ::: "memory");
        __builtin_amdgcn_sched_barrier(0);
        __builtin_amdgcn_s_setprio(1);
#pragma unroll
        for (int ks = 0; ks < 2; ++ks)
#pragma unroll
            for (int mi = 0; mi < 4; ++mi)
#pragma unroll
                for (int ni = 0; ni < 2; ++ni)
                    acc[4 + mi][2 + ni] = __builtin_amdgcn_mfma_f32_16x16x32_bf16(
                        a[mi][ks], b1[ni][ks], acc[4 + mi][2 + ni], 0, 0, 0);
        __builtin_amdgcn_s_setprio(0);

        __builtin_amdgcn_s_barrier();   // #2

        if (kt + 2 < NT) { stageA(kt + 2, 0); stageA(kt + 2, 1); }
        __builtin_amdgcn_s_setprio(1);
#pragma unroll
        for (int ks = 0; ks < 2; ++ks)
#pragma unroll
            for (int mi = 0; mi < 4; ++mi)
#pragma unroll
                for (int ni = 0; ni < 2; ++ni)
                    acc[4 + mi][ni] = __builtin_amdgcn_mfma_f32_16x16x32_bf16(
                        a[mi][ks], b0[ni][ks], acc[4 + mi][ni], 0, 0, 0);
        __builtin_amdgcn_s_setprio(0);

        if (kt + 2 < NT)      { asm volatile("s_waitcnt vmcnt(8)" ::: "memory"); }
        else if (kt + 1 < NT) { asm volatile("s_waitcnt vmcnt(0)" ::: "memory"); }
        __builtin_amdgcn_s_barrier();   // #3
    }

    int rbase = 128 * wr;
    int cbase = 64 * wc;
#pragma unroll
    for (int ni = 0; ni < 4; ++ni) {
#pragma unroll
        for (int mi = 0; mi < 8; ++mi)
#pragma unroll
            for (int rr = 0; rr < 4; ++rr) {
                int gr = rbase + 16 * mi + 4 * lhi + rr;
                out[(size_t)gr * DM + cbase + 16 * ni + llo] = f2bf(acc[mi][ni][rr]);
            }
    }
}

// -------- table-driven rotary + per-head LN (one block per token row) ---------
__global__ __launch_bounds__(256)
void rot_ln_kernel(const u16* __restrict__ Qf, const u16* __restrict__ Kf,
                   const float* __restrict__ ftab,
                   const float* __restrict__ g, const float* __restrict__ b,
                   u16* __restrict__ qnB, u16* __restrict__ knB,
                   float qk_scale, float fold_q)
{
    int c = blockIdx.x, t = threadIdx.x;
    int h  = t >> 4;
    int dl = (t & 15) * 8;
    const float* tab = ftab + ((size_t)c * 64 + (dl >> 1)) * 2;
    float fre[4], fim[4];
#pragma unroll
    for (int p = 0; p < 4; ++p) { fre[p] = tab[2 * p]; fim[p] = tab[2 * p + 1]; }
    float gv[8], bv2[8];
#pragma unroll
    for (int j = 0; j < 8; ++j) { gv[j] = g[dl + j]; bv2[j] = b[dl + j]; }

#pragma unroll
    for (int z = 0; z < 2; ++z) {
        const u16* src = z ? Kf : Qf;
        u16* dst = z ? knB : qnB;
        float fold = z ? 1.f : fold_q;
        short8 vv = *(const short8*)(src + (size_t)c * DM + t * 8);
        float o[8];
        float s = 0.f, ss = 0.f;
#pragma unroll
        for (int p = 0; p < 4; ++p) {
            float a  = bf2f((u16)vv[2 * p])     * qk_scale;
            float b2 = bf2f((u16)vv[2 * p + 1]) * qk_scale;
            float o0 = a * fre[p] - b2 * fim[p];
            float o1 = a * fim[p] + b2 * fre[p];
            o[2 * p] = o0; o[2 * p + 1] = o1;
            s += o0 + o1;
            ss += o0 * o0 + o1 * o1;
        }
#pragma unroll
        for (int off = 1; off < 16; off <<= 1) {
            s += __shfl_xor(s, off);
            ss += __shfl_xor(ss, off);
        }
        float mu   = s * (1.f / HD);
        float var  = ss * (1.f / HD) - mu * mu;
        float rstd = rsqrtf(var + 1e-5f);
        short8 r;
#pragma unroll
        for (int j = 0; j < 8; ++j)
            r[j] = (short)f2bf(((o[j] - mu) * rstd * gv[j] + bv2[j]) * fold);
        *(short8*)(dst + ((size_t)h * CTX + c) * HD + dl) = r;
    }
}

// ---------------- causal flash attention v4b ----------------------------------
__global__ __launch_bounds__(256, 2)
void attn_kernel(const u16* __restrict__ qn, const u16* __restrict__ kn,
                 const u16* __restrict__ vT, u16* __restrict__ aout)
{
    __shared__ __align__(16) u16 Kb[2][64][128];
    __shared__ __align__(16) u16 Vb[2][128][64];
    __shared__ __align__(16) u16 p_lds[4][16][72];

    int h  = blockIdx.y;
    int xs = blockIdx.x;
    int qb = (h >= 8) ? (31 - xs) : xs;   // CU load-balance pairing
    int q0 = qb * 64;
    int tid = threadIdx.x, w = tid >> 6, l = tid & 63;
    int lhi = l >> 4, llo = l & 15;

    const u16* qrow = qn + ((size_t)h * CTX + q0 + 16 * w + llo) * HD + 8 * lhi;
    short8 qf[4];
#pragma unroll
    for (int ks = 0; ks < 4; ++ks) qf[ks] = *(const short8*)(qrow + 32 * ks);

    auto stage = [&](int buf, int kv0) {
        int rb = 16 * w;
#pragma unroll
        for (int j = 0; j < 4; ++j) {
            int r = rb + 4 * j + (l >> 4);
            int csw = (l & 15) ^ (r & 15);
            const u16* src = kn + ((size_t)h * CTX + kv0 + r) * HD + (csw << 3);
            __builtin_amdgcn_global_load_lds((const __attribute__((address_space(1))) void*)src,
                (__attribute__((address_space(3))) void*)&Kb[buf][rb + 4 * j][0], 16, 0, 0);
        }
        int db = 32 * w;
#pragma unroll
        for (int j = 0; j < 4; ++j) {
            int d = db + 8 * j + (l >> 3);
            int csw = (l & 7) ^ (d & 7);
            const u16* src = vT + ((size_t)h * HD + d) * CTX + kv0 + (csw << 3);
            __builtin_amdgcn_global_load_lds((const __attribute__((address_space(1))) void*)src,
                (__attribute__((address_space(3))) void*)&Vb[buf][db + 8 * j][0], 16, 0, 0);
        }
    };

    float m_s = -1e30f, l_p = 0.f;
    f32x4 o_acc[8];
#pragma unroll
    for (int ni = 0; ni < 8; ++ni) o_acc[ni] = (f32x4){0.f, 0.f, 0.f, 0.f};

    stage(0, 0);
    __syncthreads();

    int cur = 0;
    for (int jt = 0; jt <= qb; ++jt) {
        if (jt < qb) stage(cur ^ 1, (jt + 1) * 64);   // prefetch overlaps compute

        f32x4 sacc[4] = {};
        __builtin_amdgcn_s_setprio(1);
#pragma unroll
        for (int ks = 0; ks < 4; ++ks) {
#pragma unroll
            for (int ni = 0; ni < 4; ++ni) {
                short8 kf = *(const short8*)&Kb[cur][16 * ni + llo][((4 * ks + lhi) ^ llo) << 3];
                sacc[ni] = __builtin_amdgcn_mfma_f32_16x16x32_bf16(kf, qf[ks], sacc[ni], 0, 0, 0);
            }
        }
        __builtin_amdgcn_s_setprio(0);

        if (jt == qb) {                  // causal mask inside diagonal tile
            int qloc = 16 * w + llo;
#pragma unroll
            for (int ni = 0; ni < 4; ++ni)
#pragma unroll
                for (int r = 0; r < 4; ++r)
                    if (16 * ni + 4 * lhi + r > qloc) sacc[ni][r] = -INFINITY;
        }

        // speculative P with OLD running max (no cross-lane wait)
        float pv[16];
#pragma unroll
        for (int ni = 0; ni < 4; ++ni)
#pragma unroll
            for (int r = 0; r < 4; ++r) pv[4 * ni + r] = exp2f(sacc[ni][r] - m_s);

        // per-lane local max only; __any supplies the cross-lane OR
        float mx = sacc[0][0];
#pragma unroll
        for (int ni = 0; ni < 4; ++ni)
#pragma unroll
            for (int r = 0; r < 4; ++r) mx = fmaxf(mx, sacc[ni][r]);

        if (__any(mx > m_s + 8.f)) {     // rare path: full reduce + rescale
            mx = fmaxf(mx, __shfl_xor(mx, 16));
            mx = fmaxf(mx, __shfl_xor(mx, 32));
            float mnew = fmaxf(m_s, mx);
            float fac = exp2f(m_s - mnew);
#pragma unroll
            for (int r = 0; r < 4; ++r) {
                float fr = __shfl(fac, 4 * lhi + r);
#pragma unroll
                for (int ni = 0; ni < 8; ++ni) o_acc[ni][r] *= fr;
            }
#pragma unroll
            for (int ni = 0; ni < 4; ++ni)
#pragma unroll
                for (int r = 0; r < 4; ++r) pv[4 * ni + r] = exp2f(sacc[ni][r] - mnew);
            l_p *= fac;
            m_s = mnew;
        }

        // pack P -> p_lds
#pragma unroll
        for (int ni = 0; ni < 4; ++ni)
#pragma unroll
            for (int hf = 0; hf < 2; ++hf) {
                unsigned pk;
                asm("v_cvt_pk_bf16_f32 %0, %1, %2" : "=v"(pk)
                    : "v"(pv[4 * ni + 2 * hf]), "v"(pv[4 * ni + 2 * hf + 1]));
                *(unsigned*)&p_lds[w][llo][16 * ni + 4 * lhi + 2 * hf] = pk;
            }

        // deferred l: per-lane partial only (cross-lane reduce in epilogue)
        float ps = 0.f;
#pragma unroll
        for (int j = 0; j < 16; ++j) ps += pv[j];
        l_p += ps;

        // O += P . V
        __builtin_amdgcn_s_setprio(1);
#pragma unroll
        for (int ks = 0; ks < 2; ++ks) {
            short8 pa = *(const short8*)&p_lds[w][llo][32 * ks + 8 * lhi];
#pragma unroll
            for (int ni = 0; ni < 8; ++ni) {
                short8 vf = *(const short8*)&Vb[cur][16 * ni + llo][((4 * ks + lhi) ^ (llo & 7)) << 3];
                o_acc[ni] = __builtin_amdgcn_mfma_f32_16x16x32_bf16(pa, vf, o_acc[ni], 0, 0, 0);
            }
        }
        __builtin_amdgcn_s_setprio(0);

        __syncthreads();   // drains prefetch vmcnt + frees buf[cur]
        cur ^= 1;
    }

    float lsum = l_p;
    lsum += __shfl_xor(lsum, 16);
    lsum += __shfl_xor(lsum, 32);
#pragma unroll
    for (int r = 0; r < 4; ++r) {
        float lr  = __shfl(lsum, 4 * lhi + r);
        float inv = 1.f / lr;
        int qrow2 = q0 + 16 * w + 4 * lhi + r;
#pragma unroll
        for (int ni = 0; ni < 8; ++ni)
            aout[(size_t)qrow2 * DM + h * HD + 16 * ni + llo] = f2bf(o_acc[ni][r] * inv);
    }
}

// ---------------- combine 4 bf16 split-K partials + bias ----------------------
__global__ __launch_bounds__(256)
void combine4_kernel(const u16* __restrict__ p, const float* __restrict__ bias,
                     float* __restrict__ out)
{
    size_t i = ((size_t)blockIdx.x * 256 + threadIdx.x) * 8;
    short8 a0 = *(const short8*)(p + i);
    short8 a1 = *(const short8*)(p + (size_t)CTX * DM + i);
    short8 a2 = *(const short8*)(p + 2 * (size_t)CTX * DM + i);
    short8 a3 = *(const short8*)(p + 3 * (size_t)CTX * DM + i);
    int dbase = (int)(i & (DM - 1));
    float4 bv0 = *(const float4*)(bias + dbase);
    float4 bv1 = *(const float4*)(bias + dbase + 4);
    float r[8];
    float bvv[8] = {bv0.x, bv0.y, bv0.z, bv0.w, bv1.x, bv1.y, bv1.z, bv1.w};
#pragma unroll
    for (int j = 0; j < 8; ++j)
        r[j] = (bf2f((u16)a0[j]) + bf2f((u16)a1[j]))
             + (bf2f((u16)a2[j]) + bf2f((u16)a3[j])) + bvv[j];
    *(float4*)(out + i)     = (float4){r[0], r[1], r[2], r[3]};
    *(float4*)(out + i + 4) = (float4){r[4], r[5], r[6], r[7]};
}

// ------------------------------- launcher ------------------------------------
extern "C" void kernel_launch(void* const* d_in, const int* in_sizes, int n_in,
                              void* d_out, int out_size, void* d_ws, size_t ws_size,
                              hipStream_t stream)
{
    const float* x   = (const float*)d_in[0];
    const float* qng = (const float*)d_in[1];
    const float* qnb = (const float*)d_in[2];
    const float* kng = (const float*)d_in[3];
    const float* knb = (const float*)d_in[4];
    const float* Wq  = (const float*)d_in[5];
    const float* bq  = (const float*)d_in[6];
    const float* Wkv = (const float*)d_in[7];
    const float* bkv = (const float*)d_in[8];
    const float* Wo  = (const float*)d_in[9];
    const float* bo  = (const float*)d_in[10];
    const float* lng = (const float*)d_in[11];
    const float* lnb = (const float*)d_in[12];
    float* out = (float*)d_out;

    uint8_t* ws = (uint8_t*)d_ws;
    size_t off = 0;
    auto alloc = [&](size_t bytes) -> void* {
        void* p = ws + off;
        off += (bytes + 255) & ~(size_t)255;
        return p;
    };
    u16*   WqT  = (u16*)alloc((size_t)DM * DM * 2);
    u16*   WkvT = (u16*)alloc((size_t)2 * DM * DM * 2);
    u16*   WoT  = (u16*)alloc((size_t)DM * DM * 2);
    u16*   Aq   = (u16*)alloc((size_t)CTX * DM * 2);
    u16*   Akv  = (u16*)alloc((size_t)CTX * DM * 2);
    float* ftab = (float*)alloc((size_t)CTX * 64 * 2 * 4);
    u16*   Qf   = (u16*)alloc((size_t)CTX * DM * 2);
    u16*   Kf   = (u16*)alloc((size_t)CTX * DM * 2);
    u16*   vTB  = (u16*)alloc((size_t)CTX * DM * 2);
    u16*   qnB  = (u16*)alloc((size_t)CTX * DM * 2);
    u16*   knB  = (u16*)alloc((size_t)CTX * DM * 2);
    u16*   aB   = (u16*)alloc((size_t)CTX * DM * 2);
    u16*   oprt = (u16*)alloc((size_t)4 * CTX * DM * 2);
    (void)ws_size; (void)in_sizes; (void)n_in; (void)out_size;

    transpose_all_kernel<<<dim3(DM / 32, DM / 32, 4), dim3(32, 8), 0, stream>>>(
        Wq, Wo, Wkv, WqT, WoT, WkvT);

    ln_stats_kernel<<<CTX, 256, 0, stream>>>(x, qng, qnb, kng, knb, Aq, Akv, ftab);

    qkv_gemm256_kernel<<<dim3(192), 512, 0, stream>>>(
        Aq, Akv, WqT, WkvT, bq, bkv, Qf, Kf, vTB);

    const float qk_scale = 0.29730177875068026f;                       // 128^-0.25
    const float fold_q   = 0.08838834764831845f * 1.4426950408889634f; // 1/sqrt(128)*log2(e)
    rot_ln_kernel<<<CTX, 256, 0, stream>>>(
        Qf, Kf, ftab, lng, lnb, qnB, knB, qk_scale, fold_q);

    attn_kernel<<<dim3(CTX / 64, NH), 256, 0, stream>>>(qnB, knB, vTB, aB);

    oproj_gemm256_kernel<<<dim3(256), 512, 0, stream>>>(aB, WoT, oprt);
    combine4_kernel<<<(CTX * DM) / 2048, 256, 0, stream>>>(oprt, bo, out);
}

// Round 5
// 190.198 us; speedup vs baseline: 1.0718x; 1.0061x over previous
//
#include <hip/hip_runtime.h>
#include <stdint.h>
#include <math.h>

#define CTX 2048
#define DM  2048
#define NH  16
#define HD  128

typedef __attribute__((ext_vector_type(8))) short short8;   // 8 x bf16 (4 VGPRs)
typedef __attribute__((ext_vector_type(4))) float f32x4;    // MFMA acc
typedef unsigned short u16;

__device__ __forceinline__ u16 f2bf(float f) {
    unsigned u = __float_as_uint(f);
    unsigned r = u + 0x7fffu + ((u >> 16) & 1u);   // RTNE
    return (u16)(r >> 16);
}
__device__ __forceinline__ float bf2f(u16 h) {
    return __uint_as_float(((unsigned)h) << 16);
}

// Opaque LDS read: invisible to SIInsertWaitcnts' LDS-DMA alias tracking, so
// the compiler cannot insert vmcnt(0) drains before it. Ordering enforced
// manually: counted lgkmcnt + sched_barrier(0) before every consumer (rule #18).
__device__ __forceinline__ short8 ds_read_b128_o(const void* p) {
    short8 r;
    asm volatile("ds_read_b128 %0, %1"
                 : "=v"(r)
                 : "v"((const __attribute__((address_space(3))) void*)p));
    return r;
}

// ------- merged weight transpose + f32->bf16 (W[K][N] -> WT[N][K]), 4 slabs ---
__global__ __launch_bounds__(256)
void transpose_all_kernel(const float* __restrict__ Wq, const float* __restrict__ Wo,
                          const float* __restrict__ Wkv,
                          u16* __restrict__ WqT, u16* __restrict__ WoT, u16* __restrict__ WkvT)
{
    __shared__ float tile[32][33];
    int z = blockIdx.z;
    const float* S; u16* D; int nsrc, c0, r0;
    if (z == 0)      { S = Wq;  D = WqT;  nsrc = DM;     c0 = 0;  r0 = 0;    }
    else if (z == 1) { S = Wo;  D = WoT;  nsrc = DM;     c0 = 0;  r0 = 0;    }
    else if (z == 2) { S = Wkv; D = WkvT; nsrc = 2 * DM; c0 = 0;  r0 = 0;    }
    else             { S = Wkv; D = WkvT; nsrc = 2 * DM; c0 = DM; r0 = DM;   }
    int k0 = blockIdx.x * 32, n0 = blockIdx.y * 32;
    int tx = threadIdx.x, ty = threadIdx.y;          // 32 x 8
#pragma unroll
    for (int j = 0; j < 4; ++j) {
        int kk = ty + 8 * j;
        tile[kk][tx] = S[(size_t)(k0 + kk) * nsrc + c0 + n0 + tx];
    }
    __syncthreads();
#pragma unroll
    for (int j = 0; j < 4; ++j) {
        int nn = ty + 8 * j;
        D[(size_t)(r0 + n0 + nn) * DM + k0 + tx] = f2bf(tile[tx][nn]);
    }
}

// -------- LN stats + normalized A matrices (bf16) + rotary factor table -------
__global__ __launch_bounds__(256)
void ln_stats_kernel(const float* __restrict__ x,
                     const float* __restrict__ qg, const float* __restrict__ qb,
                     const float* __restrict__ kg, const float* __restrict__ kb,
                     u16* __restrict__ Aq, u16* __restrict__ Akv, float* __restrict__ ftab)
{
    int c = blockIdx.x, t = threadIdx.x;
    const float* row = x + (size_t)c * DM;
    float4 v0 = *(const float4*)(row + t * 8);
    float4 v1 = *(const float4*)(row + t * 8 + 4);
    float vals[8] = {v0.x, v0.y, v0.z, v0.w, v1.x, v1.y, v1.z, v1.w};
    float s = 0.f, ss = 0.f;
#pragma unroll
    for (int j = 0; j < 8; ++j) { s += vals[j]; ss += vals[j] * vals[j]; }
#pragma unroll
    for (int off = 32; off; off >>= 1) { s += __shfl_xor(s, off); ss += __shfl_xor(ss, off); }
    __shared__ float red[8];
    int w = t >> 6;
    if ((t & 63) == 0) { red[w] = s; red[4 + w] = ss; }
    __syncthreads();
    float st  = red[0] + red[1] + red[2] + red[3];
    float sst = red[4] + red[5] + red[6] + red[7];
    float mu   = st * (1.f / DM);
    float var  = sst * (1.f / DM) - mu * mu;
    float rstd = rsqrtf(var + 1e-5f);
    if (t < 64) {                         // rotary table, m folded in
        const float LT64 = 10.30895266f / 64.f;   // ln(30000)/64
        float m = sqrtf(sst);
        float sn, cs;
        sincosf((float)c * ((float)t * LT64), &sn, &cs);
        float2 wv = {m * cs, m * sn};
        *(float2*)(ftab + ((size_t)c * 64 + t) * 2) = wv;
    }
    short8 aq, akv;
#pragma unroll
    for (int j = 0; j < 8; ++j) {
        int d = t * 8 + j;
        float xh = (vals[j] - mu) * rstd;
        aq[j]  = (short)f2bf(xh * qg[d] + qb[d]);
        akv[j] = (short)f2bf(xh * kg[d] + kb[d]);
    }
    *(short8*)(Aq  + (size_t)c * DM + t * 8) = aq;
    *(short8*)(Akv + (size_t)c * DM + t * 8) = akv;
}

// ---------------- fused QKV projection GEMM -----------------------------------
// 256x256 tile, BK=64, 8 waves (2Mx4N). v4: one-barrier software-pipelined
// schedule. Tile-kt fragments (a03,b0) are read one iteration AHEAD (issued in
// iter kt-1's post-barrier region), so q00/q01 hit lgkm waits on long-retired
// reads and the LDS pipe stays busy through the MFMA phases.
//
// Per-iteration order and race audit:
//   issue b1,a47 from buf[kt]        (buf landed: proven by prev iter's
//                                     vmcnt(0)+barrier, chip-wide)
//   lgkm(12) -> q00 (a03,b0 carried) (retires the 12 carry reads: in-order DS)
//   lgkm(8)  -> q01 (b1 ready)
//   lgkm(0); vmcnt(0); BARRIER       (ALL waves: every LDS read retired; tile
//                                     kt+1's DMA landed -> both hazards closed)
//   stage tile kt+2 -> buf           (safe: no read of buf can be in flight)
//   issue a03' from buf^1            (tile kt+1: landed per the barrier)
//   q11 (a47,b1); q10 (a47,b0)       (register-only; overlaps the issues above)
//   issue b0' from buf^1             (after q10 released old b0)
// Cross-iteration: a03'/b0' retire at the NEXT iter's lgkm(0) before its
// barrier, and the overwrite of buf^1 (stage of tile kt+3) happens only after
// that barrier -> no wave can race a stage against an in-flight read.
__global__ __launch_bounds__(512, 2)
void qkv_gemm256_kernel(const u16* __restrict__ Aq, const u16* __restrict__ Akv,
                        const u16* __restrict__ WqT, const u16* __restrict__ WkvT,
                        const float* __restrict__ bq, const float* __restrict__ bkv,
                        u16* __restrict__ Qf, u16* __restrict__ Kf, u16* __restrict__ vT)
{
    __shared__ __align__(16) u16 As[2][2][128][64];   // [buf][half][row][col]
    __shared__ __align__(16) u16 Bs[2][2][128][64];

    constexpr int NT = DM / 64;                       // 32 K-tiles

    // XCD-aware swizzle: 192 blocks, 24 contiguous tiles per XCD (192 % 8 == 0)
    int lin = blockIdx.x;
    int swz = (lin & 7) * 24 + (lin >> 3);
    int mt  = swz & 7;          // M tile 0..7
    int ng  = swz >> 3;         // 0..23
    int seg = ng >> 3;          // 0:Q 1:K 2:V
    int nt  = ng & 7;           // N tile 0..7

    const u16* Amat; const u16* Bmat; const float* bias; u16* outp; bool rowbias;
    if (seg == 0) {
        Amat = Aq  + (size_t)mt * 256 * DM;
        Bmat = WqT + (size_t)nt * 256 * DM;
        bias = bq + nt * 256;
        outp = Qf + (size_t)mt * 256 * DM + nt * 256;
        rowbias = false;
    } else if (seg == 1) {
        Amat = Akv  + (size_t)mt * 256 * DM;
        Bmat = WkvT + (size_t)nt * 256 * DM;
        bias = bkv + nt * 256;
        outp = Kf + (size_t)mt * 256 * DM + nt * 256;
        rowbias = false;
    } else {
        Amat = WkvT + (size_t)(DM + mt * 256) * DM;   // V dims as GEMM rows
        Bmat = Akv  + (size_t)nt * 256 * DM;          // context as GEMM cols
        bias = bkv + DM + mt * 256;                   // per-row bias
        outp = vT + (size_t)mt * 256 * CTX + nt * 256;
        rowbias = true;
    }

    int tid = threadIdx.x;
    int wid = tid >> 6, l = tid & 63;
    int wr = wid >> 2, wc = wid & 3;                  // 2x4 wave grid
    int lhi = l >> 4, llo = l & 15;
    int srow  = l >> 3;                               // staging: row within 8-row group
    int sunit = (l & 7) ^ srow;                       // inverse-swizzled global 16B unit

    auto stageA = [&](int kt, int h) {
#pragma unroll
        for (int rd = 0; rd < 2; ++rd) {
            const u16* src = Amat + (size_t)(h * 128 + rd * 64 + wid * 8 + srow) * DM
                             + kt * 64 + sunit * 8;
            __builtin_amdgcn_global_load_lds((const __attribute__((address_space(1))) void*)src,
                (__attribute__((address_space(3))) void*)&As[kt & 1][h][rd * 64 + wid * 8][0],
                16, 0, 0);
        }
    };
    auto stageB = [&](int kt, int h) {
#pragma unroll
        for (int rd = 0; rd < 2; ++rd) {
            const u16* src = Bmat + (size_t)(h * 128 + rd * 64 + wid * 8 + srow) * DM
                             + kt * 64 + sunit * 8;
            __builtin_amdgcn_global_load_lds((const __attribute__((address_space(1))) void*)src,
                (__attribute__((address_space(3))) void*)&Bs[kt & 1][h][rd * 64 + wid * 8][0],
                16, 0, 0);
        }
    };

    f32x4 acc[8][4] = {};                 // accumulator (AGPR side)
    short8 a0f[4][2];                     // carried: tile kt, m-frags 0-3
    short8 b0f[2][2];                     // carried: tile kt, n-frags 0-1
    int bhalf = wc >> 1, brow = (wc & 1) * 64;

    // prologue: stage tiles 0,1; preload tile0's carry fragments (12 reads)
    stageA(0, 0); stageA(0, 1); stageB(0, 0); stageB(0, 1);
    stageA(1, 0); stageA(1, 1); stageB(1, 0); stageB(1, 1);
    asm volatile("s_waitcnt vmcnt(8)" ::: "memory");
    __builtin_amdgcn_s_barrier();
#pragma unroll
    for (int mi = 0; mi < 4; ++mi)
#pragma unroll
        for (int ks = 0; ks < 2; ++ks)
            a0f[mi][ks] = ds_read_b128_o(&As[0][wr][16 * mi + llo][((ks * 4 + lhi) ^ (llo & 7)) << 3]);
#pragma unroll
    for (int ni = 0; ni < 2; ++ni)
#pragma unroll
        for (int ks = 0; ks < 2; ++ks)
            b0f[ni][ks] = ds_read_b128_o(&Bs[0][bhalf][brow + 16 * ni + llo][((ks * 4 + lhi) ^ (llo & 7)) << 3]);

    for (int kt = 0; kt < NT; ++kt) {
        int buf = kt & 1;
        short8 a1f[4][2], b1f[2][2];

        // ---- issue this tile's second-half reads: b1 (4) then a47 (8) -------
#pragma unroll
        for (int ni = 0; ni < 2; ++ni)
#pragma unroll
            for (int ks = 0; ks < 2; ++ks) {
                int r = brow + 16 * (2 + ni) + llo;
                b1f[ni][ks] = ds_read_b128_o(&Bs[buf][bhalf][r][((ks * 4 + lhi) ^ (llo & 7)) << 3]);
            }
#pragma unroll
        for (int mi = 0; mi < 4; ++mi)
#pragma unroll
            for (int ks = 0; ks < 2; ++ks) {
                int r = 16 * (4 + mi) + llo;
                a1f[mi][ks] = ds_read_b128_o(&As[buf][wr][r][((ks * 4 + lhi) ^ (llo & 7)) << 3]);
            }

        // ---- q00: carried fragments; lgkm(12) retires them (issued last iter)
        asm volatile("s_waitcnt lgkmcnt(12)" ::: "memory");
        __builtin_amdgcn_sched_barrier(0);
        __builtin_amdgcn_s_setprio(1);
#pragma unroll
        for (int ks = 0; ks < 2; ++ks)
#pragma unroll
            for (int mi = 0; mi < 4; ++mi)
#pragma unroll
                for (int ni = 0; ni < 2; ++ni)
                    acc[mi][ni] = __builtin_amdgcn_mfma_f32_16x16x32_bf16(
                        a0f[mi][ks], b0f[ni][ks], acc[mi][ni], 0, 0, 0);
        __builtin_amdgcn_s_setprio(0);

        // ---- q01: needs b1 (first 4 of this iter's 12) -----------------------
        asm volatile("s_waitcnt lgkmcnt(8)" ::: "memory");
        __builtin_amdgcn_sched_barrier(0);
        __builtin_amdgcn_s_setprio(1);
#pragma unroll
        for (int ks = 0; ks < 2; ++ks)
#pragma unroll
            for (int mi = 0; mi < 4; ++mi)
#pragma unroll
                for (int ni = 0; ni < 2; ++ni)
                    acc[mi][2 + ni] = __builtin_amdgcn_mfma_f32_16x16x32_bf16(
                        a0f[mi][ks], b1f[ni][ks], acc[mi][2 + ni], 0, 0, 0);
        __builtin_amdgcn_s_setprio(0);

        // ---- close all hazards, single barrier ------------------------------
        asm volatile("s_waitcnt lgkmcnt(0)" ::: "memory");
        asm volatile("s_waitcnt vmcnt(0)" ::: "memory");
        __builtin_amdgcn_sched_barrier(0);
        __builtin_amdgcn_s_barrier();

        // ---- stage tile kt+2 into buf; prefetch next iter's carry frags ------
        if (kt + 2 < NT) { stageB(kt + 2, 0); stageB(kt + 2, 1);
                           stageA(kt + 2, 0); stageA(kt + 2, 1); }
        if (kt + 1 < NT) {
            int nb = buf ^ 1;
#pragma unroll
            for (int mi = 0; mi < 4; ++mi)
#pragma unroll
                for (int ks = 0; ks < 2; ++ks)
                    a0f[mi][ks] = ds_read_b128_o(&As[nb][wr][16 * mi + llo][((ks * 4 + lhi) ^ (llo & 7)) << 3]);
        }

        // ---- q11, q10 from registers (overlap the issues above) -------------
        __builtin_amdgcn_s_setprio(1);
#pragma unroll
        for (int ks = 0; ks < 2; ++ks)
#pragma unroll
            for (int mi = 0; mi < 4; ++mi)
#pragma unroll
                for (int ni = 0; ni < 2; ++ni)
                    acc[4 + mi][2 + ni] = __builtin_amdgcn_mfma_f32_16x16x32_bf16(
                        a1f[mi][ks], b1f[ni][ks], acc[4 + mi][2 + ni], 0, 0, 0);
#pragma unroll
        for (int ks = 0; ks < 2; ++ks)
#pragma unroll
            for (int mi = 0; mi < 4; ++mi)
#pragma unroll
                for (int ni = 0; ni < 2; ++ni)
                    acc[4 + mi][ni] = __builtin_amdgcn_mfma_f32_16x16x32_bf16(
                        a1f[mi][ks], b0f[ni][ks], acc[4 + mi][ni], 0, 0, 0);
        __builtin_amdgcn_s_setprio(0);

        // ---- b0 released by q10: prefetch next iter's b0 --------------------
        if (kt + 1 < NT) {
            int nb = buf ^ 1;
#pragma unroll
            for (int ni = 0; ni < 2; ++ni)
#pragma unroll
                for (int ks = 0; ks < 2; ++ks)
                    b0f[ni][ks] = ds_read_b128_o(&Bs[nb][bhalf][brow + 16 * ni + llo][((ks * 4 + lhi) ^ (llo & 7)) << 3]);
        }
    }

    // ---------------- epilogue: bias + bf16 store ----------------------------
    int rbase = 128 * wr;
    int cbase = 64 * wc;
    if (!rowbias) {
#pragma unroll
        for (int ni = 0; ni < 4; ++ni) {
            float bv = bias[cbase + 16 * ni + llo];
#pragma unroll
            for (int mi = 0; mi < 8; ++mi)
#pragma unroll
                for (int rr = 0; rr < 4; ++rr) {
                    int gr = rbase + 16 * mi + 4 * lhi + rr;
                    outp[(size_t)gr * DM + cbase + 16 * ni + llo] = f2bf(acc[mi][ni][rr] + bv);
                }
        }
    } else {
#pragma unroll
        for (int mi = 0; mi < 8; ++mi)
#pragma unroll
            for (int rr = 0; rr < 4; ++rr) {
                int gr = rbase + 16 * mi + 4 * lhi + rr;
                float bv = bias[gr];
#pragma unroll
                for (int ni = 0; ni < 4; ++ni)
                    outp[(size_t)gr * CTX + cbase + 16 * ni + llo] = f2bf(acc[mi][ni][rr] + bv);
            }
    }
}

// ---------------- O-projection GEMM: 256^2 tile, 4-way split-K ----------------
__global__ __launch_bounds__(512, 2)
void oproj_gemm256_kernel(const u16* __restrict__ A, const u16* __restrict__ BT,
                          u16* __restrict__ outp)
{
    __shared__ __align__(16) u16 As[2][2][128][64];
    __shared__ __align__(16) u16 Bs[2][2][128][64];

    constexpr int NT = 8;                             // 8 K-tiles = 512 deep

    // XCD swizzle: 256 blocks, 32 contiguous per XCD (256 % 8 == 0, bijective)
    int lin = blockIdx.x;
    int swz = (lin & 7) * 32 + (lin >> 3);
    int kz  = swz >> 6;          // K split 0..3
    int rem = swz & 63;
    int mt  = rem & 7;
    int nt  = rem >> 3;

    const u16* Amat = A  + (size_t)mt * 256 * DM + kz * 512;
    const u16* Bmat = BT + (size_t)nt * 256 * DM + kz * 512;
    u16* out = outp + (size_t)kz * CTX * DM + (size_t)mt * 256 * DM + nt * 256;

    int tid = threadIdx.x;
    int wid = tid >> 6, l = tid & 63;
    int wr = wid >> 2, wc = wid & 3;
    int lhi = l >> 4, llo = l & 15;
    int srow  = l >> 3;
    int sunit = (l & 7) ^ srow;

    auto stageA = [&](int kt, int h) {
#pragma unroll
        for (int rd = 0; rd < 2; ++rd) {
            const u16* src = Amat + (size_t)(h * 128 + rd * 64 + wid * 8 + srow) * DM
                             + kt * 64 + sunit * 8;
            __builtin_amdgcn_global_load_lds((const __attribute__((address_space(1))) void*)src,
                (__attribute__((address_space(3))) void*)&As[kt & 1][h][rd * 64 + wid * 8][0],
                16, 0, 0);
        }
    };
    auto stageB = [&](int kt, int h) {
#pragma unroll
        for (int rd = 0; rd < 2; ++rd) {
            const u16* src = Bmat + (size_t)(h * 128 + rd * 64 + wid * 8 + srow) * DM
                             + kt * 64 + sunit * 8;
            __builtin_amdgcn_global_load_lds((const __attribute__((address_space(1))) void*)src,
                (__attribute__((address_space(3))) void*)&Bs[kt & 1][h][rd * 64 + wid * 8][0],
                16, 0, 0);
        }
    };

    f32x4 acc[8][4] = {};
    short8 a[4][2];
    short8 b0[2][2], b1[2][2];
    int bhalf = wc >> 1, brow = (wc & 1) * 64;

    stageA(0, 0); stageA(0, 1); stageB(0, 0); stageB(0, 1);
    stageA(1, 0); stageA(1, 1); stageB(1, 0); stageB(1, 1);
    asm volatile("s_waitcnt vmcnt(8)" ::: "memory");
    __builtin_amdgcn_s_barrier();

    for (int kt = 0; kt < NT; ++kt) {
        int buf = kt & 1;

#pragma unroll
        for (int ni = 0; ni < 2; ++ni)
#pragma unroll
            for (int ks = 0; ks < 2; ++ks) {
                int r = brow + 16 * ni + llo;
                b0[ni][ks] = ds_read_b128_o(&Bs[buf][bhalf][r][((ks * 4 + lhi) ^ (llo & 7)) << 3]);
            }
#pragma unroll
        for (int mi = 0; mi < 4; ++mi)
#pragma unroll
            for (int ks = 0; ks < 2; ++ks) {
                int r = 16 * mi + llo;
                a[mi][ks] = ds_read_b128_o(&As[buf][wr][r][((ks * 4 + lhi) ^ (llo & 7)) << 3]);
            }
#pragma unroll
        for (int ni = 0; ni < 2; ++ni)
#pragma unroll
            for (int ks = 0; ks < 2; ++ks) {
                int r = brow + 16 * (2 + ni) + llo;
                b1[ni][ks] = ds_read_b128_o(&Bs[buf][bhalf][r][((ks * 4 + lhi) ^ (llo & 7)) << 3]);
            }

        asm volatile("s_waitcnt lgkmcnt(4)" ::: "memory");
        __builtin_amdgcn_sched_barrier(0);
        __builtin_amdgcn_s_setprio(1);
#pragma unroll
        for (int ks = 0; ks < 2; ++ks)
#pragma unroll
            for (int mi = 0; mi < 4; ++mi)
#pragma unroll
                for (int ni = 0; ni < 2; ++ni)
                    acc[mi][ni] = __builtin_amdgcn_mfma_f32_16x16x32_bf16(
                        a[mi][ks], b0[ni][ks], acc[mi][ni], 0, 0, 0);
        __builtin_amdgcn_s_setprio(0);

        asm volatile("s_waitcnt lgkmcnt(0)" ::: "memory");
        __builtin_amdgcn_sched_barrier(0);
        __builtin_amdgcn_s_setprio(1);
#pragma unroll
        for (int ks = 0; ks < 2; ++ks)
#pragma unroll
            for (int mi = 0; mi < 4; ++mi)
#pragma unroll
                for (int ni = 0; ni < 2; ++ni)
                    acc[mi][2 + ni] = __builtin_amdgcn_mfma_f32_16x16x32_bf16(
                        a[mi][ks], b1[ni][ks], acc[mi][2 + ni], 0, 0, 0);
        __builtin_amdgcn_s_setprio(0);

        __builtin_amdgcn_s_barrier();   // #1

        if (kt + 2 < NT) { stageB(kt + 2, 0); stageB(kt + 2, 1); }
#pragma unroll
        for (int mi = 0; mi < 4; ++mi)
#pragma unroll
            for (int ks = 0; ks < 2; ++ks) {
                int r = 16 * (4 + mi) + llo;
                a[mi][ks] = ds_read_b128_o(&As[buf][wr][r][((ks * 4 + lhi) ^ (llo & 7)) << 3]);
            }

        asm volatile("s_waitcnt lgkmcnt(0)" ::: "memory");
        __builtin_amdgcn_sched_barrier(0);
        __builtin_amdgcn_s_setprio(1);
#pragma unroll
        for (int ks = 0; ks < 2; ++ks)
#pragma unroll
            for (int mi = 0; mi < 4; ++mi)
#pragma unroll
                for (int ni = 0; ni < 2; ++ni)
                    acc[4 + mi][2 + ni] = __builtin_amdgcn_mfma_f32_16x16x32_bf16(
                        a[mi][ks], b1[ni][ks], acc[4 + mi][2 + ni], 0, 0, 0);
        __builtin_amdgcn_s_setprio(0);

        __builtin_amdgcn_s_barrier();   // #2

        if (kt + 2 < NT) { stageA(kt + 2, 0); stageA(kt + 2, 1); }
        __builtin_amdgcn_s_setprio(1);
#pragma unroll
        for (int ks = 0; ks < 2; ++ks)
#pragma unroll
            for (int mi = 0; mi < 4; ++mi)
#pragma unroll
                for (int ni = 0; ni < 2; ++ni)
                    acc[4 + mi][ni] = __builtin_amdgcn_mfma_f32_16x16x32_bf16(
                        a[mi][ks], b0[ni][ks], acc[4 + mi][ni], 0, 0, 0);
        __builtin_amdgcn_s_setprio(0);

        if (kt + 2 < NT)      { asm volatile("s_waitcnt vmcnt(8)" ::: "memory"); }
        else if (kt + 1 < NT) { asm volatile("s_waitcnt vmcnt(0)" ::: "memory"); }
        __builtin_amdgcn_s_barrier();   // #3
    }

    int rbase = 128 * wr;
    int cbase = 64 * wc;
#pragma unroll
    for (int ni = 0; ni < 4; ++ni) {
#pragma unroll
        for (int mi = 0; mi < 8; ++mi)
#pragma unroll
            for (int rr = 0; rr < 4; ++rr) {
                int gr = rbase + 16 * mi + 4 * lhi + rr;
                out[(size_t)gr * DM + cbase + 16 * ni + llo] = f2bf(acc[mi][ni][rr]);
            }
    }
}

// -------- table-driven rotary + per-head LN (one block per token row) ---------
__global__ __launch_bounds__(256)
void rot_ln_kernel(const u16* __restrict__ Qf, const u16* __restrict__ Kf,
                   const float* __restrict__ ftab,
                   const float* __restrict__ g, const float* __restrict__ b,
                   u16* __restrict__ qnB, u16* __restrict__ knB,
                   float qk_scale, float fold_q)
{
    int c = blockIdx.x, t = threadIdx.x;
    int h  = t >> 4;
    int dl = (t & 15) * 8;
    const float* tab = ftab + ((size_t)c * 64 + (dl >> 1)) * 2;
    float fre[4], fim[4];
#pragma unroll
    for (int p = 0; p < 4; ++p) { fre[p] = tab[2 * p]; fim[p] = tab[2 * p + 1]; }
    float gv[8], bv2[8];
#pragma unroll
    for (int j = 0; j < 8; ++j) { gv[j] = g[dl + j]; bv2[j] = b[dl + j]; }

#pragma unroll
    for (int z = 0; z < 2; ++z) {
        const u16* src = z ? Kf : Qf;
        u16* dst = z ? knB : qnB;
        float fold = z ? 1.f : fold_q;
        short8 vv = *(const short8*)(src + (size_t)c * DM + t * 8);
        float o[8];
        float s = 0.f, ss = 0.f;
#pragma unroll
        for (int p = 0; p < 4; ++p) {
            float a  = bf2f((u16)vv[2 * p])     * qk_scale;
            float b2 = bf2f((u16)vv[2 * p + 1]) * qk_scale;
            float o0 = a * fre[p] - b2 * fim[p];
            float o1 = a * fim[p] + b2 * fre[p];
            o[2 * p] = o0; o[2 * p + 1] = o1;
            s += o0 + o1;
            ss += o0 * o0 + o1 * o1;
        }
#pragma unroll
        for (int off = 1; off < 16; off <<= 1) {
            s += __shfl_xor(s, off);
            ss += __shfl_xor(ss, off);
        }
        float mu   = s * (1.f / HD);
        float var  = ss * (1.f / HD) - mu * mu;
        float rstd = rsqrtf(var + 1e-5f);
        short8 r;
#pragma unroll
        for (int j = 0; j < 8; ++j)
            r[j] = (short)f2bf(((o[j] - mu) * rstd * gv[j] + bv2[j]) * fold);
        *(short8*)(dst + ((size_t)h * CTX + c) * HD + dl) = r;
    }
}

// ---------------- causal flash attention v4b ----------------------------------
__global__ __launch_bounds__(256, 2)
void attn_kernel(const u16* __restrict__ qn, const u16* __restrict__ kn,
                 const u16* __restrict__ vT, u16* __restrict__ aout)
{
    __shared__ __align__(16) u16 Kb[2][64][128];
    __shared__ __align__(16) u16 Vb[2][128][64];
    __shared__ __align__(16) u16 p_lds[4][16][72];

    int h  = blockIdx.y;
    int xs = blockIdx.x;
    int qb = (h >= 8) ? (31 - xs) : xs;   // CU load-balance pairing
    int q0 = qb * 64;
    int tid = threadIdx.x, w = tid >> 6, l = tid & 63;
    int lhi = l >> 4, llo = l & 15;

    const u16* qrow = qn + ((size_t)h * CTX + q0 + 16 * w + llo) * HD + 8 * lhi;
    short8 qf[4];
#pragma unroll
    for (int ks = 0; ks < 4; ++ks) qf[ks] = *(const short8*)(qrow + 32 * ks);

    auto stage = [&](int buf, int kv0) {
        int rb = 16 * w;
#pragma unroll
        for (int j = 0; j < 4; ++j) {
            int r = rb + 4 * j + (l >> 4);
            int csw = (l & 15) ^ (r & 15);
            const u16* src = kn + ((size_t)h * CTX + kv0 + r) * HD + (csw << 3);
            __builtin_amdgcn_global_load_lds((const __attribute__((address_space(1))) void*)src,
                (__attribute__((address_space(3))) void*)&Kb[buf][rb + 4 * j][0], 16, 0, 0);
        }
        int db = 32 * w;
#pragma unroll
        for (int j = 0; j < 4; ++j) {
            int d = db + 8 * j + (l >> 3);
            int csw = (l & 7) ^ (d & 7);
            const u16* src = vT + ((size_t)h * HD + d) * CTX + kv0 + (csw << 3);
            __builtin_amdgcn_global_load_lds((const __attribute__((address_space(1))) void*)src,
                (__attribute__((address_space(3))) void*)&Vb[buf][db + 8 * j][0], 16, 0, 0);
        }
    };

    float m_s = -1e30f, l_p = 0.f;
    f32x4 o_acc[8];
#pragma unroll
    for (int ni = 0; ni < 8; ++ni) o_acc[ni] = (f32x4){0.f, 0.f, 0.f, 0.f};

    stage(0, 0);
    __syncthreads();

    int cur = 0;
    for (int jt = 0; jt <= qb; ++jt) {
        if (jt < qb) stage(cur ^ 1, (jt + 1) * 64);   // prefetch overlaps compute

        f32x4 sacc[4] = {};
        __builtin_amdgcn_s_setprio(1);
#pragma unroll
        for (int ks = 0; ks < 4; ++ks) {
#pragma unroll
            for (int ni = 0; ni < 4; ++ni) {
                short8 kf = *(const short8*)&Kb[cur][16 * ni + llo][((4 * ks + lhi) ^ llo) << 3];
                sacc[ni] = __builtin_amdgcn_mfma_f32_16x16x32_bf16(kf, qf[ks], sacc[ni], 0, 0, 0);
            }
        }
        __builtin_amdgcn_s_setprio(0);

        if (jt == qb) {                  // causal mask inside diagonal tile
            int qloc = 16 * w + llo;
#pragma unroll
            for (int ni = 0; ni < 4; ++ni)
#pragma unroll
                for (int r = 0; r < 4; ++r)
                    if (16 * ni + 4 * lhi + r > qloc) sacc[ni][r] = -INFINITY;
        }

        // speculative P with OLD running max (no cross-lane wait)
        float pv[16];
#pragma unroll
        for (int ni = 0; ni < 4; ++ni)
#pragma unroll
            for (int r = 0; r < 4; ++r) pv[4 * ni + r] = exp2f(sacc[ni][r] - m_s);

        // per-lane local max only; __any supplies the cross-lane OR
        float mx = sacc[0][0];
#pragma unroll
        for (int ni = 0; ni < 4; ++ni)
#pragma unroll
            for (int r = 0; r < 4; ++r) mx = fmaxf(mx, sacc[ni][r]);

        if (__any(mx > m_s + 8.f)) {     // rare path: full reduce + rescale
            mx = fmaxf(mx, __shfl_xor(mx, 16));
            mx = fmaxf(mx, __shfl_xor(mx, 32));
            float mnew = fmaxf(m_s, mx);
            float fac = exp2f(m_s - mnew);
#pragma unroll
            for (int r = 0; r < 4; ++r) {
                float fr = __shfl(fac, 4 * lhi + r);
#pragma unroll
                for (int ni = 0; ni < 8; ++ni) o_acc[ni][r] *= fr;
            }
#pragma unroll
            for (int ni = 0; ni < 4; ++ni)
#pragma unroll
                for (int r = 0; r < 4; ++r) pv[4 * ni + r] = exp2f(sacc[ni][r] - mnew);
            l_p *= fac;
            m_s = mnew;
        }

        // pack P -> p_lds
#pragma unroll
        for (int ni = 0; ni < 4; ++ni)
#pragma unroll
            for (int hf = 0; hf < 2; ++hf) {
                unsigned pk;
                asm("v_cvt_pk_bf16_f32 %0, %1, %2" : "=v"(pk)
                    : "v"(pv[4 * ni + 2 * hf]), "v"(pv[4 * ni + 2 * hf + 1]));
                *(unsigned*)&p_lds[w][llo][16 * ni + 4 * lhi + 2 * hf] = pk;
            }

        // deferred l: per-lane partial only (cross-lane reduce in epilogue)
        float ps = 0.f;
#pragma unroll
        for (int j = 0; j < 16; ++j) ps += pv[j];
        l_p += ps;

        // O += P . V
        __builtin_amdgcn_s_setprio(1);
#pragma unroll
        for (int ks = 0; ks < 2; ++ks) {
            short8 pa = *(const short8*)&p_lds[w][llo][32 * ks + 8 * lhi];
#pragma unroll
            for (int ni = 0; ni < 8; ++ni) {
                short8 vf = *(const short8*)&Vb[cur][16 * ni + llo][((4 * ks + lhi) ^ (llo & 7)) << 3];
                o_acc[ni] = __builtin_amdgcn_mfma_f32_16x16x32_bf16(pa, vf, o_acc[ni], 0, 0, 0);
            }
        }
        __builtin_amdgcn_s_setprio(0);

        __syncthreads();   // drains prefetch vmcnt + frees buf[cur]
        cur ^= 1;
    }

    float lsum = l_p;
    lsum += __shfl_xor(lsum, 16);
    lsum += __shfl_xor(lsum, 32);
#pragma unroll
    for (int r = 0; r < 4; ++r) {
        float lr  = __shfl(lsum, 4 * lhi + r);
        float inv = 1.f / lr;
        int qrow2 = q0 + 16 * w + 4 * lhi + r;
#pragma unroll
        for (int ni = 0; ni < 8; ++ni)
            aout[(size_t)qrow2 * DM + h * HD + 16 * ni + llo] = f2bf(o_acc[ni][r] * inv);
    }
}

// ---------------- combine 4 bf16 split-K partials + bias ----------------------
__global__ __launch_bounds__(256)
void combine4_kernel(const u16* __restrict__ p, const float* __restrict__ bias,
                     float* __restrict__ out)
{
    size_t i = ((size_t)blockIdx.x * 256 + threadIdx.x) * 8;
    short8 a0 = *(const short8*)(p + i);
    short8 a1 = *(const short8*)(p + (size_t)CTX * DM + i);
    short8 a2 = *(const short8*)(p + 2 * (size_t)CTX * DM + i);
    short8 a3 = *(const short8*)(p + 3 * (size_t)CTX * DM + i);
    int dbase = (int)(i & (DM - 1));
    float4 bv0 = *(const float4*)(bias + dbase);
    float4 bv1 = *(const float4*)(bias + dbase + 4);
    float r[8];
    float bvv[8] = {bv0.x, bv0.y, bv0.z, bv0.w, bv1.x, bv1.y, bv1.z, bv1.w};
#pragma unroll
    for (int j = 0; j < 8; ++j)
        r[j] = (bf2f((u16)a0[j]) + bf2f((u16)a1[j]))
             + (bf2f((u16)a2[j]) + bf2f((u16)a3[j])) + bvv[j];
    *(float4*)(out + i)     = (float4){r[0], r[1], r[2], r[3]};
    *(float4*)(out + i + 4) = (float4){r[4], r[5], r[6], r[7]};
}

// ------------------------------- launcher ------------------------------------
extern "C" void kernel_launch(void* const* d_in, const int* in_sizes, int n_in,
                              void* d_out, int out_size, void* d_ws, size_t ws_size,
                              hipStream_t stream)
{
    const float* x   = (const float*)d_in[0];
    const float* qng = (const float*)d_in[1];
    const float* qnb = (const float*)d_in[2];
    const float* kng = (const float*)d_in[3];
    const float* knb = (const float*)d_in[4];
    const float* Wq  = (const float*)d_in[5];
    const float* bq  = (const float*)d_in[6];
    const float* Wkv = (const float*)d_in[7];
    const float* bkv = (const float*)d_in[8];
    const float* Wo  = (const float*)d_in[9];
    const float* bo  = (const float*)d_in[10];
    const float* lng = (const float*)d_in[11];
    const float* lnb = (const float*)d_in[12];
    float* out = (float*)d_out;

    uint8_t* ws = (uint8_t*)d_ws;
    size_t off = 0;
    auto alloc = [&](size_t bytes) -> void* {
        void* p = ws + off;
        off += (bytes + 255) & ~(size_t)255;
        return p;
    };
    u16*   WqT  = (u16*)alloc((size_t)DM * DM * 2);
    u16*   WkvT = (u16*)alloc((size_t)2 * DM * DM * 2);
    u16*   WoT  = (u16*)alloc((size_t)DM * DM * 2);
    u16*   Aq   = (u16*)alloc((size_t)CTX * DM * 2);
    u16*   Akv  = (u16*)alloc((size_t)CTX * DM * 2);
    float* ftab = (float*)alloc((size_t)CTX * 64 * 2 * 4);
    u16*   Qf   = (u16*)alloc((size_t)CTX * DM * 2);
    u16*   Kf   = (u16*)alloc((size_t)CTX * DM * 2);
    u16*   vTB  = (u16*)alloc((size_t)CTX * DM * 2);
    u16*   qnB  = (u16*)alloc((size_t)CTX * DM * 2);
    u16*   knB  = (u16*)alloc((size_t)CTX * DM * 2);
    u16*   aB   = (u16*)alloc((size_t)CTX * DM * 2);
    u16*   oprt = (u16*)alloc((size_t)4 * CTX * DM * 2);
    (void)ws_size; (void)in_sizes; (void)n_in; (void)out_size;

    transpose_all_kernel<<<dim3(DM / 32, DM / 32, 4), dim3(32, 8), 0, stream>>>(
        Wq, Wo, Wkv, WqT, WoT, WkvT);

    ln_stats_kernel<<<CTX, 256, 0, stream>>>(x, qng, qnb, kng, knb, Aq, Akv, ftab);

    qkv_gemm256_kernel<<<dim3(192), 512, 0, stream>>>(
        Aq, Akv, WqT, WkvT, bq, bkv, Qf, Kf, vTB);

    const float qk_scale = 0.29730177875068026f;                       // 128^-0.25
    const float fold_q   = 0.08838834764831845f * 1.4426950408889634f; // 1/sqrt(128)*log2(e)
    rot_ln_kernel<<<CTX, 256, 0, stream>>>(
        Qf, Kf, ftab, lng, lnb, qnB, knB, qk_scale, fold_q);

    attn_kernel<<<dim3(CTX / 64, NH), 256, 0, stream>>>(qnB, knB, vTB, aB);

    oproj_gemm256_kernel<<<dim3(256), 512, 0, stream>>>(aB, WoT, oprt);
    combine4_kernel<<<(CTX * DM) / 2048, 256, 0, stream>>>(oprt, bo, out);
}

// Round 6
// 190.009 us; speedup vs baseline: 1.0728x; 1.0010x over previous
//
#include <hip/hip_runtime.h>
#include <stdint.h>
#include <math.h>

#define CTX 2048
#define DM  2048
#define NH  16
#define HD  128

typedef __attribute__((ext_vector_type(8))) short short8;   // 8 x bf16 (4 VGPRs)
typedef __attribute__((ext_vector_type(4))) float f32x4;    // MFMA acc
typedef unsigned short u16;

__device__ __forceinline__ u16 f2bf(float f) {
    unsigned u = __float_as_uint(f);
    unsigned r = u + 0x7fffu + ((u >> 16) & 1u);   // RTNE
    return (u16)(r >> 16);
}
__device__ __forceinline__ float bf2f(u16 h) {
    return __uint_as_float(((unsigned)h) << 16);
}

// Opaque LDS read: invisible to SIInsertWaitcnts' LDS-DMA alias tracking, so
// the compiler cannot insert vmcnt(0) drains before it. Ordering enforced
// manually: counted lgkmcnt + sched_barrier(0) before every consumer (rule #18).
__device__ __forceinline__ short8 ds_read_b128_o(const void* p) {
    short8 r;
    asm volatile("ds_read_b128 %0, %1"
                 : "=v"(r)
                 : "v"((const __attribute__((address_space(3))) void*)p));
    return r;
}

// ------- merged weight transpose + f32->bf16 (W[K][N] -> WT[N][K]), 4 slabs ---
__global__ __launch_bounds__(256)
void transpose_all_kernel(const float* __restrict__ Wq, const float* __restrict__ Wo,
                          const float* __restrict__ Wkv,
                          u16* __restrict__ WqT, u16* __restrict__ WoT, u16* __restrict__ WkvT)
{
    __shared__ float tile[32][33];
    int z = blockIdx.z;
    const float* S; u16* D; int nsrc, c0, r0;
    if (z == 0)      { S = Wq;  D = WqT;  nsrc = DM;     c0 = 0;  r0 = 0;    }
    else if (z == 1) { S = Wo;  D = WoT;  nsrc = DM;     c0 = 0;  r0 = 0;    }
    else if (z == 2) { S = Wkv; D = WkvT; nsrc = 2 * DM; c0 = 0;  r0 = 0;    }
    else             { S = Wkv; D = WkvT; nsrc = 2 * DM; c0 = DM; r0 = DM;   }
    int k0 = blockIdx.x * 32, n0 = blockIdx.y * 32;
    int tx = threadIdx.x, ty = threadIdx.y;          // 32 x 8
#pragma unroll
    for (int j = 0; j < 4; ++j) {
        int kk = ty + 8 * j;
        tile[kk][tx] = S[(size_t)(k0 + kk) * nsrc + c0 + n0 + tx];
    }
    __syncthreads();
#pragma unroll
    for (int j = 0; j < 4; ++j) {
        int nn = ty + 8 * j;
        D[(size_t)(r0 + n0 + nn) * DM + k0 + tx] = f2bf(tile[tx][nn]);
    }
}

// -------- LN stats + normalized A matrices (bf16) + rotary factor table -------
__global__ __launch_bounds__(256)
void ln_stats_kernel(const float* __restrict__ x,
                     const float* __restrict__ qg, const float* __restrict__ qb,
                     const float* __restrict__ kg, const float* __restrict__ kb,
                     u16* __restrict__ Aq, u16* __restrict__ Akv, float* __restrict__ ftab)
{
    int c = blockIdx.x, t = threadIdx.x;
    const float* row = x + (size_t)c * DM;
    float4 v0 = *(const float4*)(row + t * 8);
    float4 v1 = *(const float4*)(row + t * 8 + 4);
    float vals[8] = {v0.x, v0.y, v0.z, v0.w, v1.x, v1.y, v1.z, v1.w};
    float s = 0.f, ss = 0.f;
#pragma unroll
    for (int j = 0; j < 8; ++j) { s += vals[j]; ss += vals[j] * vals[j]; }
#pragma unroll
    for (int off = 32; off; off >>= 1) { s += __shfl_xor(s, off); ss += __shfl_xor(ss, off); }
    __shared__ float red[8];
    int w = t >> 6;
    if ((t & 63) == 0) { red[w] = s; red[4 + w] = ss; }
    __syncthreads();
    float st  = red[0] + red[1] + red[2] + red[3];
    float sst = red[4] + red[5] + red[6] + red[7];
    float mu   = st * (1.f / DM);
    float var  = sst * (1.f / DM) - mu * mu;
    float rstd = rsqrtf(var + 1e-5f);
    if (t < 64) {                         // rotary table, m folded in
        const float LT64 = 10.30895266f / 64.f;   // ln(30000)/64
        float m = sqrtf(sst);
        float sn, cs;
        sincosf((float)c * ((float)t * LT64), &sn, &cs);
        float2 wv = {m * cs, m * sn};
        *(float2*)(ftab + ((size_t)c * 64 + t) * 2) = wv;
    }
    short8 aq, akv;
#pragma unroll
    for (int j = 0; j < 8; ++j) {
        int d = t * 8 + j;
        float xh = (vals[j] - mu) * rstd;
        aq[j]  = (short)f2bf(xh * qg[d] + qb[d]);
        akv[j] = (short)f2bf(xh * kg[d] + kb[d]);
    }
    *(short8*)(Aq  + (size_t)c * DM + t * 8) = aq;
    *(short8*)(Akv + (size_t)c * DM + t * 8) = akv;
}

// ---------------- fused QKV projection GEMM -----------------------------------
// v5: 128x256 tile, BK=64, 4 waves (1Mx4N), SINGLE-buffered 48 KiB LDS ->
// 2 blocks/CU co-resident, grid 384 = all 256 CUs busy (was: 128 KiB, 192
// blocks, 64 CUs idle, occupancy 14%). Cross-BLOCK TLP now covers the stage
// stall and lgkm drains (m97 mechanism) instead of in-block pipelining.
// Per-wave geometry (128x64 output, fragments, XOR swizzle, staging pattern)
// identical to the proven v3 kernel.
//
// Per K-tile: read b0,a03,b1 (16) -> lgkm(4) q00 -> lgkm(0) q01 -> read a47
// (reusing a[] regs, keeps VGPR ~= v3) -> lgkm(0) q11,q10 -> BARRIER (all
// reads of S retired block-wide) -> stage kt+1 into S -> vmcnt(0) -> BARRIER
// (every wave drained its own DMA; after barrier all of S is valid).
__global__ __launch_bounds__(256, 2)
void qkv_gemm256_kernel(const u16* __restrict__ Aq, const u16* __restrict__ Akv,
                        const u16* __restrict__ WqT, const u16* __restrict__ WkvT,
                        const float* __restrict__ bq, const float* __restrict__ bkv,
                        u16* __restrict__ Qf, u16* __restrict__ Kf, u16* __restrict__ vT)
{
    __shared__ __align__(16) u16 As[128][64];         // 16 KiB
    __shared__ __align__(16) u16 Bs[2][128][64];      // 32 KiB

    constexpr int NT = DM / 64;                       // 32 K-tiles

    // XCD swizzle: 384 blocks, 48 contiguous per XCD (384 % 8 == 0, bijective).
    // Within an XCD: 3 consecutive ng values x 16 mt -> B-panel L2 locality.
    int lin = blockIdx.x;
    int swz = (lin & 7) * 48 + (lin >> 3);
    int mt  = swz & 15;         // M tile 0..15 (128 rows)
    int ng  = swz >> 4;         // 0..23
    int seg = ng >> 3;          // 0:Q 1:K 2:V
    int nt  = ng & 7;           // N tile 0..7 (256 cols)

    const u16* Amat; const u16* Bmat; const float* bias; u16* outp; bool rowbias;
    if (seg == 0) {
        Amat = Aq  + (size_t)mt * 128 * DM;
        Bmat = WqT + (size_t)nt * 256 * DM;
        bias = bq + nt * 256;
        outp = Qf + (size_t)mt * 128 * DM + nt * 256;
        rowbias = false;
    } else if (seg == 1) {
        Amat = Akv  + (size_t)mt * 128 * DM;
        Bmat = WkvT + (size_t)nt * 256 * DM;
        bias = bkv + nt * 256;
        outp = Kf + (size_t)mt * 128 * DM + nt * 256;
        rowbias = false;
    } else {
        Amat = WkvT + (size_t)(DM + mt * 128) * DM;   // V dims as GEMM rows
        Bmat = Akv  + (size_t)nt * 256 * DM;          // context as GEMM cols
        bias = bkv + DM + mt * 128;                   // per-row bias
        outp = vT + (size_t)mt * 128 * CTX + nt * 256;
        rowbias = true;
    }

    int tid = threadIdx.x;
    int wid = tid >> 6, l = tid & 63;                 // 4 waves, wave = N slice
    int wc = wid;                                     // 0..3
    int lhi = l >> 4, llo = l & 15;
    int srow  = l >> 3;                               // staging row within 8-row group
    int sunit = (l & 7) ^ srow;                       // inverse-swizzled 16B unit

    // stage tile kt: A 128x64 (4 loads/wave), B 2x128x64 (8 loads/wave)
    auto stage = [&](int kt) {
#pragma unroll
        for (int rd = 0; rd < 4; ++rd) {
            int r = wid * 32 + rd * 8;
            const u16* src = Amat + (size_t)(r + srow) * DM + kt * 64 + sunit * 8;
            __builtin_amdgcn_global_load_lds((const __attribute__((address_space(1))) void*)src,
                (__attribute__((address_space(3))) void*)&As[r][0], 16, 0, 0);
        }
#pragma unroll
        for (int h = 0; h < 2; ++h)
#pragma unroll
            for (int rd = 0; rd < 4; ++rd) {
                int r = wid * 32 + rd * 8;
                const u16* src = Bmat + (size_t)(h * 128 + r + srow) * DM + kt * 64 + sunit * 8;
                __builtin_amdgcn_global_load_lds((const __attribute__((address_space(1))) void*)src,
                    (__attribute__((address_space(3))) void*)&Bs[h][r][0], 16, 0, 0);
            }
    };

    f32x4 acc[8][4] = {};                 // accumulator
    short8 a[4][2];                       // reused for a03 then a47 (VGPR cap)
    short8 b0[2][2], b1[2][2];
    int bhalf = wc >> 1, brow = (wc & 1) * 64;

    stage(0);
    asm volatile("s_waitcnt vmcnt(0)" ::: "memory");
    __builtin_amdgcn_s_barrier();

    for (int kt = 0; kt < NT; ++kt) {
        // ---- reads: b0 (4) + a03 (8) + b1 (4) -------------------------------
#pragma unroll
        for (int ni = 0; ni < 2; ++ni)
#pragma unroll
            for (int ks = 0; ks < 2; ++ks) {
                int r = brow + 16 * ni + llo;
                b0[ni][ks] = ds_read_b128_o(&Bs[bhalf][r][((ks * 4 + lhi) ^ (llo & 7)) << 3]);
            }
#pragma unroll
        for (int mi = 0; mi < 4; ++mi)
#pragma unroll
            for (int ks = 0; ks < 2; ++ks) {
                int r = 16 * mi + llo;
                a[mi][ks] = ds_read_b128_o(&As[r][((ks * 4 + lhi) ^ (llo & 7)) << 3]);
            }
#pragma unroll
        for (int ni = 0; ni < 2; ++ni)
#pragma unroll
            for (int ks = 0; ks < 2; ++ks) {
                int r = brow + 16 * (2 + ni) + llo;
                b1[ni][ks] = ds_read_b128_o(&Bs[bhalf][r][((ks * 4 + lhi) ^ (llo & 7)) << 3]);
            }

        // ---- q00 ------------------------------------------------------------
        asm volatile("s_waitcnt lgkmcnt(4)" ::: "memory");
        __builtin_amdgcn_sched_barrier(0);
        __builtin_amdgcn_s_setprio(1);
#pragma unroll
        for (int ks = 0; ks < 2; ++ks)
#pragma unroll
            for (int mi = 0; mi < 4; ++mi)
#pragma unroll
                for (int ni = 0; ni < 2; ++ni)
                    acc[mi][ni] = __builtin_amdgcn_mfma_f32_16x16x32_bf16(
                        a[mi][ks], b0[ni][ks], acc[mi][ni], 0, 0, 0);
        __builtin_amdgcn_s_setprio(0);

        // ---- q01 ------------------------------------------------------------
        asm volatile("s_waitcnt lgkmcnt(0)" ::: "memory");
        __builtin_amdgcn_sched_barrier(0);
        __builtin_amdgcn_s_setprio(1);
#pragma unroll
        for (int ks = 0; ks < 2; ++ks)
#pragma unroll
            for (int mi = 0; mi < 4; ++mi)
#pragma unroll
                for (int ni = 0; ni < 2; ++ni)
                    acc[mi][2 + ni] = __builtin_amdgcn_mfma_f32_16x16x32_bf16(
                        a[mi][ks], b1[ni][ks], acc[mi][2 + ni], 0, 0, 0);
        __builtin_amdgcn_s_setprio(0);

        // ---- read a47 (reuse regs); q11, q10 --------------------------------
#pragma unroll
        for (int mi = 0; mi < 4; ++mi)
#pragma unroll
            for (int ks = 0; ks < 2; ++ks) {
                int r = 16 * (4 + mi) + llo;
                a[mi][ks] = ds_read_b128_o(&As[r][((ks * 4 + lhi) ^ (llo & 7)) << 3]);
            }
        asm volatile("s_waitcnt lgkmcnt(0)" ::: "memory");
        __builtin_amdgcn_sched_barrier(0);
        __builtin_amdgcn_s_setprio(1);
#pragma unroll
        for (int ks = 0; ks < 2; ++ks)
#pragma unroll
            for (int mi = 0; mi < 4; ++mi)
#pragma unroll
                for (int ni = 0; ni < 2; ++ni)
                    acc[4 + mi][2 + ni] = __builtin_amdgcn_mfma_f32_16x16x32_bf16(
                        a[mi][ks], b1[ni][ks], acc[4 + mi][2 + ni], 0, 0, 0);
#pragma unroll
        for (int ks = 0; ks < 2; ++ks)
#pragma unroll
            for (int mi = 0; mi < 4; ++mi)
#pragma unroll
                for (int ni = 0; ni < 2; ++ni)
                    acc[4 + mi][ni] = __builtin_amdgcn_mfma_f32_16x16x32_bf16(
                        a[mi][ks], b0[ni][ks], acc[4 + mi][ni], 0, 0, 0);
        __builtin_amdgcn_s_setprio(0);

        // ---- all reads of S retired block-wide -> restage -------------------
        __builtin_amdgcn_s_barrier();
        if (kt + 1 < NT) {
            stage(kt + 1);
            asm volatile("s_waitcnt vmcnt(0)" ::: "memory");
            __builtin_amdgcn_s_barrier();
        }
    }

    // ---------------- epilogue: bias + bf16 store ----------------------------
    int cbase = 64 * wc;
    if (!rowbias) {
#pragma unroll
        for (int ni = 0; ni < 4; ++ni) {
            float bv = bias[cbase + 16 * ni + llo];
#pragma unroll
            for (int mi = 0; mi < 8; ++mi)
#pragma unroll
                for (int rr = 0; rr < 4; ++rr) {
                    int gr = 16 * mi + 4 * lhi + rr;
                    outp[(size_t)gr * DM + cbase + 16 * ni + llo] = f2bf(acc[mi][ni][rr] + bv);
                }
        }
    } else {
#pragma unroll
        for (int mi = 0; mi < 8; ++mi)
#pragma unroll
            for (int rr = 0; rr < 4; ++rr) {
                int gr = 16 * mi + 4 * lhi + rr;
                float bv = bias[gr];
#pragma unroll
                for (int ni = 0; ni < 4; ++ni)
                    outp[(size_t)gr * CTX + cbase + 16 * ni + llo] = f2bf(acc[mi][ni][rr] + bv);
            }
    }
}

// ---------------- O-projection GEMM: 256^2 tile, 4-way split-K ----------------
__global__ __launch_bounds__(512, 2)
void oproj_gemm256_kernel(const u16* __restrict__ A, const u16* __restrict__ BT,
                          u16* __restrict__ outp)
{
    __shared__ __align__(16) u16 As[2][2][128][64];
    __shared__ __align__(16) u16 Bs[2][2][128][64];

    constexpr int NT = 8;                             // 8 K-tiles = 512 deep

    // XCD swizzle: 256 blocks, 32 contiguous per XCD (256 % 8 == 0, bijective)
    int lin = blockIdx.x;
    int swz = (lin & 7) * 32 + (lin >> 3);
    int kz  = swz >> 6;          // K split 0..3
    int rem = swz & 63;
    int mt  = rem & 7;
    int nt  = rem >> 3;

    const u16* Amat = A  + (size_t)mt * 256 * DM + kz * 512;
    const u16* Bmat = BT + (size_t)nt * 256 * DM + kz * 512;
    u16* out = outp + (size_t)kz * CTX * DM + (size_t)mt * 256 * DM + nt * 256;

    int tid = threadIdx.x;
    int wid = tid >> 6, l = tid & 63;
    int wr = wid >> 2, wc = wid & 3;
    int lhi = l >> 4, llo = l & 15;
    int srow  = l >> 3;
    int sunit = (l & 7) ^ srow;

    auto stageA = [&](int kt, int h) {
#pragma unroll
        for (int rd = 0; rd < 2; ++rd) {
            const u16* src = Amat + (size_t)(h * 128 + rd * 64 + wid * 8 + srow) * DM
                             + kt * 64 + sunit * 8;
            __builtin_amdgcn_global_load_lds((const __attribute__((address_space(1))) void*)src,
                (__attribute__((address_space(3))) void*)&As[kt & 1][h][rd * 64 + wid * 8][0],
                16, 0, 0);
        }
    };
    auto stageB = [&](int kt, int h) {
#pragma unroll
        for (int rd = 0; rd < 2; ++rd) {
            const u16* src = Bmat + (size_t)(h * 128 + rd * 64 + wid * 8 + srow) * DM
                             + kt * 64 + sunit * 8;
            __builtin_amdgcn_global_load_lds((const __attribute__((address_space(1))) void*)src,
                (__attribute__((address_space(3))) void*)&Bs[kt & 1][h][rd * 64 + wid * 8][0],
                16, 0, 0);
        }
    };

    f32x4 acc[8][4] = {};
    short8 a[4][2];
    short8 b0[2][2], b1[2][2];
    int bhalf = wc >> 1, brow = (wc & 1) * 64;

    stageA(0, 0); stageA(0, 1); stageB(0, 0); stageB(0, 1);
    stageA(1, 0); stageA(1, 1); stageB(1, 0); stageB(1, 1);
    asm volatile("s_waitcnt vmcnt(8)" ::: "memory");
    __builtin_amdgcn_s_barrier();

    for (int kt = 0; kt < NT; ++kt) {
        int buf = kt & 1;

#pragma unroll
        for (int ni = 0; ni < 2; ++ni)
#pragma unroll
            for (int ks = 0; ks < 2; ++ks) {
                int r = brow + 16 * ni + llo;
                b0[ni][ks] = ds_read_b128_o(&Bs[buf][bhalf][r][((ks * 4 + lhi) ^ (llo & 7)) << 3]);
            }
#pragma unroll
        for (int mi = 0; mi < 4; ++mi)
#pragma unroll
            for (int ks = 0; ks < 2; ++ks) {
                int r = 16 * mi + llo;
                a[mi][ks] = ds_read_b128_o(&As[buf][wr][r][((ks * 4 + lhi) ^ (llo & 7)) << 3]);
            }
#pragma unroll
        for (int ni = 0; ni < 2; ++ni)
#pragma unroll
            for (int ks = 0; ks < 2; ++ks) {
                int r = brow + 16 * (2 + ni) + llo;
                b1[ni][ks] = ds_read_b128_o(&Bs[buf][bhalf][r][((ks * 4 + lhi) ^ (llo & 7)) << 3]);
            }

        asm volatile("s_waitcnt lgkmcnt(4)" ::: "memory");
        __builtin_amdgcn_sched_barrier(0);
        __builtin_amdgcn_s_setprio(1);
#pragma unroll
        for (int ks = 0; ks < 2; ++ks)
#pragma unroll
            for (int mi = 0; mi < 4; ++mi)
#pragma unroll
                for (int ni = 0; ni < 2; ++ni)
                    acc[mi][ni] = __builtin_amdgcn_mfma_f32_16x16x32_bf16(
                        a[mi][ks], b0[ni][ks], acc[mi][ni], 0, 0, 0);
        __builtin_amdgcn_s_setprio(0);

        asm volatile("s_waitcnt lgkmcnt(0)" ::: "memory");
        __builtin_amdgcn_sched_barrier(0);
        __builtin_amdgcn_s_setprio(1);
#pragma unroll
        for (int ks = 0; ks < 2; ++ks)
#pragma unroll
            for (int mi = 0; mi < 4; ++mi)
#pragma unroll
                for (int ni = 0; ni < 2; ++ni)
                    acc[mi][2 + ni] = __builtin_amdgcn_mfma_f32_16x16x32_bf16(
                        a[mi][ks], b1[ni][ks], acc[mi][2 + ni], 0, 0, 0);
        __builtin_amdgcn_s_setprio(0);

        __builtin_amdgcn_s_barrier();   // #1

        if (kt + 2 < NT) { stageB(kt + 2, 0); stageB(kt + 2, 1); }
#pragma unroll
        for (int mi = 0; mi < 4; ++mi)
#pragma unroll
            for (int ks = 0; ks < 2; ++ks) {
                int r = 16 * (4 + mi) + llo;
                a[mi][ks] = ds_read_b128_o(&As[buf][wr][r][((ks * 4 + lhi) ^ (llo & 7)) << 3]);
            }

        asm volatile("s_waitcnt lgkmcnt(0)" ::: "memory");
        __builtin_amdgcn_sched_barrier(0);
        __builtin_amdgcn_s_setprio(1);
#pragma unroll
        for (int ks = 0; ks < 2; ++ks)
#pragma unroll
            for (int mi = 0; mi < 4; ++mi)
#pragma unroll
                for (int ni = 0; ni < 2; ++ni)
                    acc[4 + mi][2 + ni] = __builtin_amdgcn_mfma_f32_16x16x32_bf16(
                        a[mi][ks], b1[ni][ks], acc[4 + mi][2 + ni], 0, 0, 0);
        __builtin_amdgcn_s_setprio(0);

        __builtin_amdgcn_s_barrier();   // #2

        if (kt + 2 < NT) { stageA(kt + 2, 0); stageA(kt + 2, 1); }
        __builtin_amdgcn_s_setprio(1);
#pragma unroll
        for (int ks = 0; ks < 2; ++ks)
#pragma unroll
            for (int mi = 0; mi < 4; ++mi)
#pragma unroll
                for (int ni = 0; ni < 2; ++ni)
                    acc[4 + mi][ni] = __builtin_amdgcn_mfma_f32_16x16x32_bf16(
                        a[mi][ks], b0[ni][ks], acc[4 + mi][ni], 0, 0, 0);
        __builtin_amdgcn_s_setprio(0);

        if (kt + 2 < NT)      { asm volatile("s_waitcnt vmcnt(8)" ::: "memory"); }
        else if (kt + 1 < NT) { asm volatile("s_waitcnt vmcnt(0)" ::: "memory"); }
        __builtin_amdgcn_s_barrier();   // #3
    }

    int rbase = 128 * wr;
    int cbase = 64 * wc;
#pragma unroll
    for (int ni = 0; ni < 4; ++ni) {
#pragma unroll
        for (int mi = 0; mi < 8; ++mi)
#pragma unroll
            for (int rr = 0; rr < 4; ++rr) {
                int gr = rbase + 16 * mi + 4 * lhi + rr;
                out[(size_t)gr * DM + cbase + 16 * ni + llo] = f2bf(acc[mi][ni][rr]);
            }
    }
}

// -------- table-driven rotary + per-head LN (one block per token row) ---------
__global__ __launch_bounds__(256)
void rot_ln_kernel(const u16* __restrict__ Qf, const u16* __restrict__ Kf,
                   const float* __restrict__ ftab,
                   const float* __restrict__ g, const float* __restrict__ b,
                   u16* __restrict__ qnB, u16* __restrict__ knB,
                   float qk_scale, float fold_q)
{
    int c = blockIdx.x, t = threadIdx.x;
    int h  = t >> 4;
    int dl = (t & 15) * 8;
    const float* tab = ftab + ((size_t)c * 64 + (dl >> 1)) * 2;
    float fre[4], fim[4];
#pragma unroll
    for (int p = 0; p < 4; ++p) { fre[p] = tab[2 * p]; fim[p] = tab[2 * p + 1]; }
    float gv[8], bv2[8];
#pragma unroll
    for (int j = 0; j < 8; ++j) { gv[j] = g[dl + j]; bv2[j] = b[dl + j]; }

#pragma unroll
    for (int z = 0; z < 2; ++z) {
        const u16* src = z ? Kf : Qf;
        u16* dst = z ? knB : qnB;
        float fold = z ? 1.f : fold_q;
        short8 vv = *(const short8*)(src + (size_t)c * DM + t * 8);
        float o[8];
        float s = 0.f, ss = 0.f;
#pragma unroll
        for (int p = 0; p < 4; ++p) {
            float a  = bf2f((u16)vv[2 * p])     * qk_scale;
            float b2 = bf2f((u16)vv[2 * p + 1]) * qk_scale;
            float o0 = a * fre[p] - b2 * fim[p];
            float o1 = a * fim[p] + b2 * fre[p];
            o[2 * p] = o0; o[2 * p + 1] = o1;
            s += o0 + o1;
            ss += o0 * o0 + o1 * o1;
        }
#pragma unroll
        for (int off = 1; off < 16; off <<= 1) {
            s += __shfl_xor(s, off);
            ss += __shfl_xor(ss, off);
        }
        float mu   = s * (1.f / HD);
        float var  = ss * (1.f / HD) - mu * mu;
        float rstd = rsqrtf(var + 1e-5f);
        short8 r;
#pragma unroll
        for (int j = 0; j < 8; ++j)
            r[j] = (short)f2bf(((o[j] - mu) * rstd * gv[j] + bv2[j]) * fold);
        *(short8*)(dst + ((size_t)h * CTX + c) * HD + dl) = r;
    }
}

// ---------------- causal flash attention v4b ----------------------------------
__global__ __launch_bounds__(256, 2)
void attn_kernel(const u16* __restrict__ qn, const u16* __restrict__ kn,
                 const u16* __restrict__ vT, u16* __restrict__ aout)
{
    __shared__ __align__(16) u16 Kb[2][64][128];
    __shared__ __align__(16) u16 Vb[2][128][64];
    __shared__ __align__(16) u16 p_lds[4][16][72];

    int h  = blockIdx.y;
    int xs = blockIdx.x;
    int qb = (h >= 8) ? (31 - xs) : xs;   // CU load-balance pairing
    int q0 = qb * 64;
    int tid = threadIdx.x, w = tid >> 6, l = tid & 63;
    int lhi = l >> 4, llo = l & 15;

    const u16* qrow = qn + ((size_t)h * CTX + q0 + 16 * w + llo) * HD + 8 * lhi;
    short8 qf[4];
#pragma unroll
    for (int ks = 0; ks < 4; ++ks) qf[ks] = *(const short8*)(qrow + 32 * ks);

    auto stage = [&](int buf, int kv0) {
        int rb = 16 * w;
#pragma unroll
        for (int j = 0; j < 4; ++j) {
            int r = rb + 4 * j + (l >> 4);
            int csw = (l & 15) ^ (r & 15);
            const u16* src = kn + ((size_t)h * CTX + kv0 + r) * HD + (csw << 3);
            __builtin_amdgcn_global_load_lds((const __attribute__((address_space(1))) void*)src,
                (__attribute__((address_space(3))) void*)&Kb[buf][rb + 4 * j][0], 16, 0, 0);
        }
        int db = 32 * w;
#pragma unroll
        for (int j = 0; j < 4; ++j) {
            int d = db + 8 * j + (l >> 3);
            int csw = (l & 7) ^ (d & 7);
            const u16* src = vT + ((size_t)h * HD + d) * CTX + kv0 + (csw << 3);
            __builtin_amdgcn_global_load_lds((const __attribute__((address_space(1))) void*)src,
                (__attribute__((address_space(3))) void*)&Vb[buf][db + 8 * j][0], 16, 0, 0);
        }
    };

    float m_s = -1e30f, l_p = 0.f;
    f32x4 o_acc[8];
#pragma unroll
    for (int ni = 0; ni < 8; ++ni) o_acc[ni] = (f32x4){0.f, 0.f, 0.f, 0.f};

    stage(0, 0);
    __syncthreads();

    int cur = 0;
    for (int jt = 0; jt <= qb; ++jt) {
        if (jt < qb) stage(cur ^ 1, (jt + 1) * 64);   // prefetch overlaps compute

        f32x4 sacc[4] = {};
        __builtin_amdgcn_s_setprio(1);
#pragma unroll
        for (int ks = 0; ks < 4; ++ks) {
#pragma unroll
            for (int ni = 0; ni < 4; ++ni) {
                short8 kf = *(const short8*)&Kb[cur][16 * ni + llo][((4 * ks + lhi) ^ llo) << 3];
                sacc[ni] = __builtin_amdgcn_mfma_f32_16x16x32_bf16(kf, qf[ks], sacc[ni], 0, 0, 0);
            }
        }
        __builtin_amdgcn_s_setprio(0);

        if (jt == qb) {                  // causal mask inside diagonal tile
            int qloc = 16 * w + llo;
#pragma unroll
            for (int ni = 0; ni < 4; ++ni)
#pragma unroll
                for (int r = 0; r < 4; ++r)
                    if (16 * ni + 4 * lhi + r > qloc) sacc[ni][r] = -INFINITY;
        }

        // speculative P with OLD running max (no cross-lane wait)
        float pv[16];
#pragma unroll
        for (int ni = 0; ni < 4; ++ni)
#pragma unroll
            for (int r = 0; r < 4; ++r) pv[4 * ni + r] = exp2f(sacc[ni][r] - m_s);

        // per-lane local max only; __any supplies the cross-lane OR
        float mx = sacc[0][0];
#pragma unroll
        for (int ni = 0; ni < 4; ++ni)
#pragma unroll
            for (int r = 0; r < 4; ++r) mx = fmaxf(mx, sacc[ni][r]);

        if (__any(mx > m_s + 8.f)) {     // rare path: full reduce + rescale
            mx = fmaxf(mx, __shfl_xor(mx, 16));
            mx = fmaxf(mx, __shfl_xor(mx, 32));
            float mnew = fmaxf(m_s, mx);
            float fac = exp2f(m_s - mnew);
#pragma unroll
            for (int r = 0; r < 4; ++r) {
                float fr = __shfl(fac, 4 * lhi + r);
#pragma unroll
                for (int ni = 0; ni < 8; ++ni) o_acc[ni][r] *= fr;
            }
#pragma unroll
            for (int ni = 0; ni < 4; ++ni)
#pragma unroll
                for (int r = 0; r < 4; ++r) pv[4 * ni + r] = exp2f(sacc[ni][r] - mnew);
            l_p *= fac;
            m_s = mnew;
        }

        // pack P -> p_lds
#pragma unroll
        for (int ni = 0; ni < 4; ++ni)
#pragma unroll
            for (int hf = 0; hf < 2; ++hf) {
                unsigned pk;
                asm("v_cvt_pk_bf16_f32 %0, %1, %2" : "=v"(pk)
                    : "v"(pv[4 * ni + 2 * hf]), "v"(pv[4 * ni + 2 * hf + 1]));
                *(unsigned*)&p_lds[w][llo][16 * ni + 4 * lhi + 2 * hf] = pk;
            }

        // deferred l: per-lane partial only (cross-lane reduce in epilogue)
        float ps = 0.f;
#pragma unroll
        for (int j = 0; j < 16; ++j) ps += pv[j];
        l_p += ps;

        // O += P . V
        __builtin_amdgcn_s_setprio(1);
#pragma unroll
        for (int ks = 0; ks < 2; ++ks) {
            short8 pa = *(const short8*)&p_lds[w][llo][32 * ks + 8 * lhi];
#pragma unroll
            for (int ni = 0; ni < 8; ++ni) {
                short8 vf = *(const short8*)&Vb[cur][16 * ni + llo][((4 * ks + lhi) ^ (llo & 7)) << 3];
                o_acc[ni] = __builtin_amdgcn_mfma_f32_16x16x32_bf16(pa, vf, o_acc[ni], 0, 0, 0);
            }
        }
        __builtin_amdgcn_s_setprio(0);

        __syncthreads();   // drains prefetch vmcnt + frees buf[cur]
        cur ^= 1;
    }

    float lsum = l_p;
    lsum += __shfl_xor(lsum, 16);
    lsum += __shfl_xor(lsum, 32);
#pragma unroll
    for (int r = 0; r < 4; ++r) {
        float lr  = __shfl(lsum, 4 * lhi + r);
        float inv = 1.f / lr;
        int qrow2 = q0 + 16 * w + 4 * lhi + r;
#pragma unroll
        for (int ni = 0; ni < 8; ++ni)
            aout[(size_t)qrow2 * DM + h * HD + 16 * ni + llo] = f2bf(o_acc[ni][r] * inv);
    }
}

// ---------------- combine 4 bf16 split-K partials + bias ----------------------
__global__ __launch_bounds__(256)
void combine4_kernel(const u16* __restrict__ p, const float* __restrict__ bias,
                     float* __restrict__ out)
{
    size_t i = ((size_t)blockIdx.x * 256 + threadIdx.x) * 8;
    short8 a0 = *(const short8*)(p + i);
    short8 a1 = *(const short8*)(p + (size_t)CTX * DM + i);
    short8 a2 = *(const short8*)(p + 2 * (size_t)CTX * DM + i);
    short8 a3 = *(const short8*)(p + 3 * (size_t)CTX * DM + i);
    int dbase = (int)(i & (DM - 1));
    float4 bv0 = *(const float4*)(bias + dbase);
    float4 bv1 = *(const float4*)(bias + dbase + 4);
    float r[8];
    float bvv[8] = {bv0.x, bv0.y, bv0.z, bv0.w, bv1.x, bv1.y, bv1.z, bv1.w};
#pragma unroll
    for (int j = 0; j < 8; ++j)
        r[j] = (bf2f((u16)a0[j]) + bf2f((u16)a1[j]))
             + (bf2f((u16)a2[j]) + bf2f((u16)a3[j])) + bvv[j];
    *(float4*)(out + i)     = (float4){r[0], r[1], r[2], r[3]};
    *(float4*)(out + i + 4) = (float4){r[4], r[5], r[6], r[7]};
}

// ------------------------------- launcher ------------------------------------
extern "C" void kernel_launch(void* const* d_in, const int* in_sizes, int n_in,
                              void* d_out, int out_size, void* d_ws, size_t ws_size,
                              hipStream_t stream)
{
    const float* x   = (const float*)d_in[0];
    const float* qng = (const float*)d_in[1];
    const float* qnb = (const float*)d_in[2];
    const float* kng = (const float*)d_in[3];
    const float* knb = (const float*)d_in[4];
    const float* Wq  = (const float*)d_in[5];
    const float* bq  = (const float*)d_in[6];
    const float* Wkv = (const float*)d_in[7];
    const float* bkv = (const float*)d_in[8];
    const float* Wo  = (const float*)d_in[9];
    const float* bo  = (const float*)d_in[10];
    const float* lng = (const float*)d_in[11];
    const float* lnb = (const float*)d_in[12];
    float* out = (float*)d_out;

    uint8_t* ws = (uint8_t*)d_ws;
    size_t off = 0;
    auto alloc = [&](size_t bytes) -> void* {
        void* p = ws + off;
        off += (bytes + 255) & ~(size_t)255;
        return p;
    };
    u16*   WqT  = (u16*)alloc((size_t)DM * DM * 2);
    u16*   WkvT = (u16*)alloc((size_t)2 * DM * DM * 2);
    u16*   WoT  = (u16*)alloc((size_t)DM * DM * 2);
    u16*   Aq   = (u16*)alloc((size_t)CTX * DM * 2);
    u16*   Akv  = (u16*)alloc((size_t)CTX * DM * 2);
    float* ftab = (float*)alloc((size_t)CTX * 64 * 2 * 4);
    u16*   Qf   = (u16*)alloc((size_t)CTX * DM * 2);
    u16*   Kf   = (u16*)alloc((size_t)CTX * DM * 2);
    u16*   vTB  = (u16*)alloc((size_t)CTX * DM * 2);
    u16*   qnB  = (u16*)alloc((size_t)CTX * DM * 2);
    u16*   knB  = (u16*)alloc((size_t)CTX * DM * 2);
    u16*   aB   = (u16*)alloc((size_t)CTX * DM * 2);
    u16*   oprt = (u16*)alloc((size_t)4 * CTX * DM * 2);
    (void)ws_size; (void)in_sizes; (void)n_in; (void)out_size;

    transpose_all_kernel<<<dim3(DM / 32, DM / 32, 4), dim3(32, 8), 0, stream>>>(
        Wq, Wo, Wkv, WqT, WoT, WkvT);

    ln_stats_kernel<<<CTX, 256, 0, stream>>>(x, qng, qnb, kng, knb, Aq, Akv, ftab);

    qkv_gemm256_kernel<<<dim3(384), 256, 0, stream>>>(
        Aq, Akv, WqT, WkvT, bq, bkv, Qf, Kf, vTB);

    const float qk_scale = 0.29730177875068026f;                       // 128^-0.25
    const float fold_q   = 0.08838834764831845f * 1.4426950408889634f; // 1/sqrt(128)*log2(e)
    rot_ln_kernel<<<CTX, 256, 0, stream>>>(
        Qf, Kf, ftab, lng, lnb, qnB, knB, qk_scale, fold_q);

    attn_kernel<<<dim3(CTX / 64, NH), 256, 0, stream>>>(qnB, knB, vTB, aB);

    oproj_gemm256_kernel<<<dim3(256), 512, 0, stream>>>(aB, WoT, oprt);
    combine4_kernel<<<(CTX * DM) / 2048, 256, 0, stream>>>(oprt, bo, out);
}